// Round 3
// baseline (1868.675 us; speedup 1.0000x reference)
//
#include <hip/hip_runtime.h>
#include <hip/hip_bf16.h>

typedef __hip_bfloat16 bf16;

// NOTE: ALL harness inputs and the output are fp32 (reference uses jnp.float32
// throughout). Internal intermediates y0/out1 are stored bf16 to keep the
// workspace at ~19 MB.

// ---------------------------------------------------------------------------
// A) transpose conv weights: wT[ci][k][co] = w_conv[co][ci][k]
// ---------------------------------------------------------------------------
__global__ __launch_bounds__(256) void wtrans_k(const float* __restrict__ w, float* __restrict__ wT){
    int idx = blockIdx.x*256 + threadIdx.x;           // < 589824
    int co = idx / 2304, r = idx % 2304;
    int ci = r / 9, k = r % 9;
    wT[(ci*9 + k)*256 + co] = w[idx];
}

// ---------------------------------------------------------------------------
// B) 3x3 conv 256->256, pad 1.  block=(cog,h,b), 256 thr, 16-ci chunks in LDS
//    output y0 stored as bf16
// ---------------------------------------------------------------------------
__global__ __launch_bounds__(256) void conv3x3_k(const float* __restrict__ x, const float* __restrict__ wT,
                                                 const float* __restrict__ bias, bf16* __restrict__ y0){
    __shared__ float xs[16][3][68];        // [ci][kh][w+1], zero-padded
    __shared__ float wsm[16*9*64];         // [ci][k][co']
    const int cog = blockIdx.x, h = blockIdx.y, b = blockIdx.z;
    const int t = threadIdx.x;
    const int tx = t & 15, ty = t >> 4;
    const int w0 = tx*4, co0 = ty*4;
    float acc[4][4] = {};
    for (int cic = 0; cic < 16; ++cic){
        __syncthreads();
        for (int i = t; i < 16*3*64; i += 256){      // 3072
            int ci = i / 192, r = i % 192, kh = r >> 6, w = r & 63;
            int hh = h + kh - 1;
            float v = 0.f;
            if (hh >= 0 && hh < 64) v = x[(((b*256 + cic*16 + ci)*64) + hh)*64 + w];
            xs[ci][kh][w+1] = v;
        }
        for (int i = t; i < 48; i += 256){           // pad cols
            int ci = i/3, kh = i%3;
            xs[ci][kh][0] = 0.f; xs[ci][kh][65] = 0.f; xs[ci][kh][66] = 0.f; xs[ci][kh][67] = 0.f;
        }
        for (int i = t; i < 16*9*64; i += 256){      // 9216
            int co = i & 63, r = i >> 6;             // r = ci*9+k
            int ci = r / 9, k = r % 9;
            wsm[i] = wT[((cic*16 + ci)*9 + k)*256 + cog*64 + co];
        }
        __syncthreads();
        for (int ci = 0; ci < 16; ++ci){
            #pragma unroll
            for (int kh = 0; kh < 3; ++kh){
                const float4 xa = *(const float4*)&xs[ci][kh][w0];
                const float4 xb = *(const float4*)&xs[ci][kh][w0+4];
                float xr[8] = {xa.x,xa.y,xa.z,xa.w,xb.x,xb.y,xb.z,xb.w};
                #pragma unroll
                for (int kw = 0; kw < 3; ++kw){
                    const float4 wv = *(const float4*)&wsm[(ci*9 + kh*3 + kw)*64 + co0];
                    const float* wf = (const float*)&wv;
                    #pragma unroll
                    for (int c = 0; c < 4; ++c){
                        #pragma unroll
                        for (int j = 0; j < 4; ++j) acc[c][j] += wf[c]*xr[j+kw];
                    }
                }
            }
        }
    }
    #pragma unroll
    for (int c = 0; c < 4; ++c){
        int co = cog*64 + co0 + c;
        float bv = bias[co];
        bf16* yp = y0 + (((b*256 + co)*64) + h)*64 + w0;
        #pragma unroll
        for (int j = 0; j < 4; ++j) yp[j] = __float2bfloat16(acc[c][j]+bv);
    }
}

// ---------------------------------------------------------------------------
// C) fused separable depthwise (7/11/21) + residual.  One block per (b,c)
//    plane: y0 plane in LDS -> hconv -> LDS -> vconv -> register acc.
// ---------------------------------------------------------------------------
template<int K>
__device__ __forceinline__ void sep_branch(float (&pl)[64][64], float (&hp)[64][64],
                                           int c, int t,
                                           const float* __restrict__ wh, const float* __restrict__ bh,
                                           const float* __restrict__ wv, const float* __restrict__ bv,
                                           float* acc){
    constexpr int P = K/2;
    float wk[K];
    #pragma unroll
    for (int j = 0; j < K; ++j) wk[j] = wh[c*K + j];
    float bhv = bh[c];
    __syncthreads();                 // pl ready / previous hp consumption done
    #pragma unroll
    for (int k = 0; k < 16; ++k){
        int h = k*4 + (t >> 6), w = t & 63;
        float s = bhv;
        #pragma unroll
        for (int j = 0; j < K; ++j){
            int ww = w + j - P;
            if (ww >= 0 && ww < 64) s += pl[h][ww]*wk[j];
        }
        hp[h][w] = s;
    }
    float vk[K];
    #pragma unroll
    for (int j = 0; j < K; ++j) vk[j] = wv[c*K + j];
    float bvv = bv[c];
    __syncthreads();                 // hp ready
    #pragma unroll
    for (int k = 0; k < 16; ++k){
        int h = k*4 + (t >> 6), w = t & 63;
        float s = bvv;
        #pragma unroll
        for (int j = 0; j < K; ++j){
            int hh = h + j - P;
            if (hh >= 0 && hh < 64) s += hp[hh][w]*vk[j];
        }
        acc[k] += s;
    }
}

__global__ __launch_bounds__(256) void sepconv_k(const bf16* __restrict__ y0,
        const float* __restrict__ w01, const float* __restrict__ b01,
        const float* __restrict__ w02, const float* __restrict__ b02,
        const float* __restrict__ w11, const float* __restrict__ b11,
        const float* __restrict__ w12, const float* __restrict__ b12,
        const float* __restrict__ w21, const float* __restrict__ b21,
        const float* __restrict__ w22, const float* __restrict__ b22,
        bf16* __restrict__ out1){
    __shared__ float pl[64][64];
    __shared__ float hp[64][64];
    int bc = blockIdx.x;             // b*256 + c
    int c = bc & 255;
    int t = threadIdx.x;
    const bf16* src = y0 + bc*4096;
    for (int i = t; i < 4096; i += 256) pl[i>>6][i&63] = __bfloat162float(src[i]);
    float acc[16];
    #pragma unroll
    for (int k = 0; k < 16; ++k) acc[k] = 0.f;
    sep_branch<7 >(pl, hp, c, t, w01, b01, w02, b02, acc);
    sep_branch<11>(pl, hp, c, t, w11, b11, w12, b12, acc);
    sep_branch<21>(pl, hp, c, t, w21, b21, w22, b22, acc);
    bf16* dst = out1 + bc*4096;
    #pragma unroll
    for (int k = 0; k < 16; ++k){
        int h = k*4 + (t >> 6), w = t & 63;
        dst[h*64 + w] = __float2bfloat16(acc[k] + pl[h][w]);
    }
}

// ---------------------------------------------------------------------------
// E) 1x1 projection 256->32: t[b][cc][p], tT[b][p][cc], rn2[b][p]
// ---------------------------------------------------------------------------
__global__ __launch_bounds__(256) void proj_k(const bf16* __restrict__ out1, const float* __restrict__ wp,
                                              const float* __restrict__ bp, float* __restrict__ tbuf,
                                              float* __restrict__ tT, float* __restrict__ rn2){
    __shared__ float wl[256][32];
    int pt = blockIdx.x, b = blockIdx.y, t = threadIdx.x;
    for (int i = t; i < 8192; i += 256){
        int ci = i >> 5, cc = i & 31;
        wl[ci][cc] = wp[cc*256 + ci];
    }
    __syncthreads();
    int p = pt*256 + t;
    float acc[32] = {};
    const bf16* xb = out1 + b*1048576;
    for (int ci = 0; ci < 256; ++ci){
        float v = __bfloat162float(xb[ci*4096 + p]);
        #pragma unroll
        for (int q = 0; q < 8; ++q){
            float4 w4 = *(const float4*)&wl[ci][q*4];
            acc[q*4+0] += w4.x*v; acc[q*4+1] += w4.y*v; acc[q*4+2] += w4.z*v; acc[q*4+3] += w4.w*v;
        }
    }
    float ss = 0.f;
    #pragma unroll
    for (int cc = 0; cc < 32; ++cc){ acc[cc] += bp[cc]; ss += acc[cc]*acc[cc]; }
    rn2[b*4096 + p] = 1.f / fmaxf(sqrtf(ss), 1e-12f);
    #pragma unroll
    for (int cc = 0; cc < 32; ++cc) tbuf[(b*32+cc)*4096 + p] = acc[cc];
    float* tp = tT + (b*4096 + p)*32;
    #pragma unroll
    for (int q = 0; q < 8; ++q){
        float4 o; o.x = acc[q*4]; o.y = acc[q*4+1]; o.z = acc[q*4+2]; o.w = acc[q*4+3];
        *(float4*)&tp[q*4] = o;
    }
}

// ---------------------------------------------------------------------------
// F) row norms of t over p (128 rows)
// ---------------------------------------------------------------------------
__global__ __launch_bounds__(256) void rn1_k(const float* __restrict__ tbuf, float* __restrict__ rn1){
    int row = blockIdx.x;
    int t = threadIdx.x;
    float ss = 0.f;
    const float* r = tbuf + row*4096;
    for (int p = t; p < 4096; p += 256){ float v = r[p]; ss += v*v; }
    #pragma unroll
    for (int o = 32; o > 0; o >>= 1) ss += __shfl_down(ss, o, 64);
    __shared__ float red[4];
    if ((t & 63) == 0) red[t >> 6] = ss;
    __syncthreads();
    if (t == 0){
        float tot = red[0]+red[1]+red[2]+red[3];
        rn1[row] = 1.f / fmaxf(sqrtf(tot), 1e-12f);
    }
}

// ---------------------------------------------------------------------------
// G1) gram[b][i][j] = <t_i, t_j>  (one block per batch, no atomics)
// ---------------------------------------------------------------------------
__global__ __launch_bounds__(256) void gram_k(const float* __restrict__ tbuf, float* __restrict__ gram){
    __shared__ float tl[32][128];
    int b = blockIdx.x, t = threadIdx.x;
    float s[4] = {0.f, 0.f, 0.f, 0.f};
    for (int ps = 0; ps < 32; ++ps){
        __syncthreads();
        for (int idx = t; idx < 4096; idx += 256){
            tl[idx>>7][idx&127] = tbuf[(b*32 + (idx>>7))*4096 + ps*128 + (idx&127)];
        }
        __syncthreads();
        #pragma unroll
        for (int k = 0; k < 4; ++k){
            int pair = k*256 + t;
            int i = pair >> 5, j = pair & 31;
            float a0 = 0.f;
            for (int pp = 0; pp < 128; pp += 4){
                float4 a = *(const float4*)&tl[i][pp];
                float4 c = *(const float4*)&tl[j][pp];
                a0 += a.x*c.x + a.y*c.y + a.z*c.z + a.w*c.w;
            }
            s[k] += a0;
        }
    }
    #pragma unroll
    for (int k = 0; k < 4; ++k) gram[b*1024 + k*256 + t] = s[k];
}

// ---------------------------------------------------------------------------
// G2) attn1 softmax (rows unit-norm -> s<=1, exp directly); store transposed
// ---------------------------------------------------------------------------
__global__ __launch_bounds__(64) void attn1_k(const float* __restrict__ gram, const float* __restrict__ rn1,
                                              float* __restrict__ attn1T){
    int i = blockIdx.x, b = blockIdx.y, j = threadIdx.x;
    float e = 0.f;
    if (j < 32) e = __expf(rn1[b*32+i]*rn1[b*32+j]*gram[b*1024 + i*32 + j]);
    float sum = e;
    #pragma unroll
    for (int o = 32; o > 0; o >>= 1) sum += __shfl_xor(sum, o, 64);
    if (j < 32) attn1T[b*1024 + j*32 + i] = e / sum;
}

// ---------------------------------------------------------------------------
// H) out2 = attn1 @ t
// ---------------------------------------------------------------------------
__global__ __launch_bounds__(256) void out2_k(const float* __restrict__ tbuf, const float* __restrict__ attn1T,
                                              float* __restrict__ out2){
    __shared__ float al[1024];
    int pt = blockIdx.x, b = blockIdx.y, t = threadIdx.x;
    for (int i = t; i < 1024; i += 256) al[i] = attn1T[b*1024 + i];
    __syncthreads();
    int p = pt*256 + t;
    float acc[32] = {};
    for (int j = 0; j < 32; ++j){
        float tv = tbuf[(b*32+j)*4096 + p];
        #pragma unroll
        for (int q = 0; q < 8; ++q){
            float4 a = *(const float4*)&al[j*32 + q*4];
            acc[q*4+0] += a.x*tv; acc[q*4+1] += a.y*tv; acc[q*4+2] += a.z*tv; acc[q*4+3] += a.w*tv;
        }
    }
    #pragma unroll
    for (int i = 0; i < 32; ++i) out2[(b*32+i)*4096 + p] = acc[i];
}

// ---------------------------------------------------------------------------
// J) spatial attention, flash-style. Unit-norm rows => max score == 1, so no
//    online max and slice merge is a plain sum.  block=(64 i)x(4 j-slices).
// ---------------------------------------------------------------------------
__global__ __launch_bounds__(256) void flash_k(const float* __restrict__ tT, const float* __restrict__ rn2,
                                               float* __restrict__ out3T){
    __shared__ float kv[4*64*36];          // tiles; reused as [256][36] for merge
    int it = blockIdx.x, b = blockIdx.y, t = threadIdx.x;
    int lane = t & 63, slice = t >> 6;
    int i = it*64 + lane;
    float q[32];
    const float* qp = tT + (b*4096 + i)*32;
    #pragma unroll
    for (int qq = 0; qq < 8; ++qq){
        float4 v = *(const float4*)&qp[qq*4];
        q[qq*4] = v.x; q[qq*4+1] = v.y; q[qq*4+2] = v.z; q[qq*4+3] = v.w;
    }
    float rni = rn2[b*4096 + i];
    float acc[32] = {};
    float l = 0.f;
    for (int jt = 0; jt < 16; ++jt){
        __syncthreads();
        for (int idx = t; idx < 9216; idx += 256){
            int c = idx % 36;
            if (c < 33){
                int rr = idx / 36;
                int jj = rr & 63, sj = rr >> 6;
                int jg = sj*1024 + jt*64 + jj;
                kv[idx] = (c < 32) ? tT[(b*4096 + jg)*32 + c] : rn2[b*4096 + jg];
            }
        }
        __syncthreads();
        const float* kb = &kv[slice*64*36];
        for (int jj = 0; jj < 64; ++jj){
            const float* kr = kb + jj*36;
            float4 v[8];
            #pragma unroll
            for (int qq = 0; qq < 8; ++qq) v[qq] = *(const float4*)&kr[qq*4];
            float s = 0.f;
            #pragma unroll
            for (int qq = 0; qq < 8; ++qq)
                s += q[qq*4]*v[qq].x + q[qq*4+1]*v[qq].y + q[qq*4+2]*v[qq].z + q[qq*4+3]*v[qq].w;
            float e = __expf(s * rni * kr[32]);
            l += e;
            #pragma unroll
            for (int qq = 0; qq < 8; ++qq){
                acc[qq*4]   += e*v[qq].x; acc[qq*4+1] += e*v[qq].y;
                acc[qq*4+2] += e*v[qq].z; acc[qq*4+3] += e*v[qq].w;
            }
        }
    }
    __syncthreads();
    float* pr = &kv[t*36];
    #pragma unroll
    for (int cc = 0; cc < 32; ++cc) pr[cc] = acc[cc];
    pr[32] = l;
    __syncthreads();
    {
        int i2 = t & 63, ccg = (t >> 6)*8;
        float ltot = 0.f;
        #pragma unroll
        for (int s = 0; s < 4; ++s) ltot += kv[(s*64 + i2)*36 + 32];
        float o[8] = {};
        #pragma unroll
        for (int s = 0; s < 4; ++s){
            const float* rr = &kv[(s*64 + i2)*36 + ccg];
            #pragma unroll
            for (int c = 0; c < 8; ++c) o[c] += rr[c];
        }
        float inv = 1.f / ltot;
        float* op = out3T + (b*4096 + it*64 + i2)*32 + ccg;
        #pragma unroll
        for (int c = 0; c < 8; ++c) op[c] = o[c]*inv;
    }
}

// ---------------------------------------------------------------------------
// K) out5 = w3 @ concat(out2,out3) + b3 + t
// ---------------------------------------------------------------------------
__global__ __launch_bounds__(256) void out5_k(const float* __restrict__ out2, const float* __restrict__ out3T,
                                              const float* __restrict__ tbuf, const float* __restrict__ w3,
                                              const float* __restrict__ b3, float* __restrict__ out5){
    __shared__ float w3T[64*32];
    int pt = blockIdx.x, b = blockIdx.y, t = threadIdx.x;
    for (int i = t; i < 2048; i += 256){
        int j = i >> 5, cc = i & 31;
        w3T[i] = w3[cc*64 + j];
    }
    __syncthreads();
    int p = pt*256 + t;
    float acc[32];
    #pragma unroll
    for (int cc = 0; cc < 32; ++cc) acc[cc] = b3[cc] + tbuf[(b*32+cc)*4096 + p];
    for (int j = 0; j < 32; ++j){
        float v = out2[(b*32+j)*4096 + p];
        #pragma unroll
        for (int q = 0; q < 8; ++q){
            float4 a = *(const float4*)&w3T[j*32 + q*4];
            acc[q*4] += a.x*v; acc[q*4+1] += a.y*v; acc[q*4+2] += a.z*v; acc[q*4+3] += a.w*v;
        }
    }
    const float* o3 = out3T + (b*4096 + p)*32;
    float v3[32];
    #pragma unroll
    for (int q = 0; q < 8; ++q){
        float4 v = *(const float4*)&o3[q*4];
        v3[q*4]=v.x; v3[q*4+1]=v.y; v3[q*4+2]=v.z; v3[q*4+3]=v.w;
    }
    #pragma unroll
    for (int j = 0; j < 32; ++j){
        float v = v3[j];
        #pragma unroll
        for (int q = 0; q < 8; ++q){
            float4 a = *(const float4*)&w3T[(32+j)*32 + q*4];
            acc[q*4] += a.x*v; acc[q*4+1] += a.y*v; acc[q*4+2] += a.z*v; acc[q*4+3] += a.w*v;
        }
    }
    #pragma unroll
    for (int cc = 0; cc < 32; ++cc) out5[(b*32+cc)*4096 + p] = acc[cc];
}

// ---------------------------------------------------------------------------
// L) out = w4 @ out5 + b4  (fp32 store)
// ---------------------------------------------------------------------------
__global__ __launch_bounds__(256) void final_k(const float* __restrict__ out5, const float* __restrict__ w4,
                                               const float* __restrict__ b4, float* __restrict__ out){
    __shared__ float w4T[32*64];
    int pt = blockIdx.x, cog = blockIdx.y, b = blockIdx.z, t = threadIdx.x;
    for (int i = t; i < 2048; i += 256){
        int cc = i >> 6, co = i & 63;
        w4T[i] = w4[(cog*64+co)*32 + cc];
    }
    __syncthreads();
    int p = pt*256 + t;
    float acc[64];
    #pragma unroll
    for (int co = 0; co < 64; ++co) acc[co] = b4[cog*64+co];
    for (int cc = 0; cc < 32; ++cc){
        float v = out5[(b*32+cc)*4096 + p];
        #pragma unroll
        for (int q = 0; q < 16; ++q){
            float4 a = *(const float4*)&w4T[cc*64 + q*4];
            acc[q*4] += a.x*v; acc[q*4+1] += a.y*v; acc[q*4+2] += a.z*v; acc[q*4+3] += a.w*v;
        }
    }
    #pragma unroll
    for (int co = 0; co < 64; ++co)
        out[(b*256 + cog*64 + co)*4096 + p] = acc[co];
}

// ---------------------------------------------------------------------------
// Workspace layout (bytes), peak ~19.0 MB:
//   [0,        8388608)  out1 (bf16, 4.19M elems)       live: sepconv..proj
//   [8388608, 16777216)  y0   (bf16, 4.19M elems)       live: conv..sepconv
//   [16777216,19136512)  wT   (fp32, 589824)            live: wtrans..conv3x3
//   [8388608, ...)       attention region (fp32), overlays dead y0/wT
// ---------------------------------------------------------------------------
extern "C" void kernel_launch(void* const* d_in, const int* in_sizes, int n_in,
                              void* d_out, int out_size, void* d_ws, size_t ws_size,
                              hipStream_t stream) {
    const float* x      = (const float*)d_in[0];
    const float* w_conv = (const float*)d_in[1];
    const float* b_conv = (const float*)d_in[2];
    const float* w01 = (const float*)d_in[3];  const float* b01 = (const float*)d_in[4];
    const float* w02 = (const float*)d_in[5];  const float* b02 = (const float*)d_in[6];
    const float* w11 = (const float*)d_in[7];  const float* b11 = (const float*)d_in[8];
    const float* w12 = (const float*)d_in[9];  const float* b12 = (const float*)d_in[10];
    const float* w21 = (const float*)d_in[11]; const float* b21 = (const float*)d_in[12];
    const float* w22 = (const float*)d_in[13]; const float* b22 = (const float*)d_in[14];
    const float* w_proj = (const float*)d_in[15]; const float* b_proj = (const float*)d_in[16];
    const float* w3 = (const float*)d_in[17]; const float* b3 = (const float*)d_in[18];
    const float* w4 = (const float*)d_in[19]; const float* b4 = (const float*)d_in[20];

    char* wsb = (char*)d_ws;
    bf16*  out1 = (bf16*)wsb;                       // 4,194,304 bf16
    bf16*  y0   = (bf16*)(wsb + 8388608);           // 4,194,304 bf16
    float* wT   = (float*)(wsb + 16777216);         // 589,824 f
    float* f    = (float*)d_ws;
    float* tbuf   = f + 2097152;   // byte  8,388,608 (overlays dead y0)
    float* tT     = f + 2621440;   // byte 10,485,760
    float* out2   = f + 3145728;   // byte 12,582,912
    float* out3T  = f + 3670016;   // byte 14,680,064
    float* out5   = f + 4194304;   // byte 16,777,216 (wT dead by then)
    float* rn1    = f + 4718592;   // byte 18,874,368
    float* gram   = f + 4718720;
    float* attn1T = f + 4722816;
    float* rn2    = f + 4726912;   // ends at byte 18,973,184

    wtrans_k<<<dim3(2304), 256, 0, stream>>>(w_conv, wT);
    conv3x3_k<<<dim3(4, 64, 4), 256, 0, stream>>>(x, wT, b_conv, y0);
    sepconv_k<<<dim3(1024), 256, 0, stream>>>(y0, w01, b01, w02, b02,
                                              w11, b11, w12, b12,
                                              w21, b21, w22, b22, out1);
    proj_k<<<dim3(16, 4), 256, 0, stream>>>(out1, w_proj, b_proj, tbuf, tT, rn2);
    rn1_k<<<dim3(128), 256, 0, stream>>>(tbuf, rn1);
    gram_k<<<dim3(4), 256, 0, stream>>>(tbuf, gram);
    attn1_k<<<dim3(32, 4), 64, 0, stream>>>(gram, rn1, attn1T);
    out2_k<<<dim3(16, 4), 256, 0, stream>>>(tbuf, attn1T, out2);
    flash_k<<<dim3(64, 4), 256, 0, stream>>>(tT, rn2, out3T);
    out5_k<<<dim3(16, 4), 256, 0, stream>>>(out2, out3T, tbuf, w3, b3, out5);
    final_k<<<dim3(16, 4, 4), 256, 0, stream>>>(out5, w4, b4, (float*)d_out);
}

// Round 4
// 1183.076 us; speedup vs baseline: 1.5795x; 1.5795x over previous
//
#include <hip/hip_runtime.h>
#include <hip/hip_bf16.h>

typedef __hip_bfloat16 bf16;

// NOTE: ALL harness inputs and the output are fp32 (reference uses jnp.float32
// throughout). Internal intermediates y0/out1 are stored bf16 to keep the
// workspace at ~19 MB.

// ---------------------------------------------------------------------------
// A) transpose conv weights: wT[ci][k][co] = w_conv[co][ci][k]
// ---------------------------------------------------------------------------
__global__ __launch_bounds__(256) void wtrans_k(const float* __restrict__ w, float* __restrict__ wT){
    int idx = blockIdx.x*256 + threadIdx.x;           // < 589824
    int co = idx / 2304, r = idx % 2304;
    int ci = r / 9, k = r % 9;
    wT[(ci*9 + k)*256 + co] = w[idx];
}

// ---------------------------------------------------------------------------
// B) 3x3 conv 256->256, pad 1.  block=(cog,h,b), 256 thr, 16-ci chunks in LDS
//    output y0 stored as bf16
// ---------------------------------------------------------------------------
__global__ __launch_bounds__(256) void conv3x3_k(const float* __restrict__ x, const float* __restrict__ wT,
                                                 const float* __restrict__ bias, bf16* __restrict__ y0){
    __shared__ float xs[16][3][68];        // [ci][kh][w+1], zero-padded
    __shared__ float wsm[16*9*64];         // [ci][k][co']
    const int cog = blockIdx.x, h = blockIdx.y, b = blockIdx.z;
    const int t = threadIdx.x;
    const int tx = t & 15, ty = t >> 4;
    const int w0 = tx*4, co0 = ty*4;
    float acc[4][4] = {};
    for (int cic = 0; cic < 16; ++cic){
        __syncthreads();
        for (int i = t; i < 16*3*64; i += 256){      // 3072
            int ci = i / 192, r = i % 192, kh = r >> 6, w = r & 63;
            int hh = h + kh - 1;
            float v = 0.f;
            if (hh >= 0 && hh < 64) v = x[(((b*256 + cic*16 + ci)*64) + hh)*64 + w];
            xs[ci][kh][w+1] = v;
        }
        for (int i = t; i < 48; i += 256){           // pad cols
            int ci = i/3, kh = i%3;
            xs[ci][kh][0] = 0.f; xs[ci][kh][65] = 0.f; xs[ci][kh][66] = 0.f; xs[ci][kh][67] = 0.f;
        }
        for (int i = t; i < 16*9*64; i += 256){      // 9216
            int co = i & 63, r = i >> 6;             // r = ci*9+k
            int ci = r / 9, k = r % 9;
            wsm[i] = wT[((cic*16 + ci)*9 + k)*256 + cog*64 + co];
        }
        __syncthreads();
        for (int ci = 0; ci < 16; ++ci){
            #pragma unroll
            for (int kh = 0; kh < 3; ++kh){
                const float4 xa = *(const float4*)&xs[ci][kh][w0];
                const float4 xb = *(const float4*)&xs[ci][kh][w0+4];
                float xr[8] = {xa.x,xa.y,xa.z,xa.w,xb.x,xb.y,xb.z,xb.w};
                #pragma unroll
                for (int kw = 0; kw < 3; ++kw){
                    const float4 wv = *(const float4*)&wsm[(ci*9 + kh*3 + kw)*64 + co0];
                    const float* wf = (const float*)&wv;
                    #pragma unroll
                    for (int c = 0; c < 4; ++c){
                        #pragma unroll
                        for (int j = 0; j < 4; ++j) acc[c][j] += wf[c]*xr[j+kw];
                    }
                }
            }
        }
    }
    #pragma unroll
    for (int c = 0; c < 4; ++c){
        int co = cog*64 + co0 + c;
        float bv = bias[co];
        bf16* yp = y0 + (((b*256 + co)*64) + h)*64 + w0;
        #pragma unroll
        for (int j = 0; j < 4; ++j) yp[j] = __float2bfloat16(acc[c][j]+bv);
    }
}

// ---------------------------------------------------------------------------
// C) fused separable depthwise (7/11/21) + residual.  One block per (b,c)
//    plane: y0 plane in LDS -> hconv -> LDS -> vconv -> register acc.
// ---------------------------------------------------------------------------
template<int K>
__device__ __forceinline__ void sep_branch(float (&pl)[64][64], float (&hp)[64][64],
                                           int c, int t,
                                           const float* __restrict__ wh, const float* __restrict__ bh,
                                           const float* __restrict__ wv, const float* __restrict__ bv,
                                           float* acc){
    constexpr int P = K/2;
    float wk[K];
    #pragma unroll
    for (int j = 0; j < K; ++j) wk[j] = wh[c*K + j];
    float bhv = bh[c];
    __syncthreads();                 // pl ready / previous hp consumption done
    #pragma unroll
    for (int k = 0; k < 16; ++k){
        int h = k*4 + (t >> 6), w = t & 63;
        float s = bhv;
        #pragma unroll
        for (int j = 0; j < K; ++j){
            int ww = w + j - P;
            if (ww >= 0 && ww < 64) s += pl[h][ww]*wk[j];
        }
        hp[h][w] = s;
    }
    float vk[K];
    #pragma unroll
    for (int j = 0; j < K; ++j) vk[j] = wv[c*K + j];
    float bvv = bv[c];
    __syncthreads();                 // hp ready
    #pragma unroll
    for (int k = 0; k < 16; ++k){
        int h = k*4 + (t >> 6), w = t & 63;
        float s = bvv;
        #pragma unroll
        for (int j = 0; j < K; ++j){
            int hh = h + j - P;
            if (hh >= 0 && hh < 64) s += hp[hh][w]*vk[j];
        }
        acc[k] += s;
    }
}

__global__ __launch_bounds__(256) void sepconv_k(const bf16* __restrict__ y0,
        const float* __restrict__ w01, const float* __restrict__ b01,
        const float* __restrict__ w02, const float* __restrict__ b02,
        const float* __restrict__ w11, const float* __restrict__ b11,
        const float* __restrict__ w12, const float* __restrict__ b12,
        const float* __restrict__ w21, const float* __restrict__ b21,
        const float* __restrict__ w22, const float* __restrict__ b22,
        bf16* __restrict__ out1){
    __shared__ float pl[64][64];
    __shared__ float hp[64][64];
    int bc = blockIdx.x;             // b*256 + c
    int c = bc & 255;
    int t = threadIdx.x;
    const bf16* src = y0 + bc*4096;
    for (int i = t; i < 4096; i += 256) pl[i>>6][i&63] = __bfloat162float(src[i]);
    float acc[16];
    #pragma unroll
    for (int k = 0; k < 16; ++k) acc[k] = 0.f;
    sep_branch<7 >(pl, hp, c, t, w01, b01, w02, b02, acc);
    sep_branch<11>(pl, hp, c, t, w11, b11, w12, b12, acc);
    sep_branch<21>(pl, hp, c, t, w21, b21, w22, b22, acc);
    bf16* dst = out1 + bc*4096;
    #pragma unroll
    for (int k = 0; k < 16; ++k){
        int h = k*4 + (t >> 6), w = t & 63;
        dst[h*64 + w] = __float2bfloat16(acc[k] + pl[h][w]);
    }
}

// ---------------------------------------------------------------------------
// E) 1x1 projection 256->32: t[b][cc][p], tT[b][p][cc], rn2[b][p]
// ---------------------------------------------------------------------------
__global__ __launch_bounds__(256) void proj_k(const bf16* __restrict__ out1, const float* __restrict__ wp,
                                              const float* __restrict__ bp, float* __restrict__ tbuf,
                                              float* __restrict__ tT, float* __restrict__ rn2){
    __shared__ float wl[256][32];
    int pt = blockIdx.x, b = blockIdx.y, t = threadIdx.x;
    for (int i = t; i < 8192; i += 256){
        int ci = i >> 5, cc = i & 31;
        wl[ci][cc] = wp[cc*256 + ci];
    }
    __syncthreads();
    int p = pt*256 + t;
    float acc[32] = {};
    const bf16* xb = out1 + b*1048576;
    for (int ci = 0; ci < 256; ++ci){
        float v = __bfloat162float(xb[ci*4096 + p]);
        #pragma unroll
        for (int q = 0; q < 8; ++q){
            float4 w4 = *(const float4*)&wl[ci][q*4];
            acc[q*4+0] += w4.x*v; acc[q*4+1] += w4.y*v; acc[q*4+2] += w4.z*v; acc[q*4+3] += w4.w*v;
        }
    }
    float ss = 0.f;
    #pragma unroll
    for (int cc = 0; cc < 32; ++cc){ acc[cc] += bp[cc]; ss += acc[cc]*acc[cc]; }
    rn2[b*4096 + p] = 1.f / fmaxf(sqrtf(ss), 1e-12f);
    #pragma unroll
    for (int cc = 0; cc < 32; ++cc) tbuf[(b*32+cc)*4096 + p] = acc[cc];
    float* tp = tT + (b*4096 + p)*32;
    #pragma unroll
    for (int q = 0; q < 8; ++q){
        float4 o; o.x = acc[q*4]; o.y = acc[q*4+1]; o.z = acc[q*4+2]; o.w = acc[q*4+3];
        *(float4*)&tp[q*4] = o;
    }
}

// ---------------------------------------------------------------------------
// F) row norms of t over p (128 rows)
// ---------------------------------------------------------------------------
__global__ __launch_bounds__(256) void rn1_k(const float* __restrict__ tbuf, float* __restrict__ rn1){
    int row = blockIdx.x;
    int t = threadIdx.x;
    float ss = 0.f;
    const float* r = tbuf + row*4096;
    for (int p = t; p < 4096; p += 256){ float v = r[p]; ss += v*v; }
    #pragma unroll
    for (int o = 32; o > 0; o >>= 1) ss += __shfl_down(ss, o, 64);
    __shared__ float red[4];
    if ((t & 63) == 0) red[t >> 6] = ss;
    __syncthreads();
    if (t == 0){
        float tot = red[0]+red[1]+red[2]+red[3];
        rn1[row] = 1.f / fmaxf(sqrtf(tot), 1e-12f);
    }
}

// ---------------------------------------------------------------------------
// G1) Gram partials, p-sliced: part[b][ps][i*32+j] = sum_{pp} t_i t_j
//     LDS tile stored transposed+padded: tl[pp][cc], conflict-free compute.
// ---------------------------------------------------------------------------
__global__ __launch_bounds__(256) void gram2_k(const float* __restrict__ tbuf, float* __restrict__ part){
    __shared__ float tl[128][33];
    int ps = blockIdx.x, b = blockIdx.y, t = threadIdx.x;
    for (int idx = t; idx < 4096; idx += 256){
        int cc = idx >> 7, pp = idx & 127;               // coalesced global read
        tl[pp][cc] = tbuf[(b*32+cc)*4096 + ps*128 + pp]; // 2-way LDS write (free)
    }
    __syncthreads();
    #pragma unroll
    for (int k = 0; k < 4; ++k){
        int pair = k*256 + t;
        int i = pair >> 5, j = pair & 31;
        float s = 0.f;
        #pragma unroll 4
        for (int pp = 0; pp < 128; ++pp) s += tl[pp][i]*tl[pp][j];
        part[(b*32+ps)*1024 + pair] = s;
    }
}

// ---------------------------------------------------------------------------
// G2) attn1 softmax: reduce 32 slice-partials, then exp/sum.
//     (rows unit-norm -> s<=1, exp directly); store transposed
// ---------------------------------------------------------------------------
__global__ __launch_bounds__(64) void attn1_k(const float* __restrict__ part, const float* __restrict__ rn1,
                                              float* __restrict__ attn1T){
    int i = blockIdx.x, b = blockIdx.y, j = threadIdx.x;
    float e = 0.f;
    if (j < 32){
        float g = 0.f;
        #pragma unroll 8
        for (int ps = 0; ps < 32; ++ps) g += part[(b*32+ps)*1024 + i*32 + j];
        e = __expf(rn1[b*32+i]*rn1[b*32+j]*g);
    }
    float sum = e;
    #pragma unroll
    for (int o = 32; o > 0; o >>= 1) sum += __shfl_xor(sum, o, 64);
    if (j < 32) attn1T[b*1024 + j*32 + i] = e / sum;
}

// ---------------------------------------------------------------------------
// H) out2 = attn1 @ t
// ---------------------------------------------------------------------------
__global__ __launch_bounds__(256) void out2_k(const float* __restrict__ tbuf, const float* __restrict__ attn1T,
                                              float* __restrict__ out2){
    __shared__ float al[1024];
    int pt = blockIdx.x, b = blockIdx.y, t = threadIdx.x;
    for (int i = t; i < 1024; i += 256) al[i] = attn1T[b*1024 + i];
    __syncthreads();
    int p = pt*256 + t;
    float acc[32] = {};
    for (int j = 0; j < 32; ++j){
        float tv = tbuf[(b*32+j)*4096 + p];
        #pragma unroll
        for (int q = 0; q < 8; ++q){
            float4 a = *(const float4*)&al[j*32 + q*4];
            acc[q*4+0] += a.x*tv; acc[q*4+1] += a.y*tv; acc[q*4+2] += a.z*tv; acc[q*4+3] += a.w*tv;
        }
    }
    #pragma unroll
    for (int i = 0; i < 32; ++i) out2[(b*32+i)*4096 + p] = acc[i];
}

// ---------------------------------------------------------------------------
// J) spatial attention, flash-style. Unit-norm rows => max score == 1, so no
//    online max and slice merge is a plain sum.  block=(64 i)x(4 j-slices).
// ---------------------------------------------------------------------------
__global__ __launch_bounds__(256) void flash_k(const float* __restrict__ tT, const float* __restrict__ rn2,
                                               float* __restrict__ out3T){
    __shared__ float kv[4*64*36];          // tiles; reused as [256][36] for merge
    int it = blockIdx.x, b = blockIdx.y, t = threadIdx.x;
    int lane = t & 63, slice = t >> 6;
    int i = it*64 + lane;
    float q[32];
    const float* qp = tT + (b*4096 + i)*32;
    #pragma unroll
    for (int qq = 0; qq < 8; ++qq){
        float4 v = *(const float4*)&qp[qq*4];
        q[qq*4] = v.x; q[qq*4+1] = v.y; q[qq*4+2] = v.z; q[qq*4+3] = v.w;
    }
    float rni = rn2[b*4096 + i];
    float acc[32] = {};
    float l = 0.f;
    for (int jt = 0; jt < 16; ++jt){
        __syncthreads();
        for (int idx = t; idx < 9216; idx += 256){
            int c = idx % 36;
            if (c < 33){
                int rr = idx / 36;
                int jj = rr & 63, sj = rr >> 6;
                int jg = sj*1024 + jt*64 + jj;
                kv[idx] = (c < 32) ? tT[(b*4096 + jg)*32 + c] : rn2[b*4096 + jg];
            }
        }
        __syncthreads();
        const float* kb = &kv[slice*64*36];
        for (int jj = 0; jj < 64; ++jj){
            const float* kr = kb + jj*36;
            float4 v[8];
            #pragma unroll
            for (int qq = 0; qq < 8; ++qq) v[qq] = *(const float4*)&kr[qq*4];
            float s = 0.f;
            #pragma unroll
            for (int qq = 0; qq < 8; ++qq)
                s += q[qq*4]*v[qq].x + q[qq*4+1]*v[qq].y + q[qq*4+2]*v[qq].z + q[qq*4+3]*v[qq].w;
            float e = __expf(s * rni * kr[32]);
            l += e;
            #pragma unroll
            for (int qq = 0; qq < 8; ++qq){
                acc[qq*4]   += e*v[qq].x; acc[qq*4+1] += e*v[qq].y;
                acc[qq*4+2] += e*v[qq].z; acc[qq*4+3] += e*v[qq].w;
            }
        }
    }
    __syncthreads();
    float* pr = &kv[t*36];
    #pragma unroll
    for (int cc = 0; cc < 32; ++cc) pr[cc] = acc[cc];
    pr[32] = l;
    __syncthreads();
    {
        int i2 = t & 63, ccg = (t >> 6)*8;
        float ltot = 0.f;
        #pragma unroll
        for (int s = 0; s < 4; ++s) ltot += kv[(s*64 + i2)*36 + 32];
        float o[8] = {};
        #pragma unroll
        for (int s = 0; s < 4; ++s){
            const float* rr = &kv[(s*64 + i2)*36 + ccg];
            #pragma unroll
            for (int c = 0; c < 8; ++c) o[c] += rr[c];
        }
        float inv = 1.f / ltot;
        float* op = out3T + (b*4096 + it*64 + i2)*32 + ccg;
        #pragma unroll
        for (int c = 0; c < 8; ++c) op[c] = o[c]*inv;
    }
}

// ---------------------------------------------------------------------------
// K) out5 = w3 @ concat(out2,out3) + b3 + t
// ---------------------------------------------------------------------------
__global__ __launch_bounds__(256) void out5_k(const float* __restrict__ out2, const float* __restrict__ out3T,
                                              const float* __restrict__ tbuf, const float* __restrict__ w3,
                                              const float* __restrict__ b3, float* __restrict__ out5){
    __shared__ float w3T[64*32];
    int pt = blockIdx.x, b = blockIdx.y, t = threadIdx.x;
    for (int i = t; i < 2048; i += 256){
        int j = i >> 5, cc = i & 31;
        w3T[i] = w3[cc*64 + j];
    }
    __syncthreads();
    int p = pt*256 + t;
    float acc[32];
    #pragma unroll
    for (int cc = 0; cc < 32; ++cc) acc[cc] = b3[cc] + tbuf[(b*32+cc)*4096 + p];
    for (int j = 0; j < 32; ++j){
        float v = out2[(b*32+j)*4096 + p];
        #pragma unroll
        for (int q = 0; q < 8; ++q){
            float4 a = *(const float4*)&w3T[j*32 + q*4];
            acc[q*4] += a.x*v; acc[q*4+1] += a.y*v; acc[q*4+2] += a.z*v; acc[q*4+3] += a.w*v;
        }
    }
    const float* o3 = out3T + (b*4096 + p)*32;
    float v3[32];
    #pragma unroll
    for (int q = 0; q < 8; ++q){
        float4 v = *(const float4*)&o3[q*4];
        v3[q*4]=v.x; v3[q*4+1]=v.y; v3[q*4+2]=v.z; v3[q*4+3]=v.w;
    }
    #pragma unroll
    for (int j = 0; j < 32; ++j){
        float v = v3[j];
        #pragma unroll
        for (int q = 0; q < 8; ++q){
            float4 a = *(const float4*)&w3T[(32+j)*32 + q*4];
            acc[q*4] += a.x*v; acc[q*4+1] += a.y*v; acc[q*4+2] += a.z*v; acc[q*4+3] += a.w*v;
        }
    }
    #pragma unroll
    for (int cc = 0; cc < 32; ++cc) out5[(b*32+cc)*4096 + p] = acc[cc];
}

// ---------------------------------------------------------------------------
// L) out = w4 @ out5 + b4  (fp32 store)
// ---------------------------------------------------------------------------
__global__ __launch_bounds__(256) void final_k(const float* __restrict__ out5, const float* __restrict__ w4,
                                               const float* __restrict__ b4, float* __restrict__ out){
    __shared__ float w4T[32*64];
    int pt = blockIdx.x, cog = blockIdx.y, b = blockIdx.z, t = threadIdx.x;
    for (int i = t; i < 2048; i += 256){
        int cc = i >> 6, co = i & 63;
        w4T[i] = w4[(cog*64+co)*32 + cc];
    }
    __syncthreads();
    int p = pt*256 + t;
    float acc[64];
    #pragma unroll
    for (int co = 0; co < 64; ++co) acc[co] = b4[cog*64+co];
    for (int cc = 0; cc < 32; ++cc){
        float v = out5[(b*32+cc)*4096 + p];
        #pragma unroll
        for (int q = 0; q < 16; ++q){
            float4 a = *(const float4*)&w4T[cc*64 + q*4];
            acc[q*4] += a.x*v; acc[q*4+1] += a.y*v; acc[q*4+2] += a.z*v; acc[q*4+3] += a.w*v;
        }
    }
    #pragma unroll
    for (int co = 0; co < 64; ++co)
        out[(b*256 + cog*64 + co)*4096 + p] = acc[co];
}

// ---------------------------------------------------------------------------
// Workspace layout (bytes), peak ~19.0 MB:
//   [0,        8388608)  out1 (bf16)  live: sepconv..proj; then part (512 KB)
//   [8388608, 16777216)  y0   (bf16)  live: conv..sepconv; then attn fp32 rgn
//   [16777216,19136512)  wT   (fp32)  live: wtrans..conv3x3; then out5
// ---------------------------------------------------------------------------
extern "C" void kernel_launch(void* const* d_in, const int* in_sizes, int n_in,
                              void* d_out, int out_size, void* d_ws, size_t ws_size,
                              hipStream_t stream) {
    const float* x      = (const float*)d_in[0];
    const float* w_conv = (const float*)d_in[1];
    const float* b_conv = (const float*)d_in[2];
    const float* w01 = (const float*)d_in[3];  const float* b01 = (const float*)d_in[4];
    const float* w02 = (const float*)d_in[5];  const float* b02 = (const float*)d_in[6];
    const float* w11 = (const float*)d_in[7];  const float* b11 = (const float*)d_in[8];
    const float* w12 = (const float*)d_in[9];  const float* b12 = (const float*)d_in[10];
    const float* w21 = (const float*)d_in[11]; const float* b21 = (const float*)d_in[12];
    const float* w22 = (const float*)d_in[13]; const float* b22 = (const float*)d_in[14];
    const float* w_proj = (const float*)d_in[15]; const float* b_proj = (const float*)d_in[16];
    const float* w3 = (const float*)d_in[17]; const float* b3 = (const float*)d_in[18];
    const float* w4 = (const float*)d_in[19]; const float* b4 = (const float*)d_in[20];

    char* wsb = (char*)d_ws;
    bf16*  out1 = (bf16*)wsb;                       // 4,194,304 bf16
    bf16*  y0   = (bf16*)(wsb + 8388608);           // 4,194,304 bf16
    float* wT   = (float*)(wsb + 16777216);         // 589,824 f
    float* f    = (float*)d_ws;
    float* part   = f + 0;         // 131,072 f (overlays dead out1)
    float* tbuf   = f + 2097152;   // byte  8,388,608 (overlays dead y0)
    float* tT     = f + 2621440;   // byte 10,485,760
    float* out2   = f + 3145728;   // byte 12,582,912
    float* out3T  = f + 3670016;   // byte 14,680,064
    float* out5   = f + 4194304;   // byte 16,777,216 (wT dead by then)
    float* rn1    = f + 4718592;   // byte 18,874,368
    float* attn1T = f + 4722816;
    float* rn2    = f + 4726912;   // ends at byte 18,973,184

    wtrans_k<<<dim3(2304), 256, 0, stream>>>(w_conv, wT);
    conv3x3_k<<<dim3(4, 64, 4), 256, 0, stream>>>(x, wT, b_conv, y0);
    sepconv_k<<<dim3(1024), 256, 0, stream>>>(y0, w01, b01, w02, b02,
                                              w11, b11, w12, b12,
                                              w21, b21, w22, b22, out1);
    proj_k<<<dim3(16, 4), 256, 0, stream>>>(out1, w_proj, b_proj, tbuf, tT, rn2);
    rn1_k<<<dim3(128), 256, 0, stream>>>(tbuf, rn1);
    gram2_k<<<dim3(32, 4), 256, 0, stream>>>(tbuf, part);
    attn1_k<<<dim3(32, 4), 64, 0, stream>>>(part, rn1, attn1T);
    out2_k<<<dim3(16, 4), 256, 0, stream>>>(tbuf, attn1T, out2);
    flash_k<<<dim3(64, 4), 256, 0, stream>>>(tT, rn2, out3T);
    out5_k<<<dim3(16, 4), 256, 0, stream>>>(out2, out3T, tbuf, w3, b3, out5);
    final_k<<<dim3(16, 4, 4), 256, 0, stream>>>(out5, w4, b4, (float*)d_out);
}

// Round 5
// 928.806 us; speedup vs baseline: 2.0119x; 1.2738x over previous
//
#include <hip/hip_runtime.h>
#include <hip/hip_bf16.h>

typedef __hip_bfloat16 bf16;

// NOTE: ALL harness inputs and the output are fp32 (reference uses jnp.float32
// throughout). Internal intermediates y0/out1 are stored bf16 to keep the
// workspace at ~19 MB.

// ---------------------------------------------------------------------------
// A) transpose conv weights: wT[ci][k][co] = w_conv[co][ci][k]
// ---------------------------------------------------------------------------
__global__ __launch_bounds__(256) void wtrans_k(const float* __restrict__ w, float* __restrict__ wT){
    int idx = blockIdx.x*256 + threadIdx.x;           // < 589824
    int co = idx / 2304, r = idx % 2304;
    int ci = r / 9, k = r % 9;
    wT[(ci*9 + k)*256 + co] = w[idx];
}

// ---------------------------------------------------------------------------
// B) 3x3 conv 256->256, pad 1.  block=(cog,h,b), 256 thr, 16-ci chunks in LDS
//    output y0 stored as bf16
// ---------------------------------------------------------------------------
__global__ __launch_bounds__(256) void conv3x3_k(const float* __restrict__ x, const float* __restrict__ wT,
                                                 const float* __restrict__ bias, bf16* __restrict__ y0){
    __shared__ float xs[16][3][68];        // [ci][kh][w+1], zero-padded
    __shared__ float wsm[16*9*64];         // [ci][k][co']
    const int cog = blockIdx.x, h = blockIdx.y, b = blockIdx.z;
    const int t = threadIdx.x;
    const int tx = t & 15, ty = t >> 4;
    const int w0 = tx*4, co0 = ty*4;
    float acc[4][4] = {};
    for (int cic = 0; cic < 16; ++cic){
        __syncthreads();
        for (int i = t; i < 16*3*64; i += 256){      // 3072
            int ci = i / 192, r = i % 192, kh = r >> 6, w = r & 63;
            int hh = h + kh - 1;
            float v = 0.f;
            if (hh >= 0 && hh < 64) v = x[(((b*256 + cic*16 + ci)*64) + hh)*64 + w];
            xs[ci][kh][w+1] = v;
        }
        for (int i = t; i < 48; i += 256){           // pad cols
            int ci = i/3, kh = i%3;
            xs[ci][kh][0] = 0.f; xs[ci][kh][65] = 0.f; xs[ci][kh][66] = 0.f; xs[ci][kh][67] = 0.f;
        }
        for (int i = t; i < 16*9*64; i += 256){      // 9216
            int co = i & 63, r = i >> 6;             // r = ci*9+k
            int ci = r / 9, k = r % 9;
            wsm[i] = wT[((cic*16 + ci)*9 + k)*256 + cog*64 + co];
        }
        __syncthreads();
        for (int ci = 0; ci < 16; ++ci){
            #pragma unroll
            for (int kh = 0; kh < 3; ++kh){
                const float4 xa = *(const float4*)&xs[ci][kh][w0];
                const float4 xb = *(const float4*)&xs[ci][kh][w0+4];
                float xr[8] = {xa.x,xa.y,xa.z,xa.w,xb.x,xb.y,xb.z,xb.w};
                #pragma unroll
                for (int kw = 0; kw < 3; ++kw){
                    const float4 wv = *(const float4*)&wsm[(ci*9 + kh*3 + kw)*64 + co0];
                    const float* wf = (const float*)&wv;
                    #pragma unroll
                    for (int c = 0; c < 4; ++c){
                        #pragma unroll
                        for (int j = 0; j < 4; ++j) acc[c][j] += wf[c]*xr[j+kw];
                    }
                }
            }
        }
    }
    #pragma unroll
    for (int c = 0; c < 4; ++c){
        int co = cog*64 + co0 + c;
        float bv = bias[co];
        bf16* yp = y0 + (((b*256 + co)*64) + h)*64 + w0;
        #pragma unroll
        for (int j = 0; j < 4; ++j) yp[j] = __float2bfloat16(acc[c][j]+bv);
    }
}

// ---------------------------------------------------------------------------
// C) fused separable depthwise (7/11/21) + residual.  One block per (b,c)
//    plane: y0 plane in LDS -> hconv -> LDS -> vconv -> register acc.
// ---------------------------------------------------------------------------
template<int K>
__device__ __forceinline__ void sep_branch(float (&pl)[64][64], float (&hp)[64][64],
                                           int c, int t,
                                           const float* __restrict__ wh, const float* __restrict__ bh,
                                           const float* __restrict__ wv, const float* __restrict__ bv,
                                           float* acc){
    constexpr int P = K/2;
    float wk[K];
    #pragma unroll
    for (int j = 0; j < K; ++j) wk[j] = wh[c*K + j];
    float bhv = bh[c];
    __syncthreads();                 // pl ready / previous hp consumption done
    #pragma unroll
    for (int k = 0; k < 16; ++k){
        int h = k*4 + (t >> 6), w = t & 63;
        float s = bhv;
        #pragma unroll
        for (int j = 0; j < K; ++j){
            int ww = w + j - P;
            if (ww >= 0 && ww < 64) s += pl[h][ww]*wk[j];
        }
        hp[h][w] = s;
    }
    float vk[K];
    #pragma unroll
    for (int j = 0; j < K; ++j) vk[j] = wv[c*K + j];
    float bvv = bv[c];
    __syncthreads();                 // hp ready
    #pragma unroll
    for (int k = 0; k < 16; ++k){
        int h = k*4 + (t >> 6), w = t & 63;
        float s = bvv;
        #pragma unroll
        for (int j = 0; j < K; ++j){
            int hh = h + j - P;
            if (hh >= 0 && hh < 64) s += hp[hh][w]*vk[j];
        }
        acc[k] += s;
    }
}

__global__ __launch_bounds__(256) void sepconv_k(const bf16* __restrict__ y0,
        const float* __restrict__ w01, const float* __restrict__ b01,
        const float* __restrict__ w02, const float* __restrict__ b02,
        const float* __restrict__ w11, const float* __restrict__ b11,
        const float* __restrict__ w12, const float* __restrict__ b12,
        const float* __restrict__ w21, const float* __restrict__ b21,
        const float* __restrict__ w22, const float* __restrict__ b22,
        bf16* __restrict__ out1){
    __shared__ float pl[64][64];
    __shared__ float hp[64][64];
    int bc = blockIdx.x;             // b*256 + c
    int c = bc & 255;
    int t = threadIdx.x;
    const bf16* src = y0 + bc*4096;
    for (int i = t; i < 4096; i += 256) pl[i>>6][i&63] = __bfloat162float(src[i]);
    float acc[16];
    #pragma unroll
    for (int k = 0; k < 16; ++k) acc[k] = 0.f;
    sep_branch<7 >(pl, hp, c, t, w01, b01, w02, b02, acc);
    sep_branch<11>(pl, hp, c, t, w11, b11, w12, b12, acc);
    sep_branch<21>(pl, hp, c, t, w21, b21, w22, b22, acc);
    bf16* dst = out1 + bc*4096;
    #pragma unroll
    for (int k = 0; k < 16; ++k){
        int h = k*4 + (t >> 6), w = t & 63;
        dst[h*64 + w] = __float2bfloat16(acc[k] + pl[h][w]);
    }
}

// ---------------------------------------------------------------------------
// E) 1x1 projection 256->32: t[b][cc][p], tT[b][p][cc], rn2[b][p]
// ---------------------------------------------------------------------------
__global__ __launch_bounds__(256) void proj_k(const bf16* __restrict__ out1, const float* __restrict__ wp,
                                              const float* __restrict__ bp, float* __restrict__ tbuf,
                                              float* __restrict__ tT, float* __restrict__ rn2){
    __shared__ float wl[256][32];
    int pt = blockIdx.x, b = blockIdx.y, t = threadIdx.x;
    for (int i = t; i < 8192; i += 256){
        int ci = i >> 5, cc = i & 31;
        wl[ci][cc] = wp[cc*256 + ci];
    }
    __syncthreads();
    int p = pt*256 + t;
    float acc[32] = {};
    const bf16* xb = out1 + b*1048576;
    for (int ci = 0; ci < 256; ++ci){
        float v = __bfloat162float(xb[ci*4096 + p]);
        #pragma unroll
        for (int q = 0; q < 8; ++q){
            float4 w4 = *(const float4*)&wl[ci][q*4];
            acc[q*4+0] += w4.x*v; acc[q*4+1] += w4.y*v; acc[q*4+2] += w4.z*v; acc[q*4+3] += w4.w*v;
        }
    }
    float ss = 0.f;
    #pragma unroll
    for (int cc = 0; cc < 32; ++cc){ acc[cc] += bp[cc]; ss += acc[cc]*acc[cc]; }
    rn2[b*4096 + p] = 1.f / fmaxf(sqrtf(ss), 1e-12f);
    #pragma unroll
    for (int cc = 0; cc < 32; ++cc) tbuf[(b*32+cc)*4096 + p] = acc[cc];
    float* tp = tT + (b*4096 + p)*32;
    #pragma unroll
    for (int q = 0; q < 8; ++q){
        float4 o; o.x = acc[q*4]; o.y = acc[q*4+1]; o.z = acc[q*4+2]; o.w = acc[q*4+3];
        *(float4*)&tp[q*4] = o;
    }
}

// ---------------------------------------------------------------------------
// F) row norms of t over p (128 rows)
// ---------------------------------------------------------------------------
__global__ __launch_bounds__(256) void rn1_k(const float* __restrict__ tbuf, float* __restrict__ rn1){
    int row = blockIdx.x;
    int t = threadIdx.x;
    float ss = 0.f;
    const float* r = tbuf + row*4096;
    for (int p = t; p < 4096; p += 256){ float v = r[p]; ss += v*v; }
    #pragma unroll
    for (int o = 32; o > 0; o >>= 1) ss += __shfl_down(ss, o, 64);
    __shared__ float red[4];
    if ((t & 63) == 0) red[t >> 6] = ss;
    __syncthreads();
    if (t == 0){
        float tot = red[0]+red[1]+red[2]+red[3];
        rn1[row] = 1.f / fmaxf(sqrtf(tot), 1e-12f);
    }
}

// ---------------------------------------------------------------------------
// G1) Gram partials, p-sliced: part[b][ps][i*32+j] = sum_{pp} t_i t_j
//     LDS tile stored transposed+padded: tl[pp][cc], conflict-free compute.
// ---------------------------------------------------------------------------
__global__ __launch_bounds__(256) void gram2_k(const float* __restrict__ tbuf, float* __restrict__ part){
    __shared__ float tl[128][33];
    int ps = blockIdx.x, b = blockIdx.y, t = threadIdx.x;
    for (int idx = t; idx < 4096; idx += 256){
        int cc = idx >> 7, pp = idx & 127;               // coalesced global read
        tl[pp][cc] = tbuf[(b*32+cc)*4096 + ps*128 + pp]; // 2-way LDS write (free)
    }
    __syncthreads();
    #pragma unroll
    for (int k = 0; k < 4; ++k){
        int pair = k*256 + t;
        int i = pair >> 5, j = pair & 31;
        float s = 0.f;
        #pragma unroll 4
        for (int pp = 0; pp < 128; ++pp) s += tl[pp][i]*tl[pp][j];
        part[(b*32+ps)*1024 + pair] = s;
    }
}

// ---------------------------------------------------------------------------
// G2) attn1 softmax: reduce 32 slice-partials, then exp/sum.
//     (rows unit-norm -> s<=1, exp directly); store transposed
// ---------------------------------------------------------------------------
__global__ __launch_bounds__(64) void attn1_k(const float* __restrict__ part, const float* __restrict__ rn1,
                                              float* __restrict__ attn1T){
    int i = blockIdx.x, b = blockIdx.y, j = threadIdx.x;
    float e = 0.f;
    if (j < 32){
        float g = 0.f;
        #pragma unroll 8
        for (int ps = 0; ps < 32; ++ps) g += part[(b*32+ps)*1024 + i*32 + j];
        e = __expf(rn1[b*32+i]*rn1[b*32+j]*g);
    }
    float sum = e;
    #pragma unroll
    for (int o = 32; o > 0; o >>= 1) sum += __shfl_xor(sum, o, 64);
    if (j < 32) attn1T[b*1024 + j*32 + i] = e / sum;
}

// ---------------------------------------------------------------------------
// H) out2 = attn1 @ t
// ---------------------------------------------------------------------------
__global__ __launch_bounds__(256) void out2_k(const float* __restrict__ tbuf, const float* __restrict__ attn1T,
                                              float* __restrict__ out2){
    __shared__ float al[1024];
    int pt = blockIdx.x, b = blockIdx.y, t = threadIdx.x;
    for (int i = t; i < 1024; i += 256) al[i] = attn1T[b*1024 + i];
    __syncthreads();
    int p = pt*256 + t;
    float acc[32] = {};
    for (int j = 0; j < 32; ++j){
        float tv = tbuf[(b*32+j)*4096 + p];
        #pragma unroll
        for (int q = 0; q < 8; ++q){
            float4 a = *(const float4*)&al[j*32 + q*4];
            acc[q*4+0] += a.x*tv; acc[q*4+1] += a.y*tv; acc[q*4+2] += a.z*tv; acc[q*4+3] += a.w*tv;
        }
    }
    #pragma unroll
    for (int i = 0; i < 32; ++i) out2[(b*32+i)*4096 + p] = acc[i];
}

// ---------------------------------------------------------------------------
// J) spatial attention, flash-style, j-split 4x for occupancy.
//    Unit-norm rows => max score == 1 => plain exp, merge = sum.
//    block=(64 i)x(4 j-slices); grid=(it, b, chunk); each chunk does 4 of the
//    16 j-tiles.  Unnormalized (acc,l) partials to global; mrg_k finishes.
// ---------------------------------------------------------------------------
__global__ __launch_bounds__(256) void flash_k(const float* __restrict__ tT, const float* __restrict__ rn2,
                                               float* __restrict__ partA, float* __restrict__ partL){
    __shared__ float kv[4*64*36];          // tiles; reused as [256][36] for merge
    int it = blockIdx.x, b = blockIdx.y, chunk = blockIdx.z, t = threadIdx.x;
    int lane = t & 63, slice = t >> 6;
    int i = it*64 + lane;
    float q[32];
    const float* qp = tT + (b*4096 + i)*32;
    #pragma unroll
    for (int qq = 0; qq < 8; ++qq){
        float4 v = *(const float4*)&qp[qq*4];
        q[qq*4] = v.x; q[qq*4+1] = v.y; q[qq*4+2] = v.z; q[qq*4+3] = v.w;
    }
    float rni = rn2[b*4096 + i];
    float acc[32] = {};
    float l = 0.f;
    for (int jt = chunk*4; jt < chunk*4 + 4; ++jt){
        __syncthreads();
        for (int idx = t; idx < 9216; idx += 256){
            int c = idx % 36;
            if (c < 33){
                int rr = idx / 36;
                int jj = rr & 63, sj = rr >> 6;
                int jg = sj*1024 + jt*64 + jj;
                kv[idx] = (c < 32) ? tT[(b*4096 + jg)*32 + c] : rn2[b*4096 + jg];
            }
        }
        __syncthreads();
        const float* kb = &kv[slice*64*36];
        for (int jj = 0; jj < 64; ++jj){
            const float* kr = kb + jj*36;
            float4 v[8];
            #pragma unroll
            for (int qq = 0; qq < 8; ++qq) v[qq] = *(const float4*)&kr[qq*4];
            float s = 0.f;
            #pragma unroll
            for (int qq = 0; qq < 8; ++qq)
                s += q[qq*4]*v[qq].x + q[qq*4+1]*v[qq].y + q[qq*4+2]*v[qq].z + q[qq*4+3]*v[qq].w;
            float e = __expf(s * rni * kr[32]);
            l += e;
            #pragma unroll
            for (int qq = 0; qq < 8; ++qq){
                acc[qq*4]   += e*v[qq].x; acc[qq*4+1] += e*v[qq].y;
                acc[qq*4+2] += e*v[qq].z; acc[qq*4+3] += e*v[qq].w;
            }
        }
    }
    __syncthreads();
    float* pr = &kv[t*36];
    #pragma unroll
    for (int cc = 0; cc < 32; ++cc) pr[cc] = acc[cc];
    pr[32] = l;
    __syncthreads();
    {
        int i2 = t & 63, g = t >> 6, ccg = g*8;
        float ltot = 0.f;
        #pragma unroll
        for (int s = 0; s < 4; ++s) ltot += kv[(s*64 + i2)*36 + 32];
        float o[8] = {};
        #pragma unroll
        for (int s = 0; s < 4; ++s){
            const float* rr = &kv[(s*64 + i2)*36 + ccg];
            #pragma unroll
            for (int c = 0; c < 8; ++c) o[c] += rr[c];
        }
        float* op = partA + (((b*4 + chunk)*4096) + it*64 + i2)*32 + ccg;
        #pragma unroll
        for (int c = 0; c < 8; ++c) op[c] = o[c];
        if (g == 0) partL[(b*4 + chunk)*4096 + it*64 + i2] = ltot;
    }
}

// ---------------------------------------------------------------------------
// J2) merge the 4 j-chunks: out3T = (sum_c partA) / (sum_c partL)
// ---------------------------------------------------------------------------
__global__ __launch_bounds__(256) void mrg_k(const float* __restrict__ partA, const float* __restrict__ partL,
                                             float* __restrict__ out3T){
    int it = blockIdx.x, b = blockIdx.y, t = threadIdx.x;
    int r = t >> 2, g = t & 3;       // 64 rows x 4 channel-groups
    int i = it*64 + r;
    float l = 0.f;
    #pragma unroll
    for (int c = 0; c < 4; ++c) l += partL[(b*4 + c)*4096 + i];
    float inv = 1.f / l;
    float o[8] = {};
    #pragma unroll
    for (int c = 0; c < 4; ++c){
        const float* pa = partA + ((b*4 + c)*4096 + i)*32 + g*8;
        #pragma unroll
        for (int k = 0; k < 8; ++k) o[k] += pa[k];
    }
    float* op = out3T + (b*4096 + i)*32 + g*8;
    #pragma unroll
    for (int k = 0; k < 8; ++k) op[k] = o[k]*inv;
}

// ---------------------------------------------------------------------------
// K) out5 = w3 @ concat(out2,out3) + b3 + t
// ---------------------------------------------------------------------------
__global__ __launch_bounds__(256) void out5_k(const float* __restrict__ out2, const float* __restrict__ out3T,
                                              const float* __restrict__ tbuf, const float* __restrict__ w3,
                                              const float* __restrict__ b3, float* __restrict__ out5){
    __shared__ float w3T[64*32];
    int pt = blockIdx.x, b = blockIdx.y, t = threadIdx.x;
    for (int i = t; i < 2048; i += 256){
        int j = i >> 5, cc = i & 31;
        w3T[i] = w3[cc*64 + j];
    }
    __syncthreads();
    int p = pt*256 + t;
    float acc[32];
    #pragma unroll
    for (int cc = 0; cc < 32; ++cc) acc[cc] = b3[cc] + tbuf[(b*32+cc)*4096 + p];
    for (int j = 0; j < 32; ++j){
        float v = out2[(b*32+j)*4096 + p];
        #pragma unroll
        for (int q = 0; q < 8; ++q){
            float4 a = *(const float4*)&w3T[j*32 + q*4];
            acc[q*4] += a.x*v; acc[q*4+1] += a.y*v; acc[q*4+2] += a.z*v; acc[q*4+3] += a.w*v;
        }
    }
    const float* o3 = out3T + (b*4096 + p)*32;
    float v3[32];
    #pragma unroll
    for (int q = 0; q < 8; ++q){
        float4 v = *(const float4*)&o3[q*4];
        v3[q*4]=v.x; v3[q*4+1]=v.y; v3[q*4+2]=v.z; v3[q*4+3]=v.w;
    }
    #pragma unroll
    for (int j = 0; j < 32; ++j){
        float v = v3[j];
        #pragma unroll
        for (int q = 0; q < 8; ++q){
            float4 a = *(const float4*)&w3T[(32+j)*32 + q*4];
            acc[q*4] += a.x*v; acc[q*4+1] += a.y*v; acc[q*4+2] += a.z*v; acc[q*4+3] += a.w*v;
        }
    }
    #pragma unroll
    for (int cc = 0; cc < 32; ++cc) out5[(b*32+cc)*4096 + p] = acc[cc];
}

// ---------------------------------------------------------------------------
// L) out = w4 @ out5 + b4  (fp32 store)
// ---------------------------------------------------------------------------
__global__ __launch_bounds__(256) void final_k(const float* __restrict__ out5, const float* __restrict__ w4,
                                               const float* __restrict__ b4, float* __restrict__ out){
    __shared__ float w4T[32*64];
    int pt = blockIdx.x, cog = blockIdx.y, b = blockIdx.z, t = threadIdx.x;
    for (int i = t; i < 2048; i += 256){
        int cc = i >> 6, co = i & 63;
        w4T[i] = w4[(cog*64+co)*32 + cc];
    }
    __syncthreads();
    int p = pt*256 + t;
    float acc[64];
    #pragma unroll
    for (int co = 0; co < 64; ++co) acc[co] = b4[cog*64+co];
    for (int cc = 0; cc < 32; ++cc){
        float v = out5[(b*32+cc)*4096 + p];
        #pragma unroll
        for (int q = 0; q < 16; ++q){
            float4 a = *(const float4*)&w4T[cc*64 + q*4];
            acc[q*4] += a.x*v; acc[q*4+1] += a.y*v; acc[q*4+2] += a.z*v; acc[q*4+3] += a.w*v;
        }
    }
    #pragma unroll
    for (int co = 0; co < 64; ++co)
        out[(b*256 + cog*64 + co)*4096 + p] = acc[co];
}

// ---------------------------------------------------------------------------
// Workspace layout (bytes), peak ~19.0 MB (same as round 4):
//   [0,        8388608)  out1 (bf16)  live: sepconv..proj; then gram part +
//                        flash partA (8.39 MB, exact fit)
//   [8388608, 16777216)  y0   (bf16)  live: conv..sepconv; then attn fp32 rgn
//   [16777216,19136512)  wT   (fp32)  live: wtrans..conv3x3; then out5
//   partL lives in the out5 slot (dead until out5_k, which runs after mrg_k)
// ---------------------------------------------------------------------------
extern "C" void kernel_launch(void* const* d_in, const int* in_sizes, int n_in,
                              void* d_out, int out_size, void* d_ws, size_t ws_size,
                              hipStream_t stream) {
    const float* x      = (const float*)d_in[0];
    const float* w_conv = (const float*)d_in[1];
    const float* b_conv = (const float*)d_in[2];
    const float* w01 = (const float*)d_in[3];  const float* b01 = (const float*)d_in[4];
    const float* w02 = (const float*)d_in[5];  const float* b02 = (const float*)d_in[6];
    const float* w11 = (const float*)d_in[7];  const float* b11 = (const float*)d_in[8];
    const float* w12 = (const float*)d_in[9];  const float* b12 = (const float*)d_in[10];
    const float* w21 = (const float*)d_in[11]; const float* b21 = (const float*)d_in[12];
    const float* w22 = (const float*)d_in[13]; const float* b22 = (const float*)d_in[14];
    const float* w_proj = (const float*)d_in[15]; const float* b_proj = (const float*)d_in[16];
    const float* w3 = (const float*)d_in[17]; const float* b3 = (const float*)d_in[18];
    const float* w4 = (const float*)d_in[19]; const float* b4 = (const float*)d_in[20];

    char* wsb = (char*)d_ws;
    bf16*  out1 = (bf16*)wsb;                       // 4,194,304 bf16
    bf16*  y0   = (bf16*)(wsb + 8388608);           // 4,194,304 bf16
    float* wT   = (float*)(wsb + 16777216);         // 589,824 f
    float* f    = (float*)d_ws;
    float* part   = f + 0;         // 131,072 f  (gram partials; dead after attn1)
    float* partA  = f + 0;         // 2,097,152 f (flash partials; after attn1)
    float* tbuf   = f + 2097152;   // byte  8,388,608 (overlays dead y0)
    float* tT     = f + 2621440;   // byte 10,485,760
    float* out2   = f + 3145728;   // byte 12,582,912
    float* out3T  = f + 3670016;   // byte 14,680,064
    float* out5   = f + 4194304;   // byte 16,777,216 (wT dead by then)
    float* partL  = f + 4194304;   // 65,536 f in out5 slot (dead until out5_k)
    float* rn1    = f + 4718592;   // byte 18,874,368
    float* attn1T = f + 4722816;
    float* rn2    = f + 4726912;   // ends at byte 18,973,184

    wtrans_k<<<dim3(2304), 256, 0, stream>>>(w_conv, wT);
    conv3x3_k<<<dim3(4, 64, 4), 256, 0, stream>>>(x, wT, b_conv, y0);
    sepconv_k<<<dim3(1024), 256, 0, stream>>>(y0, w01, b01, w02, b02,
                                              w11, b11, w12, b12,
                                              w21, b21, w22, b22, out1);
    proj_k<<<dim3(16, 4), 256, 0, stream>>>(out1, w_proj, b_proj, tbuf, tT, rn2);
    rn1_k<<<dim3(128), 256, 0, stream>>>(tbuf, rn1);
    gram2_k<<<dim3(32, 4), 256, 0, stream>>>(tbuf, part);
    attn1_k<<<dim3(32, 4), 64, 0, stream>>>(part, rn1, attn1T);
    out2_k<<<dim3(16, 4), 256, 0, stream>>>(tbuf, attn1T, out2);
    flash_k<<<dim3(64, 4, 4), 256, 0, stream>>>(tT, rn2, partA, partL);
    mrg_k<<<dim3(64, 4), 256, 0, stream>>>(partA, partL, out3T);
    out5_k<<<dim3(16, 4), 256, 0, stream>>>(out2, out3T, tbuf, w3, b3, out5);
    final_k<<<dim3(16, 4, 4), 256, 0, stream>>>(out5, w4, b4, (float*)d_out);
}

// Round 7
// 570.701 us; speedup vs baseline: 3.2743x; 1.6275x over previous
//
#include <hip/hip_runtime.h>
#include <hip/hip_bf16.h>

typedef __hip_bfloat16 bf16;
typedef short s16;
typedef __attribute__((ext_vector_type(4))) short s16x4;
typedef __attribute__((ext_vector_type(8))) short s16x8;
typedef __attribute__((ext_vector_type(4))) float f32x4;

// bf16 bit helpers (avoid struct punning entirely)
__device__ __forceinline__ s16 f2b(float f){
    unsigned u = __float_as_uint(f);
    unsigned r = (u + 0x7FFFu + ((u >> 16) & 1u)) >> 16;
    return (s16)r;
}

// NOTE: ALL harness inputs and the output are fp32. Internal intermediates:
// xcl/wpk are raw-bf16-bit short arrays (vector-loaded), y0/out1 are bf16.

// ---------------------------------------------------------------------------
// A1) x (fp32 NCHW) -> xcl (bf16-bits channels-last [b][h][w][ci])
// ---------------------------------------------------------------------------
__global__ __launch_bounds__(256) void xtrans_k(const float* __restrict__ x, s16* __restrict__ xcl){
    __shared__ s16 lb[64][258];              // stride 258 shorts -> conflict-free
    int h = blockIdx.x, b = blockIdx.y, t = threadIdx.x;
    for (int i = t; i < 16384; i += 256){
        int ci = i >> 6, w = i & 63;
        lb[w][ci] = f2b(x[((b*256 + ci)*64 + h)*64 + w]);
    }
    __syncthreads();
    for (int i = t; i < 16384; i += 256){
        int w = i >> 8, ci = i & 255;
        xcl[(b*4096 + h*64 + w)*256 + ci] = lb[w][ci];
    }
}

// ---------------------------------------------------------------------------
// A2) w_conv (fp32 [co][ci][3][3]) -> wpk (bf16-bits [cc8][tap9][co256][ci32])
// ---------------------------------------------------------------------------
__global__ __launch_bounds__(256) void wpack_k(const float* __restrict__ w, s16* __restrict__ wpk){
    int idx = blockIdx.x*256 + threadIdx.x;      // < 589824
    int cil = idx & 31;
    int r   = idx >> 5;
    int co  = r & 255;
    int r2  = r >> 8;
    int tap = r2 % 9, cc = r2 / 9;
    wpk[idx] = f2b(w[(co*256 + cc*32 + cil)*9 + tap]);
}

// ---------------------------------------------------------------------------
// B) 3x3 conv 256->256 as MFMA implicit GEMM.
//    Block tile: M=128 spatial (2 h-rows x 64 w) x N=64 co; K = 8 chunks x
//    (32 ci x 9 taps).  v_mfma_f32_16x16x32_bf16; per wave 2x4 acc tiles.
//    A and B frags use identical (lane-group,elem)->ci maps, so any within-
//    lane k-permutation cancels; C/D mapping is the HW-verified
//    col=lane&15, row=(lane>>4)*4+reg.
//    ALL vector accesses are short-element ext-vectors (alias-clean).
// ---------------------------------------------------------------------------
__global__ __launch_bounds__(256) void conv3x3m_k(const s16* __restrict__ xcl,
        const s16* __restrict__ wpk, const float* __restrict__ bias,
        bf16* __restrict__ y0){
    __shared__ alignas(16) s16 smem[30240];      // 60.5 KB
    s16* xls = smem;                             // [4 rows][66 w][36 ci-pad]
    s16* wls = smem + 9504;                      // [9 tap][64 co][36 ci-pad]
    const int sp = blockIdx.x, cog = blockIdx.y;
    const int b = sp >> 5, h0 = (sp & 31)*2;
    const int t = threadIdx.x;
    const int wv = t >> 6, lane = t & 63;
    const int lm = lane & 15, g = lane >> 4;

    f32x4 acc[2][4];
    #pragma unroll
    for (int mi = 0; mi < 2; ++mi)
        #pragma unroll
        for (int ni = 0; ni < 4; ++ni) acc[mi][ni] = (f32x4){0.f,0.f,0.f,0.f};

    for (int cc = 0; cc < 8; ++cc){
        __syncthreads();
        // stage x: rows h0-1..h0+2, w=-1..64, 32 ci (granules of 8 ci = 16B)
        for (int i = t; i < 1056; i += 256){
            int g8 = i & 3, wi = (i>>2) % 66, r = (i>>2) / 66;
            int h = h0 - 1 + r, w = wi - 1;
            s16x8 v = {0,0,0,0,0,0,0,0};
            if (h >= 0 && h < 64 && w >= 0 && w < 64)
                v = *(const s16x8*)&xcl[(b*4096 + h*64 + w)*256 + cc*32 + g8*8];
            s16* d = &xls[(r*66 + wi)*36 + g8*8];
            *(s16x4*)d       = __builtin_shufflevector(v, v, 0,1,2,3);
            *(s16x4*)(d + 4) = __builtin_shufflevector(v, v, 4,5,6,7);
        }
        // stage w: 9 taps x 64 co x 32 ci
        for (int i = t; i < 2304; i += 256){
            int g8 = i & 3, co = (i>>2) & 63, tap = i >> 8;
            s16x8 v = *(const s16x8*)&wpk[((cc*9 + tap)*256 + cog*64 + co)*32 + g8*8];
            s16* d = &wls[(tap*64 + co)*36 + g8*8];
            *(s16x4*)d       = __builtin_shufflevector(v, v, 0,1,2,3);
            *(s16x4*)(d + 4) = __builtin_shufflevector(v, v, 4,5,6,7);
        }
        __syncthreads();
        #pragma unroll
        for (int tap = 0; tap < 9; ++tap){
            const int kh = tap/3, kw = tap%3;
            s16x8 bfr[4], afr[2];
            #pragma unroll
            for (int ni = 0; ni < 4; ++ni){
                const s16* p = &wls[(tap*64 + ni*16 + lm)*36 + g*8];
                s16x4 lo = *(const s16x4*)p;
                s16x4 hi = *(const s16x4*)(p + 4);
                bfr[ni] = __builtin_shufflevector(lo, hi, 0,1,2,3,4,5,6,7);
            }
            #pragma unroll
            for (int mi = 0; mi < 2; ++mi){
                int m = (wv*2 + mi)*16 + lm;
                int hr = m >> 6, ww = m & 63;
                const s16* p = &xls[((hr + kh)*66 + (ww + kw))*36 + g*8];
                s16x4 lo = *(const s16x4*)p;
                s16x4 hi = *(const s16x4*)(p + 4);
                afr[mi] = __builtin_shufflevector(lo, hi, 0,1,2,3,4,5,6,7);
            }
            #pragma unroll
            for (int mi = 0; mi < 2; ++mi)
                #pragma unroll
                for (int ni = 0; ni < 4; ++ni)
                    acc[mi][ni] = __builtin_amdgcn_mfma_f32_16x16x32_bf16(
                        afr[mi], bfr[ni], acc[mi][ni], 0, 0, 0);
        }
    }
    // epilogue: acc -> LDS [co][m] -> coalesced bf16 stores (+bias)
    __syncthreads();
    float* ot = (float*)smem;                    // [64 co][132 m-pad]
    #pragma unroll
    for (int mi = 0; mi < 2; ++mi)
        #pragma unroll
        for (int ni = 0; ni < 4; ++ni)
            #pragma unroll
            for (int r = 0; r < 4; ++r){
                int m  = (wv*2 + mi)*16 + g*4 + r;   // row=(lane>>4)*4+reg (verified)
                int co = ni*16 + lm;                 // col=lane&15 (verified)
                ot[co*132 + m] = acc[mi][ni][r];
            }
    __syncthreads();
    for (int i = t; i < 8192; i += 256){
        int co = i >> 7, m = i & 127;
        float v = ot[co*132 + m] + bias[cog*64 + co];
        y0[((b*256 + cog*64 + co)*64 + h0 + (m>>6))*64 + (m & 63)] = __float2bfloat16(v);
    }
}

// ---------------------------------------------------------------------------
// C) fused separable depthwise (7/11/21) + residual.  One block per (b,c)
// ---------------------------------------------------------------------------
template<int K>
__device__ __forceinline__ void sep_branch(float (&pl)[64][64], float (&hp)[64][64],
                                           int c, int t,
                                           const float* __restrict__ wh, const float* __restrict__ bh,
                                           const float* __restrict__ wv, const float* __restrict__ bv,
                                           float* acc){
    constexpr int P = K/2;
    float wk[K];
    #pragma unroll
    for (int j = 0; j < K; ++j) wk[j] = wh[c*K + j];
    float bhv = bh[c];
    __syncthreads();
    #pragma unroll
    for (int k = 0; k < 16; ++k){
        int h = k*4 + (t >> 6), w = t & 63;
        float s = bhv;
        #pragma unroll
        for (int j = 0; j < K; ++j){
            int ww = w + j - P;
            if (ww >= 0 && ww < 64) s += pl[h][ww]*wk[j];
        }
        hp[h][w] = s;
    }
    float vk[K];
    #pragma unroll
    for (int j = 0; j < K; ++j) vk[j] = wv[c*K + j];
    float bvv = bv[c];
    __syncthreads();
    #pragma unroll
    for (int k = 0; k < 16; ++k){
        int h = k*4 + (t >> 6), w = t & 63;
        float s = bvv;
        #pragma unroll
        for (int j = 0; j < K; ++j){
            int hh = h + j - P;
            if (hh >= 0 && hh < 64) s += hp[hh][w]*vk[j];
        }
        acc[k] += s;
    }
}

__global__ __launch_bounds__(256) void sepconv_k(const bf16* __restrict__ y0,
        const float* __restrict__ w01, const float* __restrict__ b01,
        const float* __restrict__ w02, const float* __restrict__ b02,
        const float* __restrict__ w11, const float* __restrict__ b11,
        const float* __restrict__ w12, const float* __restrict__ b12,
        const float* __restrict__ w21, const float* __restrict__ b21,
        const float* __restrict__ w22, const float* __restrict__ b22,
        bf16* __restrict__ out1){
    __shared__ float pl[64][64];
    __shared__ float hp[64][64];
    int bc = blockIdx.x;             // b*256 + c
    int c = bc & 255;
    int t = threadIdx.x;
    const bf16* src = y0 + bc*4096;
    for (int i = t; i < 4096; i += 256) pl[i>>6][i&63] = __bfloat162float(src[i]);
    float acc[16];
    #pragma unroll
    for (int k = 0; k < 16; ++k) acc[k] = 0.f;
    sep_branch<7 >(pl, hp, c, t, w01, b01, w02, b02, acc);
    sep_branch<11>(pl, hp, c, t, w11, b11, w12, b12, acc);
    sep_branch<21>(pl, hp, c, t, w21, b21, w22, b22, acc);
    bf16* dst = out1 + bc*4096;
    #pragma unroll
    for (int k = 0; k < 16; ++k){
        int h = k*4 + (t >> 6), w = t & 63;
        dst[h*64 + w] = __float2bfloat16(acc[k] + pl[h][w]);
    }
}

// ---------------------------------------------------------------------------
// E) 1x1 projection 256->32: t[b][cc][p], tT[b][p][cc], rn2[b][p]
// ---------------------------------------------------------------------------
__global__ __launch_bounds__(256) void proj_k(const bf16* __restrict__ out1, const float* __restrict__ wp,
                                              const float* __restrict__ bp, float* __restrict__ tbuf,
                                              float* __restrict__ tT, float* __restrict__ rn2){
    __shared__ float wl[256][32];
    int pt = blockIdx.x, b = blockIdx.y, t = threadIdx.x;
    for (int i = t; i < 8192; i += 256){
        int ci = i >> 5, cc = i & 31;
        wl[ci][cc] = wp[cc*256 + ci];
    }
    __syncthreads();
    int p = pt*256 + t;
    float acc[32] = {};
    const bf16* xb = out1 + b*1048576;
    for (int ci = 0; ci < 256; ++ci){
        float v = __bfloat162float(xb[ci*4096 + p]);
        #pragma unroll
        for (int q = 0; q < 8; ++q){
            float4 w4 = *(const float4*)&wl[ci][q*4];
            acc[q*4+0] += w4.x*v; acc[q*4+1] += w4.y*v; acc[q*4+2] += w4.z*v; acc[q*4+3] += w4.w*v;
        }
    }
    float ss = 0.f;
    #pragma unroll
    for (int cc = 0; cc < 32; ++cc){ acc[cc] += bp[cc]; ss += acc[cc]*acc[cc]; }
    rn2[b*4096 + p] = 1.f / fmaxf(sqrtf(ss), 1e-12f);
    #pragma unroll
    for (int cc = 0; cc < 32; ++cc) tbuf[(b*32+cc)*4096 + p] = acc[cc];
    float* tp = tT + (b*4096 + p)*32;
    #pragma unroll
    for (int q = 0; q < 8; ++q){
        float4 o; o.x = acc[q*4]; o.y = acc[q*4+1]; o.z = acc[q*4+2]; o.w = acc[q*4+3];
        *(float4*)&tp[q*4] = o;
    }
}

// ---------------------------------------------------------------------------
// F) row norms of t over p (128 rows)
// ---------------------------------------------------------------------------
__global__ __launch_bounds__(256) void rn1_k(const float* __restrict__ tbuf, float* __restrict__ rn1){
    int row = blockIdx.x;
    int t = threadIdx.x;
    float ss = 0.f;
    const float* r = tbuf + row*4096;
    for (int p = t; p < 4096; p += 256){ float v = r[p]; ss += v*v; }
    #pragma unroll
    for (int o = 32; o > 0; o >>= 1) ss += __shfl_down(ss, o, 64);
    __shared__ float red[4];
    if ((t & 63) == 0) red[t >> 6] = ss;
    __syncthreads();
    if (t == 0){
        float tot = red[0]+red[1]+red[2]+red[3];
        rn1[row] = 1.f / fmaxf(sqrtf(tot), 1e-12f);
    }
}

// ---------------------------------------------------------------------------
// G1) Gram partials, p-sliced, conflict-free transposed LDS tile
// ---------------------------------------------------------------------------
__global__ __launch_bounds__(256) void gram2_k(const float* __restrict__ tbuf, float* __restrict__ part){
    __shared__ float tl[128][33];
    int ps = blockIdx.x, b = blockIdx.y, t = threadIdx.x;
    for (int idx = t; idx < 4096; idx += 256){
        int cc = idx >> 7, pp = idx & 127;
        tl[pp][cc] = tbuf[(b*32+cc)*4096 + ps*128 + pp];
    }
    __syncthreads();
    #pragma unroll
    for (int k = 0; k < 4; ++k){
        int pair = k*256 + t;
        int i = pair >> 5, j = pair & 31;
        float s = 0.f;
        #pragma unroll 4
        for (int pp = 0; pp < 128; ++pp) s += tl[pp][i]*tl[pp][j];
        part[(b*32+ps)*1024 + pair] = s;
    }
}

// ---------------------------------------------------------------------------
// G2) attn1 softmax: reduce 32 slice-partials, then exp/sum; store transposed
// ---------------------------------------------------------------------------
__global__ __launch_bounds__(64) void attn1_k(const float* __restrict__ part, const float* __restrict__ rn1,
                                              float* __restrict__ attn1T){
    int i = blockIdx.x, b = blockIdx.y, j = threadIdx.x;
    float e = 0.f;
    if (j < 32){
        float g = 0.f;
        #pragma unroll 8
        for (int ps = 0; ps < 32; ++ps) g += part[(b*32+ps)*1024 + i*32 + j];
        e = __expf(rn1[b*32+i]*rn1[b*32+j]*g);
    }
    float sum = e;
    #pragma unroll
    for (int o = 32; o > 0; o >>= 1) sum += __shfl_xor(sum, o, 64);
    if (j < 32) attn1T[b*1024 + j*32 + i] = e / sum;
}

// ---------------------------------------------------------------------------
// H) out2 = attn1 @ t
// ---------------------------------------------------------------------------
__global__ __launch_bounds__(256) void out2_k(const float* __restrict__ tbuf, const float* __restrict__ attn1T,
                                              float* __restrict__ out2){
    __shared__ float al[1024];
    int pt = blockIdx.x, b = blockIdx.y, t = threadIdx.x;
    for (int i = t; i < 1024; i += 256) al[i] = attn1T[b*1024 + i];
    __syncthreads();
    int p = pt*256 + t;
    float acc[32] = {};
    for (int j = 0; j < 32; ++j){
        float tv = tbuf[(b*32+j)*4096 + p];
        #pragma unroll
        for (int q = 0; q < 8; ++q){
            float4 a = *(const float4*)&al[j*32 + q*4];
            acc[q*4+0] += a.x*tv; acc[q*4+1] += a.y*tv; acc[q*4+2] += a.z*tv; acc[q*4+3] += a.w*tv;
        }
    }
    #pragma unroll
    for (int i = 0; i < 32; ++i) out2[(b*32+i)*4096 + p] = acc[i];
}

// ---------------------------------------------------------------------------
// J) spatial attention, flash-style, j-split 4x; partials to global
// ---------------------------------------------------------------------------
__global__ __launch_bounds__(256) void flash_k(const float* __restrict__ tT, const float* __restrict__ rn2,
                                               float* __restrict__ partA, float* __restrict__ partL){
    __shared__ float kv[4*64*36];
    int it = blockIdx.x, b = blockIdx.y, chunk = blockIdx.z, t = threadIdx.x;
    int lane = t & 63, slice = t >> 6;
    int i = it*64 + lane;
    float q[32];
    const float* qp = tT + (b*4096 + i)*32;
    #pragma unroll
    for (int qq = 0; qq < 8; ++qq){
        float4 v = *(const float4*)&qp[qq*4];
        q[qq*4] = v.x; q[qq*4+1] = v.y; q[qq*4+2] = v.z; q[qq*4+3] = v.w;
    }
    float rni = rn2[b*4096 + i];
    float acc[32] = {};
    float l = 0.f;
    for (int jt = chunk*4; jt < chunk*4 + 4; ++jt){
        __syncthreads();
        for (int idx = t; idx < 9216; idx += 256){
            int c = idx % 36;
            if (c < 33){
                int rr = idx / 36;
                int jj = rr & 63, sj = rr >> 6;
                int jg = sj*1024 + jt*64 + jj;
                kv[idx] = (c < 32) ? tT[(b*4096 + jg)*32 + c] : rn2[b*4096 + jg];
            }
        }
        __syncthreads();
        const float* kb = &kv[slice*64*36];
        for (int jj = 0; jj < 64; ++jj){
            const float* kr = kb + jj*36;
            float4 v[8];
            #pragma unroll
            for (int qq = 0; qq < 8; ++qq) v[qq] = *(const float4*)&kr[qq*4];
            float s = 0.f;
            #pragma unroll
            for (int qq = 0; qq < 8; ++qq)
                s += q[qq*4]*v[qq].x + q[qq*4+1]*v[qq].y + q[qq*4+2]*v[qq].z + q[qq*4+3]*v[qq].w;
            float e = __expf(s * rni * kr[32]);
            l += e;
            #pragma unroll
            for (int qq = 0; qq < 8; ++qq){
                acc[qq*4]   += e*v[qq].x; acc[qq*4+1] += e*v[qq].y;
                acc[qq*4+2] += e*v[qq].z; acc[qq*4+3] += e*v[qq].w;
            }
        }
    }
    __syncthreads();
    float* pr = &kv[t*36];
    #pragma unroll
    for (int cc = 0; cc < 32; ++cc) pr[cc] = acc[cc];
    pr[32] = l;
    __syncthreads();
    {
        int i2 = t & 63, g = t >> 6, ccg = g*8;
        float ltot = 0.f;
        #pragma unroll
        for (int s = 0; s < 4; ++s) ltot += kv[(s*64 + i2)*36 + 32];
        float o[8] = {};
        #pragma unroll
        for (int s = 0; s < 4; ++s){
            const float* rr = &kv[(s*64 + i2)*36 + ccg];
            #pragma unroll
            for (int c = 0; c < 8; ++c) o[c] += rr[c];
        }
        float* op = partA + (((b*4 + chunk)*4096) + it*64 + i2)*32 + ccg;
        #pragma unroll
        for (int c = 0; c < 8; ++c) op[c] = o[c];
        if (g == 0) partL[(b*4 + chunk)*4096 + it*64 + i2] = ltot;
    }
}

// ---------------------------------------------------------------------------
// J2) merge the 4 j-chunks
// ---------------------------------------------------------------------------
__global__ __launch_bounds__(256) void mrg_k(const float* __restrict__ partA, const float* __restrict__ partL,
                                             float* __restrict__ out3T){
    int it = blockIdx.x, b = blockIdx.y, t = threadIdx.x;
    int r = t >> 2, g = t & 3;
    int i = it*64 + r;
    float l = 0.f;
    #pragma unroll
    for (int c = 0; c < 4; ++c) l += partL[(b*4 + c)*4096 + i];
    float inv = 1.f / l;
    float o[8] = {};
    #pragma unroll
    for (int c = 0; c < 4; ++c){
        const float* pa = partA + ((b*4 + c)*4096 + i)*32 + g*8;
        #pragma unroll
        for (int k = 0; k < 8; ++k) o[k] += pa[k];
    }
    float* op = out3T + (b*4096 + i)*32 + g*8;
    #pragma unroll
    for (int k = 0; k < 8; ++k) op[k] = o[k]*inv;
}

// ---------------------------------------------------------------------------
// K) out5 = w3 @ concat(out2,out3) + b3 + t
// ---------------------------------------------------------------------------
__global__ __launch_bounds__(256) void out5_k(const float* __restrict__ out2, const float* __restrict__ out3T,
                                              const float* __restrict__ tbuf, const float* __restrict__ w3,
                                              const float* __restrict__ b3, float* __restrict__ out5){
    __shared__ float w3T[64*32];
    int pt = blockIdx.x, b = blockIdx.y, t = threadIdx.x;
    for (int i = t; i < 2048; i += 256){
        int j = i >> 5, cc = i & 31;
        w3T[i] = w3[cc*64 + j];
    }
    __syncthreads();
    int p = pt*256 + t;
    float acc[32];
    #pragma unroll
    for (int cc = 0; cc < 32; ++cc) acc[cc] = b3[cc] + tbuf[(b*32+cc)*4096 + p];
    for (int j = 0; j < 32; ++j){
        float v = out2[(b*32+j)*4096 + p];
        #pragma unroll
        for (int q = 0; q < 8; ++q){
            float4 a = *(const float4*)&w3T[j*32 + q*4];
            acc[q*4] += a.x*v; acc[q*4+1] += a.y*v; acc[q*4+2] += a.z*v; acc[q*4+3] += a.w*v;
        }
    }
    const float* o3 = out3T + (b*4096 + p)*32;
    float v3[32];
    #pragma unroll
    for (int q = 0; q < 8; ++q){
        float4 v = *(const float4*)&o3[q*4];
        v3[q*4]=v.x; v3[q*4+1]=v.y; v3[q*4+2]=v.z; v3[q*4+3]=v.w;
    }
    #pragma unroll
    for (int j = 0; j < 32; ++j){
        float v = v3[j];
        #pragma unroll
        for (int q = 0; q < 8; ++q){
            float4 a = *(const float4*)&w3T[(32+j)*32 + q*4];
            acc[q*4] += a.x*v; acc[q*4+1] += a.y*v; acc[q*4+2] += a.z*v; acc[q*4+3] += a.w*v;
        }
    }
    #pragma unroll
    for (int cc = 0; cc < 32; ++cc) out5[(b*32+cc)*4096 + p] = acc[cc];
}

// ---------------------------------------------------------------------------
// L) out = w4 @ out5 + b4  (fp32 store)
// ---------------------------------------------------------------------------
__global__ __launch_bounds__(256) void final_k(const float* __restrict__ out5, const float* __restrict__ w4,
                                               const float* __restrict__ b4, float* __restrict__ out){
    __shared__ float w4T[32*64];
    int pt = blockIdx.x, cog = blockIdx.y, b = blockIdx.z, t = threadIdx.x;
    for (int i = t; i < 2048; i += 256){
        int cc = i >> 6, co = i & 63;
        w4T[i] = w4[(cog*64+co)*32 + cc];
    }
    __syncthreads();
    int p = pt*256 + t;
    float acc[64];
    #pragma unroll
    for (int co = 0; co < 64; ++co) acc[co] = b4[cog*64+co];
    for (int cc = 0; cc < 32; ++cc){
        float v = out5[(b*32+cc)*4096 + p];
        #pragma unroll
        for (int q = 0; q < 16; ++q){
            float4 a = *(const float4*)&w4T[cc*64 + q*4];
            acc[q*4] += a.x*v; acc[q*4+1] += a.y*v; acc[q*4+2] += a.z*v; acc[q*4+3] += a.w*v;
        }
    }
    #pragma unroll
    for (int co = 0; co < 64; ++co)
        out[(b*256 + cog*64 + co)*4096 + p] = acc[co];
}

// ---------------------------------------------------------------------------
// Workspace layout (bytes), peak ~19.0 MB:
//   [0,        8388608)  xcl (s16 bf16-bits) -> out1 (bf16) after conv
//                        -> gram part / flash partA after proj
//   [8388608, 16777216)  y0 (bf16)  live conv..sepconv; then attn fp32 region
//   [16777216,17956864)  wpk (s16 prepack); then out5/partL region
// ---------------------------------------------------------------------------
extern "C" void kernel_launch(void* const* d_in, const int* in_sizes, int n_in,
                              void* d_out, int out_size, void* d_ws, size_t ws_size,
                              hipStream_t stream) {
    const float* x      = (const float*)d_in[0];
    const float* w_conv = (const float*)d_in[1];
    const float* b_conv = (const float*)d_in[2];
    const float* w01 = (const float*)d_in[3];  const float* b01 = (const float*)d_in[4];
    const float* w02 = (const float*)d_in[5];  const float* b02 = (const float*)d_in[6];
    const float* w11 = (const float*)d_in[7];  const float* b11 = (const float*)d_in[8];
    const float* w12 = (const float*)d_in[9];  const float* b12 = (const float*)d_in[10];
    const float* w21 = (const float*)d_in[11]; const float* b21 = (const float*)d_in[12];
    const float* w22 = (const float*)d_in[13]; const float* b22 = (const float*)d_in[14];
    const float* w_proj = (const float*)d_in[15]; const float* b_proj = (const float*)d_in[16];
    const float* w3 = (const float*)d_in[17]; const float* b3 = (const float*)d_in[18];
    const float* w4 = (const float*)d_in[19]; const float* b4 = (const float*)d_in[20];

    char* wsb = (char*)d_ws;
    s16*   xcl  = (s16*)wsb;                        // 4,194,304 s16 (conv input)
    bf16*  out1 = (bf16*)wsb;                       // same slot, after conv
    bf16*  y0   = (bf16*)(wsb + 8388608);           // 4,194,304 bf16
    s16*   wpk  = (s16*)(wsb + 16777216);           // 589,824 s16
    float* f    = (float*)d_ws;
    float* part   = f + 0;         // gram partials (out1 dead after proj)
    float* partA  = f + 0;         // flash partials (same slot)
    float* tbuf   = f + 2097152;   // byte  8,388,608 (overlays dead y0)
    float* tT     = f + 2621440;   // byte 10,485,760
    float* out2   = f + 3145728;   // byte 12,582,912
    float* out3T  = f + 3670016;   // byte 14,680,064
    float* out5   = f + 4194304;   // byte 16,777,216 (wpk dead by then)
    float* partL  = f + 4194304;   // 65,536 f in out5 slot (dead until out5_k)
    float* rn1    = f + 4718592;   // byte 18,874,368
    float* attn1T = f + 4722816;
    float* rn2    = f + 4726912;   // ends at byte 18,973,184

    xtrans_k<<<dim3(64, 4), 256, 0, stream>>>(x, xcl);
    wpack_k<<<dim3(2304), 256, 0, stream>>>(w_conv, wpk);
    conv3x3m_k<<<dim3(128, 4), 256, 0, stream>>>(xcl, wpk, b_conv, y0);
    sepconv_k<<<dim3(1024), 256, 0, stream>>>(y0, w01, b01, w02, b02,
                                              w11, b11, w12, b12,
                                              w21, b21, w22, b22, out1);
    proj_k<<<dim3(16, 4), 256, 0, stream>>>(out1, w_proj, b_proj, tbuf, tT, rn2);
    rn1_k<<<dim3(128), 256, 0, stream>>>(tbuf, rn1);
    gram2_k<<<dim3(32, 4), 256, 0, stream>>>(tbuf, part);
    attn1_k<<<dim3(32, 4), 64, 0, stream>>>(part, rn1, attn1T);
    out2_k<<<dim3(16, 4), 256, 0, stream>>>(tbuf, attn1T, out2);
    flash_k<<<dim3(64, 4, 4), 256, 0, stream>>>(tT, rn2, partA, partL);
    mrg_k<<<dim3(64, 4), 256, 0, stream>>>(partA, partL, out3T);
    out5_k<<<dim3(16, 4), 256, 0, stream>>>(out2, out3T, tbuf, w3, b3, out5);
    final_k<<<dim3(16, 4, 4), 256, 0, stream>>>(out5, w4, b4, (float*)d_out);
}

// Round 8
// 419.334 us; speedup vs baseline: 4.4563x; 1.3610x over previous
//
#include <hip/hip_runtime.h>
#include <hip/hip_bf16.h>

typedef __hip_bfloat16 bf16;
typedef short s16;
typedef __attribute__((ext_vector_type(4))) short s16x4;
typedef __attribute__((ext_vector_type(8))) short s16x8;
typedef __attribute__((ext_vector_type(4))) float f32x4;

__device__ __forceinline__ s16 f2b(float f){
    unsigned u = __float_as_uint(f);
    unsigned r = (u + 0x7FFFu + ((u >> 16) & 1u)) >> 16;
    return (s16)r;
}

// ---------------------------------------------------------------------------
// A1) x (fp32 NCHW) -> xcl (bf16-bits channels-last [b][h][w][ci])
// ---------------------------------------------------------------------------
__global__ __launch_bounds__(256) void xtrans_k(const float* __restrict__ x, s16* __restrict__ xcl){
    __shared__ s16 lb[64][258];
    int h = blockIdx.x, b = blockIdx.y, t = threadIdx.x;
    for (int i = t; i < 16384; i += 256){
        int ci = i >> 6, w = i & 63;
        lb[w][ci] = f2b(x[((b*256 + ci)*64 + h)*64 + w]);
    }
    __syncthreads();
    for (int i = t; i < 16384; i += 256){
        int w = i >> 8, ci = i & 255;
        xcl[(b*4096 + h*64 + w)*256 + ci] = lb[w][ci];
    }
}

// ---------------------------------------------------------------------------
// A2) w_conv (fp32 [co][ci][3][3]) -> wpk (bf16-bits [cc8][tap9][co256][ci32])
// ---------------------------------------------------------------------------
__global__ __launch_bounds__(256) void wpack_k(const float* __restrict__ w, s16* __restrict__ wpk){
    int idx = blockIdx.x*256 + threadIdx.x;      // < 589824
    int cil = idx & 31;
    int r   = idx >> 5;
    int co  = r & 255;
    int r2  = r >> 8;
    int tap = r2 % 9, cc = r2 / 9;
    wpk[idx] = f2b(w[(co*256 + cc*32 + cil)*9 + tap]);
}

// ---------------------------------------------------------------------------
// B) 3x3 conv 256->256 as MFMA implicit GEMM (unchanged from passing R7)
// ---------------------------------------------------------------------------
__global__ __launch_bounds__(256) void conv3x3m_k(const s16* __restrict__ xcl,
        const s16* __restrict__ wpk, const float* __restrict__ bias,
        bf16* __restrict__ y0){
    __shared__ alignas(16) s16 smem[30240];      // 60.5 KB
    s16* xls = smem;                             // [4 rows][66 w][36 ci-pad]
    s16* wls = smem + 9504;                      // [9 tap][64 co][36 ci-pad]
    const int sp = blockIdx.x, cog = blockIdx.y;
    const int b = sp >> 5, h0 = (sp & 31)*2;
    const int t = threadIdx.x;
    const int wv = t >> 6, lane = t & 63;
    const int lm = lane & 15, g = lane >> 4;

    f32x4 acc[2][4];
    #pragma unroll
    for (int mi = 0; mi < 2; ++mi)
        #pragma unroll
        for (int ni = 0; ni < 4; ++ni) acc[mi][ni] = (f32x4){0.f,0.f,0.f,0.f};

    for (int cc = 0; cc < 8; ++cc){
        __syncthreads();
        for (int i = t; i < 1056; i += 256){
            int g8 = i & 3, wi = (i>>2) % 66, r = (i>>2) / 66;
            int h = h0 - 1 + r, w = wi - 1;
            s16x8 v = {0,0,0,0,0,0,0,0};
            if (h >= 0 && h < 64 && w >= 0 && w < 64)
                v = *(const s16x8*)&xcl[(b*4096 + h*64 + w)*256 + cc*32 + g8*8];
            s16* d = &xls[(r*66 + wi)*36 + g8*8];
            *(s16x4*)d       = __builtin_shufflevector(v, v, 0,1,2,3);
            *(s16x4*)(d + 4) = __builtin_shufflevector(v, v, 4,5,6,7);
        }
        for (int i = t; i < 2304; i += 256){
            int g8 = i & 3, co = (i>>2) & 63, tap = i >> 8;
            s16x8 v = *(const s16x8*)&wpk[((cc*9 + tap)*256 + cog*64 + co)*32 + g8*8];
            s16* d = &wls[(tap*64 + co)*36 + g8*8];
            *(s16x4*)d       = __builtin_shufflevector(v, v, 0,1,2,3);
            *(s16x4*)(d + 4) = __builtin_shufflevector(v, v, 4,5,6,7);
        }
        __syncthreads();
        #pragma unroll
        for (int tap = 0; tap < 9; ++tap){
            const int kh = tap/3, kw = tap%3;
            s16x8 bfr[4], afr[2];
            #pragma unroll
            for (int ni = 0; ni < 4; ++ni){
                const s16* p = &wls[(tap*64 + ni*16 + lm)*36 + g*8];
                s16x4 lo = *(const s16x4*)p;
                s16x4 hi = *(const s16x4*)(p + 4);
                bfr[ni] = __builtin_shufflevector(lo, hi, 0,1,2,3,4,5,6,7);
            }
            #pragma unroll
            for (int mi = 0; mi < 2; ++mi){
                int m = (wv*2 + mi)*16 + lm;
                int hr = m >> 6, ww = m & 63;
                const s16* p = &xls[((hr + kh)*66 + (ww + kw))*36 + g*8];
                s16x4 lo = *(const s16x4*)p;
                s16x4 hi = *(const s16x4*)(p + 4);
                afr[mi] = __builtin_shufflevector(lo, hi, 0,1,2,3,4,5,6,7);
            }
            #pragma unroll
            for (int mi = 0; mi < 2; ++mi)
                #pragma unroll
                for (int ni = 0; ni < 4; ++ni)
                    acc[mi][ni] = __builtin_amdgcn_mfma_f32_16x16x32_bf16(
                        afr[mi], bfr[ni], acc[mi][ni], 0, 0, 0);
        }
    }
    __syncthreads();
    float* ot = (float*)smem;                    // [64 co][132 m-pad]
    #pragma unroll
    for (int mi = 0; mi < 2; ++mi)
        #pragma unroll
        for (int ni = 0; ni < 4; ++ni)
            #pragma unroll
            for (int r = 0; r < 4; ++r){
                int m  = (wv*2 + mi)*16 + g*4 + r;
                int co = ni*16 + lm;
                ot[co*132 + m] = acc[mi][ni][r];
            }
    __syncthreads();
    for (int i = t; i < 8192; i += 256){
        int co = i >> 7, m = i & 127;
        float v = ot[co*132 + m] + bias[cog*64 + co];
        y0[((b*256 + cog*64 + co)*64 + h0 + (m>>6))*64 + (m & 63)] = __float2bfloat16(v);
    }
}

// ---------------------------------------------------------------------------
// C) fused separable depthwise (7/11/21) + residual (unchanged)
// ---------------------------------------------------------------------------
template<int K>
__device__ __forceinline__ void sep_branch(float (&pl)[64][64], float (&hp)[64][64],
                                           int c, int t,
                                           const float* __restrict__ wh, const float* __restrict__ bh,
                                           const float* __restrict__ wv, const float* __restrict__ bv,
                                           float* acc){
    constexpr int P = K/2;
    float wk[K];
    #pragma unroll
    for (int j = 0; j < K; ++j) wk[j] = wh[c*K + j];
    float bhv = bh[c];
    __syncthreads();
    #pragma unroll
    for (int k = 0; k < 16; ++k){
        int h = k*4 + (t >> 6), w = t & 63;
        float s = bhv;
        #pragma unroll
        for (int j = 0; j < K; ++j){
            int ww = w + j - P;
            if (ww >= 0 && ww < 64) s += pl[h][ww]*wk[j];
        }
        hp[h][w] = s;
    }
    float vk[K];
    #pragma unroll
    for (int j = 0; j < K; ++j) vk[j] = wv[c*K + j];
    float bvv = bv[c];
    __syncthreads();
    #pragma unroll
    for (int k = 0; k < 16; ++k){
        int h = k*4 + (t >> 6), w = t & 63;
        float s = bvv;
        #pragma unroll
        for (int j = 0; j < K; ++j){
            int hh = h + j - P;
            if (hh >= 0 && hh < 64) s += hp[hh][w]*vk[j];
        }
        acc[k] += s;
    }
}

__global__ __launch_bounds__(256) void sepconv_k(const bf16* __restrict__ y0,
        const float* __restrict__ w01, const float* __restrict__ b01,
        const float* __restrict__ w02, const float* __restrict__ b02,
        const float* __restrict__ w11, const float* __restrict__ b11,
        const float* __restrict__ w12, const float* __restrict__ b12,
        const float* __restrict__ w21, const float* __restrict__ b21,
        const float* __restrict__ w22, const float* __restrict__ b22,
        bf16* __restrict__ out1){
    __shared__ float pl[64][64];
    __shared__ float hp[64][64];
    int bc = blockIdx.x;             // b*256 + c
    int c = bc & 255;
    int t = threadIdx.x;
    const bf16* src = y0 + bc*4096;
    for (int i = t; i < 4096; i += 256) pl[i>>6][i&63] = __bfloat162float(src[i]);
    float acc[16];
    #pragma unroll
    for (int k = 0; k < 16; ++k) acc[k] = 0.f;
    sep_branch<7 >(pl, hp, c, t, w01, b01, w02, b02, acc);
    sep_branch<11>(pl, hp, c, t, w11, b11, w12, b12, acc);
    sep_branch<21>(pl, hp, c, t, w21, b21, w22, b22, acc);
    bf16* dst = out1 + bc*4096;
    #pragma unroll
    for (int k = 0; k < 16; ++k){
        int h = k*4 + (t >> 6), w = t & 63;
        dst[h*64 + w] = __float2bfloat16(acc[k] + pl[h][w]);
    }
}

// ---------------------------------------------------------------------------
// E) 1x1 projection 256->32: t[b][cc][p], tTb (bf16 [b][p][cc]), rn2[b][p]
// ---------------------------------------------------------------------------
__global__ __launch_bounds__(256) void proj_k(const bf16* __restrict__ out1, const float* __restrict__ wp,
                                              const float* __restrict__ bp, float* __restrict__ tbuf,
                                              s16* __restrict__ tTb, float* __restrict__ rn2){
    __shared__ float wl[256][32];
    int pt = blockIdx.x, b = blockIdx.y, t = threadIdx.x;
    for (int i = t; i < 8192; i += 256){
        int ci = i >> 5, cc = i & 31;
        wl[ci][cc] = wp[cc*256 + ci];
    }
    __syncthreads();
    int p = pt*256 + t;
    float acc[32] = {};
    const bf16* xb = out1 + b*1048576;
    for (int ci = 0; ci < 256; ++ci){
        float v = __bfloat162float(xb[ci*4096 + p]);
        #pragma unroll
        for (int q = 0; q < 8; ++q){
            float4 w4 = *(const float4*)&wl[ci][q*4];
            acc[q*4+0] += w4.x*v; acc[q*4+1] += w4.y*v; acc[q*4+2] += w4.z*v; acc[q*4+3] += w4.w*v;
        }
    }
    float ss = 0.f;
    #pragma unroll
    for (int cc = 0; cc < 32; ++cc){ acc[cc] += bp[cc]; ss += acc[cc]*acc[cc]; }
    rn2[b*4096 + p] = 1.f / fmaxf(sqrtf(ss), 1e-12f);
    #pragma unroll
    for (int cc = 0; cc < 32; ++cc) tbuf[(b*32+cc)*4096 + p] = acc[cc];
    s16* tp = tTb + (b*4096 + p)*32;
    #pragma unroll
    for (int q = 0; q < 8; ++q){
        s16x4 o; o[0]=f2b(acc[q*4]); o[1]=f2b(acc[q*4+1]); o[2]=f2b(acc[q*4+2]); o[3]=f2b(acc[q*4+3]);
        *(s16x4*)&tp[q*4] = o;
    }
}

// ---------------------------------------------------------------------------
// F) row norms of t over p (128 rows)
// ---------------------------------------------------------------------------
__global__ __launch_bounds__(256) void rn1_k(const float* __restrict__ tbuf, float* __restrict__ rn1){
    int row = blockIdx.x;
    int t = threadIdx.x;
    float ss = 0.f;
    const float* r = tbuf + row*4096;
    for (int p = t; p < 4096; p += 256){ float v = r[p]; ss += v*v; }
    #pragma unroll
    for (int o = 32; o > 0; o >>= 1) ss += __shfl_down(ss, o, 64);
    __shared__ float red[4];
    if ((t & 63) == 0) red[t >> 6] = ss;
    __syncthreads();
    if (t == 0){
        float tot = red[0]+red[1]+red[2]+red[3];
        rn1[row] = 1.f / fmaxf(sqrtf(tot), 1e-12f);
    }
}

// ---------------------------------------------------------------------------
// G1) Gram partials, p-sliced, conflict-free transposed LDS tile
// ---------------------------------------------------------------------------
__global__ __launch_bounds__(256) void gram2_k(const float* __restrict__ tbuf, float* __restrict__ part){
    __shared__ float tl[128][33];
    int ps = blockIdx.x, b = blockIdx.y, t = threadIdx.x;
    for (int idx = t; idx < 4096; idx += 256){
        int cc = idx >> 7, pp = idx & 127;
        tl[pp][cc] = tbuf[(b*32+cc)*4096 + ps*128 + pp];
    }
    __syncthreads();
    #pragma unroll
    for (int k = 0; k < 4; ++k){
        int pair = k*256 + t;
        int i = pair >> 5, j = pair & 31;
        float s = 0.f;
        #pragma unroll 4
        for (int pp = 0; pp < 128; ++pp) s += tl[pp][i]*tl[pp][j];
        part[(b*32+ps)*1024 + pair] = s;
    }
}

// ---------------------------------------------------------------------------
// G2) attn1 softmax: reduce 32 slice-partials, then exp/sum; store transposed
// ---------------------------------------------------------------------------
__global__ __launch_bounds__(64) void attn1_k(const float* __restrict__ part, const float* __restrict__ rn1,
                                              float* __restrict__ attn1T){
    int i = blockIdx.x, b = blockIdx.y, j = threadIdx.x;
    float e = 0.f;
    if (j < 32){
        float g = 0.f;
        #pragma unroll 8
        for (int ps = 0; ps < 32; ++ps) g += part[(b*32+ps)*1024 + i*32 + j];
        e = __expf(rn1[b*32+i]*rn1[b*32+j]*g);
    }
    float sum = e;
    #pragma unroll
    for (int o = 32; o > 0; o >>= 1) sum += __shfl_xor(sum, o, 64);
    if (j < 32) attn1T[b*1024 + j*32 + i] = e / sum;
}

// ---------------------------------------------------------------------------
// H) out2 = attn1 @ t
// ---------------------------------------------------------------------------
__global__ __launch_bounds__(256) void out2_k(const float* __restrict__ tbuf, const float* __restrict__ attn1T,
                                              float* __restrict__ out2){
    __shared__ float al[1024];
    int pt = blockIdx.x, b = blockIdx.y, t = threadIdx.x;
    for (int i = t; i < 1024; i += 256) al[i] = attn1T[b*1024 + i];
    __syncthreads();
    int p = pt*256 + t;
    float acc[32] = {};
    for (int j = 0; j < 32; ++j){
        float tv = tbuf[(b*32+j)*4096 + p];
        #pragma unroll
        for (int q = 0; q < 8; ++q){
            float4 a = *(const float4*)&al[j*32 + q*4];
            acc[q*4+0] += a.x*tv; acc[q*4+1] += a.y*tv; acc[q*4+2] += a.z*tv; acc[q*4+3] += a.w*tv;
        }
    }
    #pragma unroll
    for (int i = 0; i < 32; ++i) out2[(b*32+i)*4096 + p] = acc[i];
}

// ---------------------------------------------------------------------------
// J) spatial attention via MFMA flash.  Block = 64 i-rows x 4 waves (16-row
//    m-tile each); j streamed in 128-tiles; 2-way j-chunk split for occupancy.
//    S = Q@K^T (one 16x16x32 bf16 mfma per n-tile), exp in C-layout, P->LDS
//    bf16 (wave-local), PV via A=P, B=V^T (vts staging).  Unnormalized
//    partials out; mrg2_k finishes.  Mappings HW-verified by conv3x3m_k.
// ---------------------------------------------------------------------------
__global__ __launch_bounds__(256) void flashm_k(const s16* __restrict__ tTb, const float* __restrict__ rn2,
                                                float* __restrict__ partA, float* __restrict__ partL){
    __shared__ alignas(16) s16 kvb[128*36];      // [j][ci]   9216 B
    __shared__ alignas(16) s16 vts[32*132];      // [ci][j]   8448 B
    __shared__ alignas(16) s16 pls[4][16*132];   // per-wave P [m][j] 16896 B
    __shared__ float rnj[128];
    __shared__ float ri[64];
    const int ib = blockIdx.x, b = blockIdx.y, chunk = blockIdx.z;
    const int t = threadIdx.x, wv = t >> 6, lane = t & 63;
    const int lm = lane & 15, g = lane >> 4;
    const int i0 = ib*64;

    if (t < 64) ri[t] = rn2[b*4096 + i0 + t];
    s16x8 qf = *(const s16x8*)&tTb[(b*4096 + i0 + wv*16 + lm)*32 + g*8];
    __syncthreads();
    float rni4[4];
    #pragma unroll
    for (int r = 0; r < 4; ++r) rni4[r] = ri[wv*16 + g*4 + r];

    f32x4 oacc[2];
    oacc[0] = (f32x4){0.f,0.f,0.f,0.f};
    oacc[1] = (f32x4){0.f,0.f,0.f,0.f};
    float lacc[4] = {0.f,0.f,0.f,0.f};
    s16* pw = pls[wv];

    for (int jt = chunk*16; jt < chunk*16 + 16; ++jt){
        const int j0 = jt*128;
        __syncthreads();
        // stage kvb [j][ci] + vts [ci][j]
        for (int gi = t; gi < 512; gi += 256){
            int j = gi >> 2, g8 = gi & 3;
            s16x8 v = *(const s16x8*)&tTb[(b*4096 + j0 + j)*32 + g8*8];
            s16* d = &kvb[j*36 + g8*8];
            *(s16x4*)d       = __builtin_shufflevector(v, v, 0,1,2,3);
            *(s16x4*)(d + 4) = __builtin_shufflevector(v, v, 4,5,6,7);
            #pragma unroll
            for (int e = 0; e < 8; ++e) vts[(g8*8 + e)*132 + j] = v[e];
        }
        if (t < 128) rnj[t] = rn2[b*4096 + j0 + t];
        __syncthreads();
        // S + exp + P write (per n-tile)
        #pragma unroll
        for (int nt = 0; nt < 8; ++nt){
            const s16* bp = &kvb[(nt*16 + lm)*36 + g*8];
            s16x4 blo = *(const s16x4*)bp;
            s16x4 bhi = *(const s16x4*)(bp + 4);
            s16x8 bf = __builtin_shufflevector(blo, bhi, 0,1,2,3,4,5,6,7);
            f32x4 s = __builtin_amdgcn_mfma_f32_16x16x32_bf16(qf, bf,
                        (f32x4){0.f,0.f,0.f,0.f}, 0, 0, 0);
            float rj = rnj[nt*16 + lm];
            #pragma unroll
            for (int r = 0; r < 4; ++r){
                float e = __expf(s[r]*rni4[r]*rj);
                lacc[r] += e;
                pw[(g*4 + r)*132 + nt*16 + lm] = f2b(e);
            }
        }
        // PV: O += P @ V  (A from pls, B from vts)
        #pragma unroll
        for (int ks = 0; ks < 4; ++ks){
            const s16* ap = &pw[lm*132 + ks*32 + g*8];
            s16x4 alo = *(const s16x4*)ap;
            s16x4 ahi = *(const s16x4*)(ap + 4);
            s16x8 af = __builtin_shufflevector(alo, ahi, 0,1,2,3,4,5,6,7);
            #pragma unroll
            for (int n2 = 0; n2 < 2; ++n2){
                const s16* vp = &vts[(n2*16 + lm)*132 + ks*32 + g*8];
                s16x4 vlo = *(const s16x4*)vp;
                s16x4 vhi = *(const s16x4*)(vp + 4);
                s16x8 vf = __builtin_shufflevector(vlo, vhi, 0,1,2,3,4,5,6,7);
                oacc[n2] = __builtin_amdgcn_mfma_f32_16x16x32_bf16(af, vf, oacc[n2], 0, 0, 0);
            }
        }
    }
    // full row-sums of l across the 16 lanes sharing g
    #pragma unroll
    for (int r = 0; r < 4; ++r){
        float v = lacc[r];
        v += __shfl_xor(v, 1, 16); v += __shfl_xor(v, 2, 16);
        v += __shfl_xor(v, 4, 16); v += __shfl_xor(v, 8, 16);
        lacc[r] = v;
    }
    const int base = (b*2 + chunk)*4096 + i0 + wv*16;
    #pragma unroll
    for (int n2 = 0; n2 < 2; ++n2)
        #pragma unroll
        for (int r = 0; r < 4; ++r)
            partA[(base + g*4 + r)*32 + n2*16 + lm] = oacc[n2][r];
    if (lm == 0){
        #pragma unroll
        for (int r = 0; r < 4; ++r) partL[base + g*4 + r] = lacc[r];
    }
}

// ---------------------------------------------------------------------------
// J2) merge the 2 j-chunks: out3T = (sum_c partA) / (sum_c partL)
// ---------------------------------------------------------------------------
__global__ __launch_bounds__(256) void mrg2_k(const float* __restrict__ partA, const float* __restrict__ partL,
                                              float* __restrict__ out3T){
    int it = blockIdx.x, b = blockIdx.y, t = threadIdx.x;
    int r = t >> 2, g = t & 3;
    int i = it*64 + r;
    float l = partL[(b*2 + 0)*4096 + i] + partL[(b*2 + 1)*4096 + i];
    float inv = 1.f / l;
    float o[8];
    #pragma unroll
    for (int k = 0; k < 8; ++k)
        o[k] = partA[((b*2 + 0)*4096 + i)*32 + g*8 + k] + partA[((b*2 + 1)*4096 + i)*32 + g*8 + k];
    float* op = out3T + (b*4096 + i)*32 + g*8;
    #pragma unroll
    for (int k = 0; k < 8; ++k) op[k] = o[k]*inv;
}

// ---------------------------------------------------------------------------
// K) out5 = w3 @ concat(out2,out3) + b3 + t
// ---------------------------------------------------------------------------
__global__ __launch_bounds__(256) void out5_k(const float* __restrict__ out2, const float* __restrict__ out3T,
                                              const float* __restrict__ tbuf, const float* __restrict__ w3,
                                              const float* __restrict__ b3, float* __restrict__ out5){
    __shared__ float w3T[64*32];
    int pt = blockIdx.x, b = blockIdx.y, t = threadIdx.x;
    for (int i = t; i < 2048; i += 256){
        int j = i >> 5, cc = i & 31;
        w3T[i] = w3[cc*64 + j];
    }
    __syncthreads();
    int p = pt*256 + t;
    float acc[32];
    #pragma unroll
    for (int cc = 0; cc < 32; ++cc) acc[cc] = b3[cc] + tbuf[(b*32+cc)*4096 + p];
    for (int j = 0; j < 32; ++j){
        float v = out2[(b*32+j)*4096 + p];
        #pragma unroll
        for (int q = 0; q < 8; ++q){
            float4 a = *(const float4*)&w3T[j*32 + q*4];
            acc[q*4] += a.x*v; acc[q*4+1] += a.y*v; acc[q*4+2] += a.z*v; acc[q*4+3] += a.w*v;
        }
    }
    const float* o3 = out3T + (b*4096 + p)*32;
    float v3[32];
    #pragma unroll
    for (int q = 0; q < 8; ++q){
        float4 v = *(const float4*)&o3[q*4];
        v3[q*4]=v.x; v3[q*4+1]=v.y; v3[q*4+2]=v.z; v3[q*4+3]=v.w;
    }
    #pragma unroll
    for (int j = 0; j < 32; ++j){
        float v = v3[j];
        #pragma unroll
        for (int q = 0; q < 8; ++q){
            float4 a = *(const float4*)&w3T[(32+j)*32 + q*4];
            acc[q*4] += a.x*v; acc[q*4+1] += a.y*v; acc[q*4+2] += a.z*v; acc[q*4+3] += a.w*v;
        }
    }
    #pragma unroll
    for (int cc = 0; cc < 32; ++cc) out5[(b*32+cc)*4096 + p] = acc[cc];
}

// ---------------------------------------------------------------------------
// L) out = w4 @ out5 + b4  (fp32 store)
// ---------------------------------------------------------------------------
__global__ __launch_bounds__(256) void final_k(const float* __restrict__ out5, const float* __restrict__ w4,
                                               const float* __restrict__ b4, float* __restrict__ out){
    __shared__ float w4T[32*64];
    int pt = blockIdx.x, cog = blockIdx.y, b = blockIdx.z, t = threadIdx.x;
    for (int i = t; i < 2048; i += 256){
        int cc = i >> 6, co = i & 63;
        w4T[i] = w4[(cog*64+co)*32 + cc];
    }
    __syncthreads();
    int p = pt*256 + t;
    float acc[64];
    #pragma unroll
    for (int co = 0; co < 64; ++co) acc[co] = b4[cog*64+co];
    for (int cc = 0; cc < 32; ++cc){
        float v = out5[(b*32+cc)*4096 + p];
        #pragma unroll
        for (int q = 0; q < 16; ++q){
            float4 a = *(const float4*)&w4T[cc*64 + q*4];
            acc[q*4] += a.x*v; acc[q*4+1] += a.y*v; acc[q*4+2] += a.z*v; acc[q*4+3] += a.w*v;
        }
    }
    #pragma unroll
    for (int co = 0; co < 64; ++co)
        out[(b*256 + cog*64 + co)*4096 + p] = acc[co];
}

// ---------------------------------------------------------------------------
// Workspace layout (bytes), peak ~19.0 MB:
//   [0,        8388608)  xcl -> out1 -> gram part / flash partA (4 MB)
//   [8388608, 16777216)  y0  -> attn fp32 region (tbuf/tTb/out2/out3T)
//   [16777216,17956864)  wpk -> partL -> out5
// ---------------------------------------------------------------------------
extern "C" void kernel_launch(void* const* d_in, const int* in_sizes, int n_in,
                              void* d_out, int out_size, void* d_ws, size_t ws_size,
                              hipStream_t stream) {
    const float* x      = (const float*)d_in[0];
    const float* w_conv = (const float*)d_in[1];
    const float* b_conv = (const float*)d_in[2];
    const float* w01 = (const float*)d_in[3];  const float* b01 = (const float*)d_in[4];
    const float* w02 = (const float*)d_in[5];  const float* b02 = (const float*)d_in[6];
    const float* w11 = (const float*)d_in[7];  const float* b11 = (const float*)d_in[8];
    const float* w12 = (const float*)d_in[9];  const float* b12 = (const float*)d_in[10];
    const float* w21 = (const float*)d_in[11]; const float* b21 = (const float*)d_in[12];
    const float* w22 = (const float*)d_in[13]; const float* b22 = (const float*)d_in[14];
    const float* w_proj = (const float*)d_in[15]; const float* b_proj = (const float*)d_in[16];
    const float* w3 = (const float*)d_in[17]; const float* b3 = (const float*)d_in[18];
    const float* w4 = (const float*)d_in[19]; const float* b4 = (const float*)d_in[20];

    char* wsb = (char*)d_ws;
    s16*   xcl  = (s16*)wsb;                        // 4,194,304 s16 (conv input)
    bf16*  out1 = (bf16*)wsb;                       // same slot, after conv
    bf16*  y0   = (bf16*)(wsb + 8388608);           // 4,194,304 bf16
    s16*   wpk  = (s16*)(wsb + 16777216);           // 589,824 s16
    float* f    = (float*)d_ws;
    float* part   = f + 0;         // gram partials (out1 dead after proj)
    float* partA  = f + 0;         // flash partials 2x4x4096x32 f = 4 MB
    float* tbuf   = f + 2097152;   // byte  8,388,608 (overlays dead y0)
    s16*   tTb    = (s16*)(wsb + 10485760);         // 524,288 s16 = 1 MB
    float* out2   = f + 3145728;   // byte 12,582,912
    float* out3T  = f + 3670016;   // byte 14,680,064
    float* out5   = f + 4194304;   // byte 16,777,216 (wpk dead by then)
    float* partL  = f + 4194304;   // 32,768 f in out5 slot (dead until out5_k)
    float* rn1    = f + 4718592;   // byte 18,874,368
    float* attn1T = f + 4722816;
    float* rn2    = f + 4726912;   // ends at byte 18,973,184

    xtrans_k<<<dim3(64, 4), 256, 0, stream>>>(x, xcl);
    wpack_k<<<dim3(2304), 256, 0, stream>>>(w_conv, wpk);
    conv3x3m_k<<<dim3(128, 4), 256, 0, stream>>>(xcl, wpk, b_conv, y0);
    sepconv_k<<<dim3(1024), 256, 0, stream>>>(y0, w01, b01, w02, b02,
                                              w11, b11, w12, b12,
                                              w21, b21, w22, b22, out1);
    proj_k<<<dim3(16, 4), 256, 0, stream>>>(out1, w_proj, b_proj, tbuf, tTb, rn2);
    rn1_k<<<dim3(128), 256, 0, stream>>>(tbuf, rn1);
    gram2_k<<<dim3(32, 4), 256, 0, stream>>>(tbuf, part);
    attn1_k<<<dim3(32, 4), 64, 0, stream>>>(part, rn1, attn1T);
    out2_k<<<dim3(16, 4), 256, 0, stream>>>(tbuf, attn1T, out2);
    flashm_k<<<dim3(64, 4, 2), 256, 0, stream>>>(tTb, rn2, partA, partL);
    mrg2_k<<<dim3(64, 4), 256, 0, stream>>>(partA, partL, out3T);
    out5_k<<<dim3(16, 4), 256, 0, stream>>>(out2, out3T, tbuf, w3, b3, out5);
    final_k<<<dim3(16, 4, 4), 256, 0, stream>>>(out5, w4, b4, (float*)d_out);
}

// Round 9
// 366.149 us; speedup vs baseline: 5.1036x; 1.1453x over previous
//
#include <hip/hip_runtime.h>
#include <hip/hip_bf16.h>

typedef __hip_bfloat16 bf16;
typedef short s16;
typedef __attribute__((ext_vector_type(4))) short s16x4;
typedef __attribute__((ext_vector_type(8))) short s16x8;
typedef __attribute__((ext_vector_type(4))) float f32x4;

__device__ __forceinline__ s16 f2b(float f){
    unsigned u = __float_as_uint(f);
    unsigned r = (u + 0x7FFFu + ((u >> 16) & 1u)) >> 16;
    return (s16)r;
}

// ---------------------------------------------------------------------------
// A1) x (fp32 NCHW) -> xcl (bf16-bits channels-last [b][h][w][ci])
// ---------------------------------------------------------------------------
__global__ __launch_bounds__(256) void xtrans_k(const float* __restrict__ x, s16* __restrict__ xcl){
    __shared__ s16 lb[64][258];
    int h = blockIdx.x, b = blockIdx.y, t = threadIdx.x;
    for (int i = t; i < 16384; i += 256){
        int ci = i >> 6, w = i & 63;
        lb[w][ci] = f2b(x[((b*256 + ci)*64 + h)*64 + w]);
    }
    __syncthreads();
    for (int i = t; i < 16384; i += 256){
        int w = i >> 8, ci = i & 255;
        xcl[(b*4096 + h*64 + w)*256 + ci] = lb[w][ci];
    }
}

// ---------------------------------------------------------------------------
// A2) w_conv (fp32 [co][ci][3][3]) -> wpk (bf16-bits [cc8][tap9][co256][ci32])
// ---------------------------------------------------------------------------
__global__ __launch_bounds__(256) void wpack_k(const float* __restrict__ w, s16* __restrict__ wpk){
    int idx = blockIdx.x*256 + threadIdx.x;      // < 589824
    int cil = idx & 31;
    int r   = idx >> 5;
    int co  = r & 255;
    int r2  = r >> 8;
    int tap = r2 % 9, cc = r2 / 9;
    wpk[idx] = f2b(w[(co*256 + cc*32 + cil)*9 + tap]);
}

// ---------------------------------------------------------------------------
// B) 3x3 conv 256->256 as MFMA implicit GEMM (unchanged from passing R8)
// ---------------------------------------------------------------------------
__global__ __launch_bounds__(256) void conv3x3m_k(const s16* __restrict__ xcl,
        const s16* __restrict__ wpk, const float* __restrict__ bias,
        bf16* __restrict__ y0){
    __shared__ alignas(16) s16 smem[30240];      // 60.5 KB
    s16* xls = smem;                             // [4 rows][66 w][36 ci-pad]
    s16* wls = smem + 9504;                      // [9 tap][64 co][36 ci-pad]
    const int sp = blockIdx.x, cog = blockIdx.y;
    const int b = sp >> 5, h0 = (sp & 31)*2;
    const int t = threadIdx.x;
    const int wv = t >> 6, lane = t & 63;
    const int lm = lane & 15, g = lane >> 4;

    f32x4 acc[2][4];
    #pragma unroll
    for (int mi = 0; mi < 2; ++mi)
        #pragma unroll
        for (int ni = 0; ni < 4; ++ni) acc[mi][ni] = (f32x4){0.f,0.f,0.f,0.f};

    for (int cc = 0; cc < 8; ++cc){
        __syncthreads();
        for (int i = t; i < 1056; i += 256){
            int g8 = i & 3, wi = (i>>2) % 66, r = (i>>2) / 66;
            int h = h0 - 1 + r, w = wi - 1;
            s16x8 v = {0,0,0,0,0,0,0,0};
            if (h >= 0 && h < 64 && w >= 0 && w < 64)
                v = *(const s16x8*)&xcl[(b*4096 + h*64 + w)*256 + cc*32 + g8*8];
            s16* d = &xls[(r*66 + wi)*36 + g8*8];
            *(s16x4*)d       = __builtin_shufflevector(v, v, 0,1,2,3);
            *(s16x4*)(d + 4) = __builtin_shufflevector(v, v, 4,5,6,7);
        }
        for (int i = t; i < 2304; i += 256){
            int g8 = i & 3, co = (i>>2) & 63, tap = i >> 8;
            s16x8 v = *(const s16x8*)&wpk[((cc*9 + tap)*256 + cog*64 + co)*32 + g8*8];
            s16* d = &wls[(tap*64 + co)*36 + g8*8];
            *(s16x4*)d       = __builtin_shufflevector(v, v, 0,1,2,3);
            *(s16x4*)(d + 4) = __builtin_shufflevector(v, v, 4,5,6,7);
        }
        __syncthreads();
        #pragma unroll
        for (int tap = 0; tap < 9; ++tap){
            const int kh = tap/3, kw = tap%3;
            s16x8 bfr[4], afr[2];
            #pragma unroll
            for (int ni = 0; ni < 4; ++ni){
                const s16* p = &wls[(tap*64 + ni*16 + lm)*36 + g*8];
                s16x4 lo = *(const s16x4*)p;
                s16x4 hi = *(const s16x4*)(p + 4);
                bfr[ni] = __builtin_shufflevector(lo, hi, 0,1,2,3,4,5,6,7);
            }
            #pragma unroll
            for (int mi = 0; mi < 2; ++mi){
                int m = (wv*2 + mi)*16 + lm;
                int hr = m >> 6, ww = m & 63;
                const s16* p = &xls[((hr + kh)*66 + (ww + kw))*36 + g*8];
                s16x4 lo = *(const s16x4*)p;
                s16x4 hi = *(const s16x4*)(p + 4);
                afr[mi] = __builtin_shufflevector(lo, hi, 0,1,2,3,4,5,6,7);
            }
            #pragma unroll
            for (int mi = 0; mi < 2; ++mi)
                #pragma unroll
                for (int ni = 0; ni < 4; ++ni)
                    acc[mi][ni] = __builtin_amdgcn_mfma_f32_16x16x32_bf16(
                        afr[mi], bfr[ni], acc[mi][ni], 0, 0, 0);
        }
    }
    __syncthreads();
    float* ot = (float*)smem;                    // [64 co][132 m-pad]
    #pragma unroll
    for (int mi = 0; mi < 2; ++mi)
        #pragma unroll
        for (int ni = 0; ni < 4; ++ni)
            #pragma unroll
            for (int r = 0; r < 4; ++r){
                int m  = (wv*2 + mi)*16 + g*4 + r;
                int co = ni*16 + lm;
                ot[co*132 + m] = acc[mi][ni][r];
            }
    __syncthreads();
    for (int i = t; i < 8192; i += 256){
        int co = i >> 7, m = i & 127;
        float v = ot[co*132 + m] + bias[cog*64 + co];
        y0[((b*256 + cog*64 + co)*64 + h0 + (m>>6))*64 + (m & 63)] = __float2bfloat16(v);
    }
}

// ---------------------------------------------------------------------------
// C) fused separable depthwise (7/11/21) + residual — sliding-window version.
//    h-conv: thread=(h, 16w strip), window in regs (16+2P LDS reads vs 16K).
//    v-conv: thread=(16h strip, w), column window in regs; acc in layout B.
//    pl/hp padded [64][65]: h-conv window reads spread banks (2-way = free),
//    v-conv lane reads consecutive w = conflict-free.
// ---------------------------------------------------------------------------
template<int K>
__device__ __forceinline__ void sep_branch(const float (*__restrict__ pl)[65], float (*__restrict__ hp)[65],
                                           int c, int t,
                                           const float* __restrict__ wh, const float* __restrict__ bh,
                                           const float* __restrict__ wv, const float* __restrict__ bv,
                                           float* acc){
    constexpr int P = K/2;
    constexpr int W = 16 + 2*P;
    float wk[K];
    #pragma unroll
    for (int j = 0; j < K; ++j) wk[j] = wh[c*K + j];
    float bhv = bh[c];
    {
        int h = t >> 2, w0 = (t & 3)*16;
        float win[W];
        #pragma unroll
        for (int j = 0; j < W; ++j){
            int ww = w0 - P + j;
            win[j] = (ww >= 0 && ww < 64) ? pl[h][ww] : 0.f;
        }
        __syncthreads();                 // prev-branch hp reads complete
        #pragma unroll
        for (int i = 0; i < 16; ++i){
            float s = bhv;
            #pragma unroll
            for (int k = 0; k < K; ++k) s += win[i+k]*wk[k];
            hp[h][w0 + i] = s;
        }
    }
    float vk[K];
    #pragma unroll
    for (int j = 0; j < K; ++j) vk[j] = wv[c*K + j];
    float bvv = bv[c];
    __syncthreads();                     // hp writes visible
    {
        int w = t & 63, h0 = (t >> 6)*16;
        float win[W];
        #pragma unroll
        for (int j = 0; j < W; ++j){
            int hh = h0 - P + j;
            win[j] = (hh >= 0 && hh < 64) ? hp[hh][w] : 0.f;
        }
        #pragma unroll
        for (int i = 0; i < 16; ++i){
            float s = bvv;
            #pragma unroll
            for (int k = 0; k < K; ++k) s += win[i+k]*vk[k];
            acc[i] += s;
        }
    }
}

__global__ __launch_bounds__(256) void sepconv_k(const bf16* __restrict__ y0,
        const float* __restrict__ w01, const float* __restrict__ b01,
        const float* __restrict__ w02, const float* __restrict__ b02,
        const float* __restrict__ w11, const float* __restrict__ b11,
        const float* __restrict__ w12, const float* __restrict__ b12,
        const float* __restrict__ w21, const float* __restrict__ b21,
        const float* __restrict__ w22, const float* __restrict__ b22,
        bf16* __restrict__ out1){
    __shared__ float pl[64][65];
    __shared__ float hp[64][65];
    int bc = blockIdx.x;             // b*256 + c
    int c = bc & 255;
    int t = threadIdx.x;
    const bf16* src = y0 + bc*4096;
    for (int i = t; i < 4096; i += 256) pl[i>>6][i&63] = __bfloat162float(src[i]);
    __syncthreads();
    float acc[16];
    #pragma unroll
    for (int k = 0; k < 16; ++k) acc[k] = 0.f;
    sep_branch<7 >(pl, hp, c, t, w01, b01, w02, b02, acc);
    sep_branch<11>(pl, hp, c, t, w11, b11, w12, b12, acc);
    sep_branch<21>(pl, hp, c, t, w21, b21, w22, b22, acc);
    bf16* dst = out1 + bc*4096;
    {
        int w = t & 63, h0 = (t >> 6)*16;
        #pragma unroll
        for (int i = 0; i < 16; ++i)
            dst[(h0 + i)*64 + w] = __float2bfloat16(acc[i] + pl[h0 + i][w]);
    }
}

// ---------------------------------------------------------------------------
// E) 1x1 projection 256->32: t[b][cc][p], tTb (bf16 [b][p][cc]), rn2[b][p]
// ---------------------------------------------------------------------------
__global__ __launch_bounds__(256) void proj_k(const bf16* __restrict__ out1, const float* __restrict__ wp,
                                              const float* __restrict__ bp, float* __restrict__ tbuf,
                                              s16* __restrict__ tTb, float* __restrict__ rn2){
    __shared__ float wl[256][32];
    int pt = blockIdx.x, b = blockIdx.y, t = threadIdx.x;
    for (int i = t; i < 8192; i += 256){
        int ci = i >> 5, cc = i & 31;
        wl[ci][cc] = wp[cc*256 + ci];
    }
    __syncthreads();
    int p = pt*256 + t;
    float acc[32] = {};
    const bf16* xb = out1 + b*1048576;
    for (int ci = 0; ci < 256; ++ci){
        float v = __bfloat162float(xb[ci*4096 + p]);
        #pragma unroll
        for (int q = 0; q < 8; ++q){
            float4 w4 = *(const float4*)&wl[ci][q*4];
            acc[q*4+0] += w4.x*v; acc[q*4+1] += w4.y*v; acc[q*4+2] += w4.z*v; acc[q*4+3] += w4.w*v;
        }
    }
    float ss = 0.f;
    #pragma unroll
    for (int cc = 0; cc < 32; ++cc){ acc[cc] += bp[cc]; ss += acc[cc]*acc[cc]; }
    rn2[b*4096 + p] = 1.f / fmaxf(sqrtf(ss), 1e-12f);
    #pragma unroll
    for (int cc = 0; cc < 32; ++cc) tbuf[(b*32+cc)*4096 + p] = acc[cc];
    s16* tp = tTb + (b*4096 + p)*32;
    #pragma unroll
    for (int q = 0; q < 8; ++q){
        s16x4 o; o[0]=f2b(acc[q*4]); o[1]=f2b(acc[q*4+1]); o[2]=f2b(acc[q*4+2]); o[3]=f2b(acc[q*4+3]);
        *(s16x4*)&tp[q*4] = o;
    }
}

// ---------------------------------------------------------------------------
// F) row norms of t over p (128 rows)
// ---------------------------------------------------------------------------
__global__ __launch_bounds__(256) void rn1_k(const float* __restrict__ tbuf, float* __restrict__ rn1){
    int row = blockIdx.x;
    int t = threadIdx.x;
    float ss = 0.f;
    const float* r = tbuf + row*4096;
    for (int p = t; p < 4096; p += 256){ float v = r[p]; ss += v*v; }
    #pragma unroll
    for (int o = 32; o > 0; o >>= 1) ss += __shfl_down(ss, o, 64);
    __shared__ float red[4];
    if ((t & 63) == 0) red[t >> 6] = ss;
    __syncthreads();
    if (t == 0){
        float tot = red[0]+red[1]+red[2]+red[3];
        rn1[row] = 1.f / fmaxf(sqrtf(tot), 1e-12f);
    }
}

// ---------------------------------------------------------------------------
// G1) Gram partials, p-sliced, conflict-free transposed LDS tile
// ---------------------------------------------------------------------------
__global__ __launch_bounds__(256) void gram2_k(const float* __restrict__ tbuf, float* __restrict__ part){
    __shared__ float tl[128][33];
    int ps = blockIdx.x, b = blockIdx.y, t = threadIdx.x;
    for (int idx = t; idx < 4096; idx += 256){
        int cc = idx >> 7, pp = idx & 127;
        tl[pp][cc] = tbuf[(b*32+cc)*4096 + ps*128 + pp];
    }
    __syncthreads();
    #pragma unroll
    for (int k = 0; k < 4; ++k){
        int pair = k*256 + t;
        int i = pair >> 5, j = pair & 31;
        float s = 0.f;
        #pragma unroll 4
        for (int pp = 0; pp < 128; ++pp) s += tl[pp][i]*tl[pp][j];
        part[(b*32+ps)*1024 + pair] = s;
    }
}

// ---------------------------------------------------------------------------
// G2) attn1 softmax: reduce 32 slice-partials, then exp/sum; store transposed
// ---------------------------------------------------------------------------
__global__ __launch_bounds__(64) void attn1_k(const float* __restrict__ part, const float* __restrict__ rn1,
                                              float* __restrict__ attn1T){
    int i = blockIdx.x, b = blockIdx.y, j = threadIdx.x;
    float e = 0.f;
    if (j < 32){
        float g = 0.f;
        #pragma unroll 8
        for (int ps = 0; ps < 32; ++ps) g += part[(b*32+ps)*1024 + i*32 + j];
        e = __expf(rn1[b*32+i]*rn1[b*32+j]*g);
    }
    float sum = e;
    #pragma unroll
    for (int o = 32; o > 0; o >>= 1) sum += __shfl_xor(sum, o, 64);
    if (j < 32) attn1T[b*1024 + j*32 + i] = e / sum;
}

// ---------------------------------------------------------------------------
// H) out2 = attn1 @ t
// ---------------------------------------------------------------------------
__global__ __launch_bounds__(256) void out2_k(const float* __restrict__ tbuf, const float* __restrict__ attn1T,
                                              float* __restrict__ out2){
    __shared__ float al[1024];
    int pt = blockIdx.x, b = blockIdx.y, t = threadIdx.x;
    for (int i = t; i < 1024; i += 256) al[i] = attn1T[b*1024 + i];
    __syncthreads();
    int p = pt*256 + t;
    float acc[32] = {};
    for (int j = 0; j < 32; ++j){
        float tv = tbuf[(b*32+j)*4096 + p];
        #pragma unroll
        for (int q = 0; q < 8; ++q){
            float4 a = *(const float4*)&al[j*32 + q*4];
            acc[q*4+0] += a.x*tv; acc[q*4+1] += a.y*tv; acc[q*4+2] += a.z*tv; acc[q*4+3] += a.w*tv;
        }
    }
    #pragma unroll
    for (int i = 0; i < 32; ++i) out2[(b*32+i)*4096 + p] = acc[i];
}

// ---------------------------------------------------------------------------
// J) spatial attention via MFMA flash (unchanged from passing R8)
// ---------------------------------------------------------------------------
__global__ __launch_bounds__(256) void flashm_k(const s16* __restrict__ tTb, const float* __restrict__ rn2,
                                                float* __restrict__ partA, float* __restrict__ partL){
    __shared__ alignas(16) s16 kvb[128*36];      // [j][ci]   9216 B
    __shared__ alignas(16) s16 vts[32*132];      // [ci][j]   8448 B
    __shared__ alignas(16) s16 pls[4][16*132];   // per-wave P [m][j] 16896 B
    __shared__ float rnj[128];
    __shared__ float ri[64];
    const int ib = blockIdx.x, b = blockIdx.y, chunk = blockIdx.z;
    const int t = threadIdx.x, wv = t >> 6, lane = t & 63;
    const int lm = lane & 15, g = lane >> 4;
    const int i0 = ib*64;

    if (t < 64) ri[t] = rn2[b*4096 + i0 + t];
    s16x8 qf = *(const s16x8*)&tTb[(b*4096 + i0 + wv*16 + lm)*32 + g*8];
    __syncthreads();
    float rni4[4];
    #pragma unroll
    for (int r = 0; r < 4; ++r) rni4[r] = ri[wv*16 + g*4 + r];

    f32x4 oacc[2];
    oacc[0] = (f32x4){0.f,0.f,0.f,0.f};
    oacc[1] = (f32x4){0.f,0.f,0.f,0.f};
    float lacc[4] = {0.f,0.f,0.f,0.f};
    s16* pw = pls[wv];

    for (int jt = chunk*16; jt < chunk*16 + 16; ++jt){
        const int j0 = jt*128;
        __syncthreads();
        for (int gi = t; gi < 512; gi += 256){
            int j = gi >> 2, g8 = gi & 3;
            s16x8 v = *(const s16x8*)&tTb[(b*4096 + j0 + j)*32 + g8*8];
            s16* d = &kvb[j*36 + g8*8];
            *(s16x4*)d       = __builtin_shufflevector(v, v, 0,1,2,3);
            *(s16x4*)(d + 4) = __builtin_shufflevector(v, v, 4,5,6,7);
            #pragma unroll
            for (int e = 0; e < 8; ++e) vts[(g8*8 + e)*132 + j] = v[e];
        }
        if (t < 128) rnj[t] = rn2[b*4096 + j0 + t];
        __syncthreads();
        #pragma unroll
        for (int nt = 0; nt < 8; ++nt){
            const s16* bp = &kvb[(nt*16 + lm)*36 + g*8];
            s16x4 blo = *(const s16x4*)bp;
            s16x4 bhi = *(const s16x4*)(bp + 4);
            s16x8 bf = __builtin_shufflevector(blo, bhi, 0,1,2,3,4,5,6,7);
            f32x4 s = __builtin_amdgcn_mfma_f32_16x16x32_bf16(qf, bf,
                        (f32x4){0.f,0.f,0.f,0.f}, 0, 0, 0);
            float rj = rnj[nt*16 + lm];
            #pragma unroll
            for (int r = 0; r < 4; ++r){
                float e = __expf(s[r]*rni4[r]*rj);
                lacc[r] += e;
                pw[(g*4 + r)*132 + nt*16 + lm] = f2b(e);
            }
        }
        #pragma unroll
        for (int ks = 0; ks < 4; ++ks){
            const s16* ap = &pw[lm*132 + ks*32 + g*8];
            s16x4 alo = *(const s16x4*)ap;
            s16x4 ahi = *(const s16x4*)(ap + 4);
            s16x8 af = __builtin_shufflevector(alo, ahi, 0,1,2,3,4,5,6,7);
            #pragma unroll
            for (int n2 = 0; n2 < 2; ++n2){
                const s16* vp = &vts[(n2*16 + lm)*132 + ks*32 + g*8];
                s16x4 vlo = *(const s16x4*)vp;
                s16x4 vhi = *(const s16x4*)(vp + 4);
                s16x8 vf = __builtin_shufflevector(vlo, vhi, 0,1,2,3,4,5,6,7);
                oacc[n2] = __builtin_amdgcn_mfma_f32_16x16x32_bf16(af, vf, oacc[n2], 0, 0, 0);
            }
        }
    }
    #pragma unroll
    for (int r = 0; r < 4; ++r){
        float v = lacc[r];
        v += __shfl_xor(v, 1, 16); v += __shfl_xor(v, 2, 16);
        v += __shfl_xor(v, 4, 16); v += __shfl_xor(v, 8, 16);
        lacc[r] = v;
    }
    const int base = (b*2 + chunk)*4096 + i0 + wv*16;
    #pragma unroll
    for (int n2 = 0; n2 < 2; ++n2)
        #pragma unroll
        for (int r = 0; r < 4; ++r)
            partA[(base + g*4 + r)*32 + n2*16 + lm] = oacc[n2][r];
    if (lm == 0){
        #pragma unroll
        for (int r = 0; r < 4; ++r) partL[base + g*4 + r] = lacc[r];
    }
}

// ---------------------------------------------------------------------------
// J2) merge the 2 j-chunks: out3T = (sum_c partA) / (sum_c partL)
// ---------------------------------------------------------------------------
__global__ __launch_bounds__(256) void mrg2_k(const float* __restrict__ partA, const float* __restrict__ partL,
                                              float* __restrict__ out3T){
    int it = blockIdx.x, b = blockIdx.y, t = threadIdx.x;
    int r = t >> 2, g = t & 3;
    int i = it*64 + r;
    float l = partL[(b*2 + 0)*4096 + i] + partL[(b*2 + 1)*4096 + i];
    float inv = 1.f / l;
    float o[8];
    #pragma unroll
    for (int k = 0; k < 8; ++k)
        o[k] = partA[((b*2 + 0)*4096 + i)*32 + g*8 + k] + partA[((b*2 + 1)*4096 + i)*32 + g*8 + k];
    float* op = out3T + (b*4096 + i)*32 + g*8;
    #pragma unroll
    for (int k = 0; k < 8; ++k) op[k] = o[k]*inv;
}

// ---------------------------------------------------------------------------
// K) out5 = w3 @ concat(out2,out3) + b3 + t
// ---------------------------------------------------------------------------
__global__ __launch_bounds__(256) void out5_k(const float* __restrict__ out2, const float* __restrict__ out3T,
                                              const float* __restrict__ tbuf, const float* __restrict__ w3,
                                              const float* __restrict__ b3, float* __restrict__ out5){
    __shared__ float w3T[64*32];
    int pt = blockIdx.x, b = blockIdx.y, t = threadIdx.x;
    for (int i = t; i < 2048; i += 256){
        int j = i >> 5, cc = i & 31;
        w3T[i] = w3[cc*64 + j];
    }
    __syncthreads();
    int p = pt*256 + t;
    float acc[32];
    #pragma unroll
    for (int cc = 0; cc < 32; ++cc) acc[cc] = b3[cc] + tbuf[(b*32+cc)*4096 + p];
    for (int j = 0; j < 32; ++j){
        float v = out2[(b*32+j)*4096 + p];
        #pragma unroll
        for (int q = 0; q < 8; ++q){
            float4 a = *(const float4*)&w3T[j*32 + q*4];
            acc[q*4] += a.x*v; acc[q*4+1] += a.y*v; acc[q*4+2] += a.z*v; acc[q*4+3] += a.w*v;
        }
    }
    const float* o3 = out3T + (b*4096 + p)*32;
    float v3[32];
    #pragma unroll
    for (int q = 0; q < 8; ++q){
        float4 v = *(const float4*)&o3[q*4];
        v3[q*4]=v.x; v3[q*4+1]=v.y; v3[q*4+2]=v.z; v3[q*4+3]=v.w;
    }
    #pragma unroll
    for (int j = 0; j < 32; ++j){
        float v = v3[j];
        #pragma unroll
        for (int q = 0; q < 8; ++q){
            float4 a = *(const float4*)&w3T[(32+j)*32 + q*4];
            acc[q*4] += a.x*v; acc[q*4+1] += a.y*v; acc[q*4+2] += a.z*v; acc[q*4+3] += a.w*v;
        }
    }
    #pragma unroll
    for (int cc = 0; cc < 32; ++cc) out5[(b*32+cc)*4096 + p] = acc[cc];
}

// ---------------------------------------------------------------------------
// L) out = w4 @ out5 + b4  (fp32 store)
// ---------------------------------------------------------------------------
__global__ __launch_bounds__(256) void final_k(const float* __restrict__ out5, const float* __restrict__ w4,
                                               const float* __restrict__ b4, float* __restrict__ out){
    __shared__ float w4T[32*64];
    int pt = blockIdx.x, cog = blockIdx.y, b = blockIdx.z, t = threadIdx.x;
    for (int i = t; i < 2048; i += 256){
        int cc = i >> 6, co = i & 63;
        w4T[i] = w4[(cog*64+co)*32 + cc];
    }
    __syncthreads();
    int p = pt*256 + t;
    float acc[64];
    #pragma unroll
    for (int co = 0; co < 64; ++co) acc[co] = b4[cog*64+co];
    for (int cc = 0; cc < 32; ++cc){
        float v = out5[(b*32+cc)*4096 + p];
        #pragma unroll
        for (int q = 0; q < 16; ++q){
            float4 a = *(const float4*)&w4T[cc*64 + q*4];
            acc[q*4] += a.x*v; acc[q*4+1] += a.y*v; acc[q*4+2] += a.z*v; acc[q*4+3] += a.w*v;
        }
    }
    #pragma unroll
    for (int co = 0; co < 64; ++co)
        out[(b*256 + cog*64 + co)*4096 + p] = acc[co];
}

// ---------------------------------------------------------------------------
// Workspace layout (bytes), peak ~19.0 MB:
//   [0,        8388608)  xcl -> out1 -> gram part / flash partA (4 MB)
//   [8388608, 16777216)  y0  -> attn fp32 region (tbuf/tTb/out2/out3T)
//   [16777216,17956864)  wpk -> partL -> out5
// ---------------------------------------------------------------------------
extern "C" void kernel_launch(void* const* d_in, const int* in_sizes, int n_in,
                              void* d_out, int out_size, void* d_ws, size_t ws_size,
                              hipStream_t stream) {
    const float* x      = (const float*)d_in[0];
    const float* w_conv = (const float*)d_in[1];
    const float* b_conv = (const float*)d_in[2];
    const float* w01 = (const float*)d_in[3];  const float* b01 = (const float*)d_in[4];
    const float* w02 = (const float*)d_in[5];  const float* b02 = (const float*)d_in[6];
    const float* w11 = (const float*)d_in[7];  const float* b11 = (const float*)d_in[8];
    const float* w12 = (const float*)d_in[9];  const float* b12 = (const float*)d_in[10];
    const float* w21 = (const float*)d_in[11]; const float* b21 = (const float*)d_in[12];
    const float* w22 = (const float*)d_in[13]; const float* b22 = (const float*)d_in[14];
    const float* w_proj = (const float*)d_in[15]; const float* b_proj = (const float*)d_in[16];
    const float* w3 = (const float*)d_in[17]; const float* b3 = (const float*)d_in[18];
    const float* w4 = (const float*)d_in[19]; const float* b4 = (const float*)d_in[20];

    char* wsb = (char*)d_ws;
    s16*   xcl  = (s16*)wsb;                        // 4,194,304 s16 (conv input)
    bf16*  out1 = (bf16*)wsb;                       // same slot, after conv
    bf16*  y0   = (bf16*)(wsb + 8388608);           // 4,194,304 bf16
    s16*   wpk  = (s16*)(wsb + 16777216);           // 589,824 s16
    float* f    = (float*)d_ws;
    float* part   = f + 0;         // gram partials (out1 dead after proj)
    float* partA  = f + 0;         // flash partials 2x4x4096x32 f = 4 MB
    float* tbuf   = f + 2097152;   // byte  8,388,608 (overlays dead y0)
    s16*   tTb    = (s16*)(wsb + 10485760);         // 524,288 s16 = 1 MB
    float* out2   = f + 3145728;   // byte 12,582,912
    float* out3T  = f + 3670016;   // byte 14,680,064
    float* out5   = f + 4194304;   // byte 16,777,216 (wpk dead by then)
    float* partL  = f + 4194304;   // 32,768 f in out5 slot (dead until out5_k)
    float* rn1    = f + 4718592;   // byte 18,874,368
    float* attn1T = f + 4722816;
    float* rn2    = f + 4726912;   // ends at byte 18,973,184

    xtrans_k<<<dim3(64, 4), 256, 0, stream>>>(x, xcl);
    wpack_k<<<dim3(2304), 256, 0, stream>>>(w_conv, wpk);
    conv3x3m_k<<<dim3(128, 4), 256, 0, stream>>>(xcl, wpk, b_conv, y0);
    sepconv_k<<<dim3(1024), 256, 0, stream>>>(y0, w01, b01, w02, b02,
                                              w11, b11, w12, b12,
                                              w21, b21, w22, b22, out1);
    proj_k<<<dim3(16, 4), 256, 0, stream>>>(out1, w_proj, b_proj, tbuf, tTb, rn2);
    rn1_k<<<dim3(128), 256, 0, stream>>>(tbuf, rn1);
    gram2_k<<<dim3(32, 4), 256, 0, stream>>>(tbuf, part);
    attn1_k<<<dim3(32, 4), 64, 0, stream>>>(part, rn1, attn1T);
    out2_k<<<dim3(16, 4), 256, 0, stream>>>(tbuf, attn1T, out2);
    flashm_k<<<dim3(64, 4, 2), 256, 0, stream>>>(tTb, rn2, partA, partL);
    mrg2_k<<<dim3(64, 4), 256, 0, stream>>>(partA, partL, out3T);
    out5_k<<<dim3(16, 4), 256, 0, stream>>>(out2, out3T, tbuf, w3, b3, out5);
    final_k<<<dim3(16, 4, 4), 256, 0, stream>>>(out5, w4, b4, (float*)d_out);
}

// Round 10
// 335.296 us; speedup vs baseline: 5.5732x; 1.0920x over previous
//
#include <hip/hip_runtime.h>
#include <hip/hip_bf16.h>

typedef __hip_bfloat16 bf16;
typedef short s16;
typedef __attribute__((ext_vector_type(4))) short s16x4;
typedef __attribute__((ext_vector_type(8))) short s16x8;
typedef __attribute__((ext_vector_type(4))) float f32x4;

__device__ __forceinline__ s16 f2b(float f){
    unsigned u = __float_as_uint(f);
    unsigned r = (u + 0x7FFFu + ((u >> 16) & 1u)) >> 16;
    return (s16)r;
}
__device__ __forceinline__ float b2f_bits(s16 v){
    return __uint_as_float(((unsigned)(unsigned short)v) << 16);
}

// ---------------------------------------------------------------------------
// A1) x (fp32 NCHW) -> xcl (bf16-bits channels-last [b][h][w][ci])
// ---------------------------------------------------------------------------
__global__ __launch_bounds__(256) void xtrans_k(const float* __restrict__ x, s16* __restrict__ xcl){
    __shared__ s16 lb[64][258];
    int h = blockIdx.x, b = blockIdx.y, t = threadIdx.x;
    for (int i = t; i < 16384; i += 256){
        int ci = i >> 6, w = i & 63;
        lb[w][ci] = f2b(x[((b*256 + ci)*64 + h)*64 + w]);
    }
    __syncthreads();
    for (int i = t; i < 16384; i += 256){
        int w = i >> 8, ci = i & 255;
        xcl[(b*4096 + h*64 + w)*256 + ci] = lb[w][ci];
    }
}

// ---------------------------------------------------------------------------
// A2) w_conv (fp32 [co][ci][3][3]) -> wpk (bf16-bits [cc8][tap9][co256][ci32])
// ---------------------------------------------------------------------------
__global__ __launch_bounds__(256) void wpack_k(const float* __restrict__ w, s16* __restrict__ wpk){
    int idx = blockIdx.x*256 + threadIdx.x;      // < 589824
    int cil = idx & 31;
    int r   = idx >> 5;
    int co  = r & 255;
    int r2  = r >> 8;
    int tap = r2 % 9, cc = r2 / 9;
    wpk[idx] = f2b(w[(co*256 + cc*32 + cil)*9 + tap]);
}

// ---------------------------------------------------------------------------
// B) 3x3 conv 256->256 as MFMA implicit GEMM (unchanged from passing R9)
// ---------------------------------------------------------------------------
__global__ __launch_bounds__(256) void conv3x3m_k(const s16* __restrict__ xcl,
        const s16* __restrict__ wpk, const float* __restrict__ bias,
        bf16* __restrict__ y0){
    __shared__ alignas(16) s16 smem[30240];      // 60.5 KB
    s16* xls = smem;                             // [4 rows][66 w][36 ci-pad]
    s16* wls = smem + 9504;                      // [9 tap][64 co][36 ci-pad]
    const int sp = blockIdx.x, cog = blockIdx.y;
    const int b = sp >> 5, h0 = (sp & 31)*2;
    const int t = threadIdx.x;
    const int wv = t >> 6, lane = t & 63;
    const int lm = lane & 15, g = lane >> 4;

    f32x4 acc[2][4];
    #pragma unroll
    for (int mi = 0; mi < 2; ++mi)
        #pragma unroll
        for (int ni = 0; ni < 4; ++ni) acc[mi][ni] = (f32x4){0.f,0.f,0.f,0.f};

    for (int cc = 0; cc < 8; ++cc){
        __syncthreads();
        for (int i = t; i < 1056; i += 256){
            int g8 = i & 3, wi = (i>>2) % 66, r = (i>>2) / 66;
            int h = h0 - 1 + r, w = wi - 1;
            s16x8 v = {0,0,0,0,0,0,0,0};
            if (h >= 0 && h < 64 && w >= 0 && w < 64)
                v = *(const s16x8*)&xcl[(b*4096 + h*64 + w)*256 + cc*32 + g8*8];
            s16* d = &xls[(r*66 + wi)*36 + g8*8];
            *(s16x4*)d       = __builtin_shufflevector(v, v, 0,1,2,3);
            *(s16x4*)(d + 4) = __builtin_shufflevector(v, v, 4,5,6,7);
        }
        for (int i = t; i < 2304; i += 256){
            int g8 = i & 3, co = (i>>2) & 63, tap = i >> 8;
            s16x8 v = *(const s16x8*)&wpk[((cc*9 + tap)*256 + cog*64 + co)*32 + g8*8];
            s16* d = &wls[(tap*64 + co)*36 + g8*8];
            *(s16x4*)d       = __builtin_shufflevector(v, v, 0,1,2,3);
            *(s16x4*)(d + 4) = __builtin_shufflevector(v, v, 4,5,6,7);
        }
        __syncthreads();
        #pragma unroll
        for (int tap = 0; tap < 9; ++tap){
            const int kh = tap/3, kw = tap%3;
            s16x8 bfr[4], afr[2];
            #pragma unroll
            for (int ni = 0; ni < 4; ++ni){
                const s16* p = &wls[(tap*64 + ni*16 + lm)*36 + g*8];
                s16x4 lo = *(const s16x4*)p;
                s16x4 hi = *(const s16x4*)(p + 4);
                bfr[ni] = __builtin_shufflevector(lo, hi, 0,1,2,3,4,5,6,7);
            }
            #pragma unroll
            for (int mi = 0; mi < 2; ++mi){
                int m = (wv*2 + mi)*16 + lm;
                int hr = m >> 6, ww = m & 63;
                const s16* p = &xls[((hr + kh)*66 + (ww + kw))*36 + g*8];
                s16x4 lo = *(const s16x4*)p;
                s16x4 hi = *(const s16x4*)(p + 4);
                afr[mi] = __builtin_shufflevector(lo, hi, 0,1,2,3,4,5,6,7);
            }
            #pragma unroll
            for (int mi = 0; mi < 2; ++mi)
                #pragma unroll
                for (int ni = 0; ni < 4; ++ni)
                    acc[mi][ni] = __builtin_amdgcn_mfma_f32_16x16x32_bf16(
                        afr[mi], bfr[ni], acc[mi][ni], 0, 0, 0);
        }
    }
    __syncthreads();
    float* ot = (float*)smem;                    // [64 co][132 m-pad]
    #pragma unroll
    for (int mi = 0; mi < 2; ++mi)
        #pragma unroll
        for (int ni = 0; ni < 4; ++ni)
            #pragma unroll
            for (int r = 0; r < 4; ++r){
                int m  = (wv*2 + mi)*16 + g*4 + r;
                int co = ni*16 + lm;
                ot[co*132 + m] = acc[mi][ni][r];
            }
    __syncthreads();
    for (int i = t; i < 8192; i += 256){
        int co = i >> 7, m = i & 127;
        float v = ot[co*132 + m] + bias[cog*64 + co];
        y0[((b*256 + cog*64 + co)*64 + h0 + (m>>6))*64 + (m & 63)] = __float2bfloat16(v);
    }
}

// ---------------------------------------------------------------------------
// C) fused separable depthwise (7/11/21) + residual, sliding-window (R9)
// ---------------------------------------------------------------------------
template<int K>
__device__ __forceinline__ void sep_branch(const float (*__restrict__ pl)[65], float (*__restrict__ hp)[65],
                                           int c, int t,
                                           const float* __restrict__ wh, const float* __restrict__ bh,
                                           const float* __restrict__ wv, const float* __restrict__ bv,
                                           float* acc){
    constexpr int P = K/2;
    constexpr int W = 16 + 2*P;
    float wk[K];
    #pragma unroll
    for (int j = 0; j < K; ++j) wk[j] = wh[c*K + j];
    float bhv = bh[c];
    {
        int h = t >> 2, w0 = (t & 3)*16;
        float win[W];
        #pragma unroll
        for (int j = 0; j < W; ++j){
            int ww = w0 - P + j;
            win[j] = (ww >= 0 && ww < 64) ? pl[h][ww] : 0.f;
        }
        __syncthreads();                 // prev-branch hp reads complete
        #pragma unroll
        for (int i = 0; i < 16; ++i){
            float s = bhv;
            #pragma unroll
            for (int k = 0; k < K; ++k) s += win[i+k]*wk[k];
            hp[h][w0 + i] = s;
        }
    }
    float vk[K];
    #pragma unroll
    for (int j = 0; j < K; ++j) vk[j] = wv[c*K + j];
    float bvv = bv[c];
    __syncthreads();                     // hp writes visible
    {
        int w = t & 63, h0 = (t >> 6)*16;
        float win[W];
        #pragma unroll
        for (int j = 0; j < W; ++j){
            int hh = h0 - P + j;
            win[j] = (hh >= 0 && hh < 64) ? hp[hh][w] : 0.f;
        }
        #pragma unroll
        for (int i = 0; i < 16; ++i){
            float s = bvv;
            #pragma unroll
            for (int k = 0; k < K; ++k) s += win[i+k]*vk[k];
            acc[i] += s;
        }
    }
}

__global__ __launch_bounds__(256) void sepconv_k(const bf16* __restrict__ y0,
        const float* __restrict__ w01, const float* __restrict__ b01,
        const float* __restrict__ w02, const float* __restrict__ b02,
        const float* __restrict__ w11, const float* __restrict__ b11,
        const float* __restrict__ w12, const float* __restrict__ b12,
        const float* __restrict__ w21, const float* __restrict__ b21,
        const float* __restrict__ w22, const float* __restrict__ b22,
        bf16* __restrict__ out1){
    __shared__ float pl[64][65];
    __shared__ float hp[64][65];
    int bc = blockIdx.x;             // b*256 + c
    int c = bc & 255;
    int t = threadIdx.x;
    const bf16* src = y0 + bc*4096;
    for (int i = t; i < 4096; i += 256) pl[i>>6][i&63] = __bfloat162float(src[i]);
    __syncthreads();
    float acc[16];
    #pragma unroll
    for (int k = 0; k < 16; ++k) acc[k] = 0.f;
    sep_branch<7 >(pl, hp, c, t, w01, b01, w02, b02, acc);
    sep_branch<11>(pl, hp, c, t, w11, b11, w12, b12, acc);
    sep_branch<21>(pl, hp, c, t, w21, b21, w22, b22, acc);
    bf16* dst = out1 + bc*4096;
    {
        int w = t & 63, h0 = (t >> 6)*16;
        #pragma unroll
        for (int i = 0; i < 16; ++i)
            dst[(h0 + i)*64 + w] = __float2bfloat16(acc[i] + pl[h0 + i][w]);
    }
}

// ---------------------------------------------------------------------------
// E) 1x1 projection 256->32, 4-way ci-split for occupancy.
//    Grid (64 pt, 4 b) = 256 blocks (1/CU, all CUs active).  Wave q reduces
//    ci in [q*64, q*64+64) for 64 p values; bf16 partials in LDS; epilogue
//    thread=(p, cc-octet) sums quarters, computes rn2 (shfl width-4), writes
//    tbuf (fp32) + tTb (bf16, 16B/lane coalesced).
// ---------------------------------------------------------------------------
__global__ __launch_bounds__(256) void proj_k(const bf16* __restrict__ out1, const float* __restrict__ wp,
                                              const float* __restrict__ bp, float* __restrict__ tbuf,
                                              s16* __restrict__ tTb, float* __restrict__ rn2){
    __shared__ float wl[256*32];         // [ci][cc] fp32, 32 KB
    __shared__ s16 part[4][64][36];      // bf16 partials, 18.4 KB
    int pt = blockIdx.x, b = blockIdx.y, t = threadIdx.x;
    int q = t >> 6, lane = t & 63;
    for (int i = t; i < 8192; i += 256){
        int ci = i >> 5, cc = i & 31;
        wl[ci*32 + cc] = wp[cc*256 + ci];
    }
    __syncthreads();
    int p = pt*64 + lane;
    float acc[32] = {};
    const bf16* xb = out1 + b*1048576 + p;
    for (int ci = q*64; ci < q*64 + 64; ++ci){
        float v = __bfloat162float(xb[ci*4096]);
        const float* wr = &wl[ci*32];
        #pragma unroll
        for (int c8 = 0; c8 < 8; ++c8){
            float4 w4 = *(const float4*)&wr[c8*4];
            acc[c8*4+0] += w4.x*v; acc[c8*4+1] += w4.y*v;
            acc[c8*4+2] += w4.z*v; acc[c8*4+3] += w4.w*v;
        }
    }
    #pragma unroll
    for (int cc = 0; cc < 32; ++cc) part[q][lane][cc] = f2b(acc[cc]);
    __syncthreads();
    // epilogue: thread = (p_loc = t>>2, qq = t&3), cc = qq*8..qq*8+7
    int p_loc = t >> 2, qq = t & 3;
    int pg = pt*64 + p_loc;
    float a8[8];
    float ss = 0.f;
    #pragma unroll
    for (int c = 0; c < 8; ++c){
        int cc = qq*8 + c;
        float v = b2f_bits(part[0][p_loc][cc]) + b2f_bits(part[1][p_loc][cc])
                + b2f_bits(part[2][p_loc][cc]) + b2f_bits(part[3][p_loc][cc]) + bp[cc];
        a8[c] = v;
        ss += v*v;
    }
    ss += __shfl_xor(ss, 1, 4);
    ss += __shfl_xor(ss, 2, 4);
    if (qq == 0) rn2[b*4096 + pg] = 1.f / fmaxf(sqrtf(ss), 1e-12f);
    #pragma unroll
    for (int c = 0; c < 8; ++c) tbuf[(b*32 + qq*8 + c)*4096 + pg] = a8[c];
    s16x8 o8;
    #pragma unroll
    for (int c = 0; c < 8; ++c) o8[c] = f2b(a8[c]);
    *(s16x8*)&tTb[(b*4096 + pg)*32 + qq*8] = o8;
}

// ---------------------------------------------------------------------------
// F) row norms of t over p (128 rows)
// ---------------------------------------------------------------------------
__global__ __launch_bounds__(256) void rn1_k(const float* __restrict__ tbuf, float* __restrict__ rn1){
    int row = blockIdx.x;
    int t = threadIdx.x;
    float ss = 0.f;
    const float* r = tbuf + row*4096;
    for (int p = t; p < 4096; p += 256){ float v = r[p]; ss += v*v; }
    #pragma unroll
    for (int o = 32; o > 0; o >>= 1) ss += __shfl_down(ss, o, 64);
    __shared__ float red[4];
    if ((t & 63) == 0) red[t >> 6] = ss;
    __syncthreads();
    if (t == 0){
        float tot = red[0]+red[1]+red[2]+red[3];
        rn1[row] = 1.f / fmaxf(sqrtf(tot), 1e-12f);
    }
}

// ---------------------------------------------------------------------------
// G1) Gram partials, p-sliced, conflict-free transposed LDS tile
// ---------------------------------------------------------------------------
__global__ __launch_bounds__(256) void gram2_k(const float* __restrict__ tbuf, float* __restrict__ part){
    __shared__ float tl[128][33];
    int ps = blockIdx.x, b = blockIdx.y, t = threadIdx.x;
    for (int idx = t; idx < 4096; idx += 256){
        int cc = idx >> 7, pp = idx & 127;
        tl[pp][cc] = tbuf[(b*32+cc)*4096 + ps*128 + pp];
    }
    __syncthreads();
    #pragma unroll
    for (int k = 0; k < 4; ++k){
        int pair = k*256 + t;
        int i = pair >> 5, j = pair & 31;
        float s = 0.f;
        #pragma unroll 4
        for (int pp = 0; pp < 128; ++pp) s += tl[pp][i]*tl[pp][j];
        part[(b*32+ps)*1024 + pair] = s;
    }
}

// ---------------------------------------------------------------------------
// G2) attn1 softmax: reduce 32 slice-partials, then exp/sum; store transposed
// ---------------------------------------------------------------------------
__global__ __launch_bounds__(64) void attn1_k(const float* __restrict__ part, const float* __restrict__ rn1,
                                              float* __restrict__ attn1T){
    int i = blockIdx.x, b = blockIdx.y, j = threadIdx.x;
    float e = 0.f;
    if (j < 32){
        float g = 0.f;
        #pragma unroll 8
        for (int ps = 0; ps < 32; ++ps) g += part[(b*32+ps)*1024 + i*32 + j];
        e = __expf(rn1[b*32+i]*rn1[b*32+j]*g);
    }
    float sum = e;
    #pragma unroll
    for (int o = 32; o > 0; o >>= 1) sum += __shfl_xor(sum, o, 64);
    if (j < 32) attn1T[b*1024 + j*32 + i] = e / sum;
}

// ---------------------------------------------------------------------------
// H) out2 = attn1 @ t
// ---------------------------------------------------------------------------
__global__ __launch_bounds__(256) void out2_k(const float* __restrict__ tbuf, const float* __restrict__ attn1T,
                                              float* __restrict__ out2){
    __shared__ float al[1024];
    int pt = blockIdx.x, b = blockIdx.y, t = threadIdx.x;
    for (int i = t; i < 1024; i += 256) al[i] = attn1T[b*1024 + i];
    __syncthreads();
    int p = pt*256 + t;
    float acc[32] = {};
    for (int j = 0; j < 32; ++j){
        float tv = tbuf[(b*32+j)*4096 + p];
        #pragma unroll
        for (int q = 0; q < 8; ++q){
            float4 a = *(const float4*)&al[j*32 + q*4];
            acc[q*4+0] += a.x*tv; acc[q*4+1] += a.y*tv; acc[q*4+2] += a.z*tv; acc[q*4+3] += a.w*tv;
        }
    }
    #pragma unroll
    for (int i = 0; i < 32; ++i) out2[(b*32+i)*4096 + p] = acc[i];
}

// ---------------------------------------------------------------------------
// J) spatial attention via MFMA flash (unchanged from passing R9)
// ---------------------------------------------------------------------------
__global__ __launch_bounds__(256) void flashm_k(const s16* __restrict__ tTb, const float* __restrict__ rn2,
                                                float* __restrict__ partA, float* __restrict__ partL){
    __shared__ alignas(16) s16 kvb[128*36];      // [j][ci]   9216 B
    __shared__ alignas(16) s16 vts[32*132];      // [ci][j]   8448 B
    __shared__ alignas(16) s16 pls[4][16*132];   // per-wave P [m][j] 16896 B
    __shared__ float rnj[128];
    __shared__ float ri[64];
    const int ib = blockIdx.x, b = blockIdx.y, chunk = blockIdx.z;
    const int t = threadIdx.x, wv = t >> 6, lane = t & 63;
    const int lm = lane & 15, g = lane >> 4;
    const int i0 = ib*64;

    if (t < 64) ri[t] = rn2[b*4096 + i0 + t];
    s16x8 qf = *(const s16x8*)&tTb[(b*4096 + i0 + wv*16 + lm)*32 + g*8];
    __syncthreads();
    float rni4[4];
    #pragma unroll
    for (int r = 0; r < 4; ++r) rni4[r] = ri[wv*16 + g*4 + r];

    f32x4 oacc[2];
    oacc[0] = (f32x4){0.f,0.f,0.f,0.f};
    oacc[1] = (f32x4){0.f,0.f,0.f,0.f};
    float lacc[4] = {0.f,0.f,0.f,0.f};
    s16* pw = pls[wv];

    for (int jt = chunk*16; jt < chunk*16 + 16; ++jt){
        const int j0 = jt*128;
        __syncthreads();
        for (int gi = t; gi < 512; gi += 256){
            int j = gi >> 2, g8 = gi & 3;
            s16x8 v = *(const s16x8*)&tTb[(b*4096 + j0 + j)*32 + g8*8];
            s16* d = &kvb[j*36 + g8*8];
            *(s16x4*)d       = __builtin_shufflevector(v, v, 0,1,2,3);
            *(s16x4*)(d + 4) = __builtin_shufflevector(v, v, 4,5,6,7);
            #pragma unroll
            for (int e = 0; e < 8; ++e) vts[(g8*8 + e)*132 + j] = v[e];
        }
        if (t < 128) rnj[t] = rn2[b*4096 + j0 + t];
        __syncthreads();
        #pragma unroll
        for (int nt = 0; nt < 8; ++nt){
            const s16* bp = &kvb[(nt*16 + lm)*36 + g*8];
            s16x4 blo = *(const s16x4*)bp;
            s16x4 bhi = *(const s16x4*)(bp + 4);
            s16x8 bf = __builtin_shufflevector(blo, bhi, 0,1,2,3,4,5,6,7);
            f32x4 s = __builtin_amdgcn_mfma_f32_16x16x32_bf16(qf, bf,
                        (f32x4){0.f,0.f,0.f,0.f}, 0, 0, 0);
            float rj = rnj[nt*16 + lm];
            #pragma unroll
            for (int r = 0; r < 4; ++r){
                float e = __expf(s[r]*rni4[r]*rj);
                lacc[r] += e;
                pw[(g*4 + r)*132 + nt*16 + lm] = f2b(e);
            }
        }
        #pragma unroll
        for (int ks = 0; ks < 4; ++ks){
            const s16* ap = &pw[lm*132 + ks*32 + g*8];
            s16x4 alo = *(const s16x4*)ap;
            s16x4 ahi = *(const s16x4*)(ap + 4);
            s16x8 af = __builtin_shufflevector(alo, ahi, 0,1,2,3,4,5,6,7);
            #pragma unroll
            for (int n2 = 0; n2 < 2; ++n2){
                const s16* vp = &vts[(n2*16 + lm)*132 + ks*32 + g*8];
                s16x4 vlo = *(const s16x4*)vp;
                s16x4 vhi = *(const s16x4*)(vp + 4);
                s16x8 vf = __builtin_shufflevector(vlo, vhi, 0,1,2,3,4,5,6,7);
                oacc[n2] = __builtin_amdgcn_mfma_f32_16x16x32_bf16(af, vf, oacc[n2], 0, 0, 0);
            }
        }
    }
    #pragma unroll
    for (int r = 0; r < 4; ++r){
        float v = lacc[r];
        v += __shfl_xor(v, 1, 16); v += __shfl_xor(v, 2, 16);
        v += __shfl_xor(v, 4, 16); v += __shfl_xor(v, 8, 16);
        lacc[r] = v;
    }
    const int base = (b*2 + chunk)*4096 + i0 + wv*16;
    #pragma unroll
    for (int n2 = 0; n2 < 2; ++n2)
        #pragma unroll
        for (int r = 0; r < 4; ++r)
            partA[(base + g*4 + r)*32 + n2*16 + lm] = oacc[n2][r];
    if (lm == 0){
        #pragma unroll
        for (int r = 0; r < 4; ++r) partL[base + g*4 + r] = lacc[r];
    }
}

// ---------------------------------------------------------------------------
// J2) merge the 2 j-chunks: out3T = (sum_c partA) / (sum_c partL)
// ---------------------------------------------------------------------------
__global__ __launch_bounds__(256) void mrg2_k(const float* __restrict__ partA, const float* __restrict__ partL,
                                              float* __restrict__ out3T){
    int it = blockIdx.x, b = blockIdx.y, t = threadIdx.x;
    int r = t >> 2, g = t & 3;
    int i = it*64 + r;
    float l = partL[(b*2 + 0)*4096 + i] + partL[(b*2 + 1)*4096 + i];
    float inv = 1.f / l;
    float o[8];
    #pragma unroll
    for (int k = 0; k < 8; ++k)
        o[k] = partA[((b*2 + 0)*4096 + i)*32 + g*8 + k] + partA[((b*2 + 1)*4096 + i)*32 + g*8 + k];
    float* op = out3T + (b*4096 + i)*32 + g*8;
    #pragma unroll
    for (int k = 0; k < 8; ++k) op[k] = o[k]*inv;
}

// ---------------------------------------------------------------------------
// K) out5 = w3 @ concat(out2,out3) + b3 + t
// ---------------------------------------------------------------------------
__global__ __launch_bounds__(256) void out5_k(const float* __restrict__ out2, const float* __restrict__ out3T,
                                              const float* __restrict__ tbuf, const float* __restrict__ w3,
                                              const float* __restrict__ b3, float* __restrict__ out5){
    __shared__ float w3T[64*32];
    int pt = blockIdx.x, b = blockIdx.y, t = threadIdx.x;
    for (int i = t; i < 2048; i += 256){
        int j = i >> 5, cc = i & 31;
        w3T[i] = w3[cc*64 + j];
    }
    __syncthreads();
    int p = pt*256 + t;
    float acc[32];
    #pragma unroll
    for (int cc = 0; cc < 32; ++cc) acc[cc] = b3[cc] + tbuf[(b*32+cc)*4096 + p];
    for (int j = 0; j < 32; ++j){
        float v = out2[(b*32+j)*4096 + p];
        #pragma unroll
        for (int q = 0; q < 8; ++q){
            float4 a = *(const float4*)&w3T[j*32 + q*4];
            acc[q*4] += a.x*v; acc[q*4+1] += a.y*v; acc[q*4+2] += a.z*v; acc[q*4+3] += a.w*v;
        }
    }
    const float* o3 = out3T + (b*4096 + p)*32;
    float v3[32];
    #pragma unroll
    for (int q = 0; q < 8; ++q){
        float4 v = *(const float4*)&o3[q*4];
        v3[q*4]=v.x; v3[q*4+1]=v.y; v3[q*4+2]=v.z; v3[q*4+3]=v.w;
    }
    #pragma unroll
    for (int j = 0; j < 32; ++j){
        float v = v3[j];
        #pragma unroll
        for (int q = 0; q < 8; ++q){
            float4 a = *(const float4*)&w3T[(32+j)*32 + q*4];
            acc[q*4] += a.x*v; acc[q*4+1] += a.y*v; acc[q*4+2] += a.z*v; acc[q*4+3] += a.w*v;
        }
    }
    #pragma unroll
    for (int cc = 0; cc < 32; ++cc) out5[(b*32+cc)*4096 + p] = acc[cc];
}

// ---------------------------------------------------------------------------
// L) out = w4 @ out5 + b4  (fp32 store)
// ---------------------------------------------------------------------------
__global__ __launch_bounds__(256) void final_k(const float* __restrict__ out5, const float* __restrict__ w4,
                                               const float* __restrict__ b4, float* __restrict__ out){
    __shared__ float w4T[32*64];
    int pt = blockIdx.x, cog = blockIdx.y, b = blockIdx.z, t = threadIdx.x;
    for (int i = t; i < 2048; i += 256){
        int cc = i >> 6, co = i & 63;
        w4T[i] = w4[(cog*64+co)*32 + cc];
    }
    __syncthreads();
    int p = pt*256 + t;
    float acc[64];
    #pragma unroll
    for (int co = 0; co < 64; ++co) acc[co] = b4[cog*64+co];
    for (int cc = 0; cc < 32; ++cc){
        float v = out5[(b*32+cc)*4096 + p];
        #pragma unroll
        for (int q = 0; q < 16; ++q){
            float4 a = *(const float4*)&w4T[cc*64 + q*4];
            acc[q*4] += a.x*v; acc[q*4+1] += a.y*v; acc[q*4+2] += a.z*v; acc[q*4+3] += a.w*v;
        }
    }
    #pragma unroll
    for (int co = 0; co < 64; ++co)
        out[(b*256 + cog*64 + co)*4096 + p] = acc[co];
}

// ---------------------------------------------------------------------------
// Workspace layout (bytes), peak ~19.0 MB:
//   [0,        8388608)  xcl -> out1 -> gram part / flash partA (4 MB)
//   [8388608, 16777216)  y0  -> attn fp32 region (tbuf/tTb/out2/out3T)
//   [16777216,17956864)  wpk -> partL -> out5
// ---------------------------------------------------------------------------
extern "C" void kernel_launch(void* const* d_in, const int* in_sizes, int n_in,
                              void* d_out, int out_size, void* d_ws, size_t ws_size,
                              hipStream_t stream) {
    const float* x      = (const float*)d_in[0];
    const float* w_conv = (const float*)d_in[1];
    const float* b_conv = (const float*)d_in[2];
    const float* w01 = (const float*)d_in[3];  const float* b01 = (const float*)d_in[4];
    const float* w02 = (const float*)d_in[5];  const float* b02 = (const float*)d_in[6];
    const float* w11 = (const float*)d_in[7];  const float* b11 = (const float*)d_in[8];
    const float* w12 = (const float*)d_in[9];  const float* b12 = (const float*)d_in[10];
    const float* w21 = (const float*)d_in[11]; const float* b21 = (const float*)d_in[12];
    const float* w22 = (const float*)d_in[13]; const float* b22 = (const float*)d_in[14];
    const float* w_proj = (const float*)d_in[15]; const float* b_proj = (const float*)d_in[16];
    const float* w3 = (const float*)d_in[17]; const float* b3 = (const float*)d_in[18];
    const float* w4 = (const float*)d_in[19]; const float* b4 = (const float*)d_in[20];

    char* wsb = (char*)d_ws;
    s16*   xcl  = (s16*)wsb;                        // 4,194,304 s16 (conv input)
    bf16*  out1 = (bf16*)wsb;                       // same slot, after conv
    bf16*  y0   = (bf16*)(wsb + 8388608);           // 4,194,304 bf16
    s16*   wpk  = (s16*)(wsb + 16777216);           // 589,824 s16
    float* f    = (float*)d_ws;
    float* part   = f + 0;         // gram partials (out1 dead after proj)
    float* partA  = f + 0;         // flash partials 2x4x4096x32 f = 4 MB
    float* tbuf   = f + 2097152;   // byte  8,388,608 (overlays dead y0)
    s16*   tTb    = (s16*)(wsb + 10485760);         // 524,288 s16 = 1 MB
    float* out2   = f + 3145728;   // byte 12,582,912
    float* out3T  = f + 3670016;   // byte 14,680,064
    float* out5   = f + 4194304;   // byte 16,777,216 (wpk dead by then)
    float* partL  = f + 4194304;   // 32,768 f in out5 slot (dead until out5_k)
    float* rn1    = f + 4718592;   // byte 18,874,368
    float* attn1T = f + 4722816;
    float* rn2    = f + 4726912;   // ends at byte 18,973,184

    xtrans_k<<<dim3(64, 4), 256, 0, stream>>>(x, xcl);
    wpack_k<<<dim3(2304), 256, 0, stream>>>(w_conv, wpk);
    conv3x3m_k<<<dim3(128, 4), 256, 0, stream>>>(xcl, wpk, b_conv, y0);
    sepconv_k<<<dim3(1024), 256, 0, stream>>>(y0, w01, b01, w02, b02,
                                              w11, b11, w12, b12,
                                              w21, b21, w22, b22, out1);
    proj_k<<<dim3(64, 4), 256, 0, stream>>>(out1, w_proj, b_proj, tbuf, tTb, rn2);
    rn1_k<<<dim3(128), 256, 0, stream>>>(tbuf, rn1);
    gram2_k<<<dim3(32, 4), 256, 0, stream>>>(tbuf, part);
    attn1_k<<<dim3(32, 4), 64, 0, stream>>>(part, rn1, attn1T);
    out2_k<<<dim3(16, 4), 256, 0, stream>>>(tbuf, attn1T, out2);
    flashm_k<<<dim3(64, 4, 2), 256, 0, stream>>>(tTb, rn2, partA, partL);
    mrg2_k<<<dim3(64, 4), 256, 0, stream>>>(partA, partL, out3T);
    out5_k<<<dim3(16, 4), 256, 0, stream>>>(out2, out3T, tbuf, w3, b3, out5);
    final_k<<<dim3(16, 4, 4), 256, 0, stream>>>(out5, w4, b4, (float*)d_out);
}

// Round 11
// 323.774 us; speedup vs baseline: 5.7715x; 1.0356x over previous
//
#include <hip/hip_runtime.h>
#include <hip/hip_bf16.h>

typedef __hip_bfloat16 bf16;
typedef short s16;
typedef __attribute__((ext_vector_type(4))) short s16x4;
typedef __attribute__((ext_vector_type(8))) short s16x8;
typedef __attribute__((ext_vector_type(4))) float f32x4;

__device__ __forceinline__ s16 f2b(float f){
    unsigned u = __float_as_uint(f);
    unsigned r = (u + 0x7FFFu + ((u >> 16) & 1u)) >> 16;
    return (s16)r;
}
__device__ __forceinline__ float b2f_bits(s16 v){
    return __uint_as_float(((unsigned)(unsigned short)v) << 16);
}

// ---------------------------------------------------------------------------
// A1) x (fp32 NCHW) -> xcl (bf16-bits channels-last [b][h][w][ci])
// ---------------------------------------------------------------------------
__global__ __launch_bounds__(256) void xtrans_k(const float* __restrict__ x, s16* __restrict__ xcl){
    __shared__ s16 lb[64][258];
    int h = blockIdx.x, b = blockIdx.y, t = threadIdx.x;
    for (int i = t; i < 16384; i += 256){
        int ci = i >> 6, w = i & 63;
        lb[w][ci] = f2b(x[((b*256 + ci)*64 + h)*64 + w]);
    }
    __syncthreads();
    for (int i = t; i < 16384; i += 256){
        int w = i >> 8, ci = i & 255;
        xcl[(b*4096 + h*64 + w)*256 + ci] = lb[w][ci];
    }
}

// ---------------------------------------------------------------------------
// A2) w_conv (fp32 [co][ci][3][3]) -> wpk (bf16-bits [cc8][tap9][co256][ci32])
// ---------------------------------------------------------------------------
__global__ __launch_bounds__(256) void wpack_k(const float* __restrict__ w, s16* __restrict__ wpk){
    int idx = blockIdx.x*256 + threadIdx.x;      // < 589824
    int cil = idx & 31;
    int r   = idx >> 5;
    int co  = r & 255;
    int r2  = r >> 8;
    int tap = r2 % 9, cc = r2 / 9;
    wpk[idx] = f2b(w[(co*256 + cc*32 + cil)*9 + tap]);
}

// ---------------------------------------------------------------------------
// B) 3x3 conv 256->256 as MFMA implicit GEMM (unchanged from passing R10)
// ---------------------------------------------------------------------------
__global__ __launch_bounds__(256) void conv3x3m_k(const s16* __restrict__ xcl,
        const s16* __restrict__ wpk, const float* __restrict__ bias,
        bf16* __restrict__ y0){
    __shared__ alignas(16) s16 smem[30240];      // 60.5 KB
    s16* xls = smem;                             // [4 rows][66 w][36 ci-pad]
    s16* wls = smem + 9504;                      // [9 tap][64 co][36 ci-pad]
    const int sp = blockIdx.x, cog = blockIdx.y;
    const int b = sp >> 5, h0 = (sp & 31)*2;
    const int t = threadIdx.x;
    const int wv = t >> 6, lane = t & 63;
    const int lm = lane & 15, g = lane >> 4;

    f32x4 acc[2][4];
    #pragma unroll
    for (int mi = 0; mi < 2; ++mi)
        #pragma unroll
        for (int ni = 0; ni < 4; ++ni) acc[mi][ni] = (f32x4){0.f,0.f,0.f,0.f};

    for (int cc = 0; cc < 8; ++cc){
        __syncthreads();
        for (int i = t; i < 1056; i += 256){
            int g8 = i & 3, wi = (i>>2) % 66, r = (i>>2) / 66;
            int h = h0 - 1 + r, w = wi - 1;
            s16x8 v = {0,0,0,0,0,0,0,0};
            if (h >= 0 && h < 64 && w >= 0 && w < 64)
                v = *(const s16x8*)&xcl[(b*4096 + h*64 + w)*256 + cc*32 + g8*8];
            s16* d = &xls[(r*66 + wi)*36 + g8*8];
            *(s16x4*)d       = __builtin_shufflevector(v, v, 0,1,2,3);
            *(s16x4*)(d + 4) = __builtin_shufflevector(v, v, 4,5,6,7);
        }
        for (int i = t; i < 2304; i += 256){
            int g8 = i & 3, co = (i>>2) & 63, tap = i >> 8;
            s16x8 v = *(const s16x8*)&wpk[((cc*9 + tap)*256 + cog*64 + co)*32 + g8*8];
            s16* d = &wls[(tap*64 + co)*36 + g8*8];
            *(s16x4*)d       = __builtin_shufflevector(v, v, 0,1,2,3);
            *(s16x4*)(d + 4) = __builtin_shufflevector(v, v, 4,5,6,7);
        }
        __syncthreads();
        #pragma unroll
        for (int tap = 0; tap < 9; ++tap){
            const int kh = tap/3, kw = tap%3;
            s16x8 bfr[4], afr[2];
            #pragma unroll
            for (int ni = 0; ni < 4; ++ni){
                const s16* p = &wls[(tap*64 + ni*16 + lm)*36 + g*8];
                s16x4 lo = *(const s16x4*)p;
                s16x4 hi = *(const s16x4*)(p + 4);
                bfr[ni] = __builtin_shufflevector(lo, hi, 0,1,2,3,4,5,6,7);
            }
            #pragma unroll
            for (int mi = 0; mi < 2; ++mi){
                int m = (wv*2 + mi)*16 + lm;
                int hr = m >> 6, ww = m & 63;
                const s16* p = &xls[((hr + kh)*66 + (ww + kw))*36 + g*8];
                s16x4 lo = *(const s16x4*)p;
                s16x4 hi = *(const s16x4*)(p + 4);
                afr[mi] = __builtin_shufflevector(lo, hi, 0,1,2,3,4,5,6,7);
            }
            #pragma unroll
            for (int mi = 0; mi < 2; ++mi)
                #pragma unroll
                for (int ni = 0; ni < 4; ++ni)
                    acc[mi][ni] = __builtin_amdgcn_mfma_f32_16x16x32_bf16(
                        afr[mi], bfr[ni], acc[mi][ni], 0, 0, 0);
        }
    }
    __syncthreads();
    float* ot = (float*)smem;                    // [64 co][132 m-pad]
    #pragma unroll
    for (int mi = 0; mi < 2; ++mi)
        #pragma unroll
        for (int ni = 0; ni < 4; ++ni)
            #pragma unroll
            for (int r = 0; r < 4; ++r){
                int m  = (wv*2 + mi)*16 + g*4 + r;
                int co = ni*16 + lm;
                ot[co*132 + m] = acc[mi][ni][r];
            }
    __syncthreads();
    for (int i = t; i < 8192; i += 256){
        int co = i >> 7, m = i & 127;
        float v = ot[co*132 + m] + bias[cog*64 + co];
        y0[((b*256 + cog*64 + co)*64 + h0 + (m>>6))*64 + (m & 63)] = __float2bfloat16(v);
    }
}

// ---------------------------------------------------------------------------
// C) fused separable depthwise (7/11/21) + residual, sliding-window (R10)
// ---------------------------------------------------------------------------
template<int K>
__device__ __forceinline__ void sep_branch(const float (*__restrict__ pl)[65], float (*__restrict__ hp)[65],
                                           int c, int t,
                                           const float* __restrict__ wh, const float* __restrict__ bh,
                                           const float* __restrict__ wv, const float* __restrict__ bv,
                                           float* acc){
    constexpr int P = K/2;
    constexpr int W = 16 + 2*P;
    float wk[K];
    #pragma unroll
    for (int j = 0; j < K; ++j) wk[j] = wh[c*K + j];
    float bhv = bh[c];
    {
        int h = t >> 2, w0 = (t & 3)*16;
        float win[W];
        #pragma unroll
        for (int j = 0; j < W; ++j){
            int ww = w0 - P + j;
            win[j] = (ww >= 0 && ww < 64) ? pl[h][ww] : 0.f;
        }
        __syncthreads();                 // prev-branch hp reads complete
        #pragma unroll
        for (int i = 0; i < 16; ++i){
            float s = bhv;
            #pragma unroll
            for (int k = 0; k < K; ++k) s += win[i+k]*wk[k];
            hp[h][w0 + i] = s;
        }
    }
    float vk[K];
    #pragma unroll
    for (int j = 0; j < K; ++j) vk[j] = wv[c*K + j];
    float bvv = bv[c];
    __syncthreads();                     // hp writes visible
    {
        int w = t & 63, h0 = (t >> 6)*16;
        float win[W];
        #pragma unroll
        for (int j = 0; j < W; ++j){
            int hh = h0 - P + j;
            win[j] = (hh >= 0 && hh < 64) ? hp[hh][w] : 0.f;
        }
        #pragma unroll
        for (int i = 0; i < 16; ++i){
            float s = bvv;
            #pragma unroll
            for (int k = 0; k < K; ++k) s += win[i+k]*vk[k];
            acc[i] += s;
        }
    }
}

__global__ __launch_bounds__(256) void sepconv_k(const bf16* __restrict__ y0,
        const float* __restrict__ w01, const float* __restrict__ b01,
        const float* __restrict__ w02, const float* __restrict__ b02,
        const float* __restrict__ w11, const float* __restrict__ b11,
        const float* __restrict__ w12, const float* __restrict__ b12,
        const float* __restrict__ w21, const float* __restrict__ b21,
        const float* __restrict__ w22, const float* __restrict__ b22,
        bf16* __restrict__ out1){
    __shared__ float pl[64][65];
    __shared__ float hp[64][65];
    int bc = blockIdx.x;             // b*256 + c
    int c = bc & 255;
    int t = threadIdx.x;
    const bf16* src = y0 + bc*4096;
    for (int i = t; i < 4096; i += 256) pl[i>>6][i&63] = __bfloat162float(src[i]);
    __syncthreads();
    float acc[16];
    #pragma unroll
    for (int k = 0; k < 16; ++k) acc[k] = 0.f;
    sep_branch<7 >(pl, hp, c, t, w01, b01, w02, b02, acc);
    sep_branch<11>(pl, hp, c, t, w11, b11, w12, b12, acc);
    sep_branch<21>(pl, hp, c, t, w21, b21, w22, b22, acc);
    bf16* dst = out1 + bc*4096;
    {
        int w = t & 63, h0 = (t >> 6)*16;
        #pragma unroll
        for (int i = 0; i < 16; ++i)
            dst[(h0 + i)*64 + w] = __float2bfloat16(acc[i] + pl[h0 + i][w]);
    }
}

// ---------------------------------------------------------------------------
// E) 1x1 projection 256->32, 4-way ci-split (unchanged from passing R10)
// ---------------------------------------------------------------------------
__global__ __launch_bounds__(256) void proj_k(const bf16* __restrict__ out1, const float* __restrict__ wp,
                                              const float* __restrict__ bp, float* __restrict__ tbuf,
                                              s16* __restrict__ tTb, float* __restrict__ rn2){
    __shared__ float wl[256*32];         // [ci][cc] fp32, 32 KB
    __shared__ s16 part[4][64][36];      // bf16 partials, 18.4 KB
    int pt = blockIdx.x, b = blockIdx.y, t = threadIdx.x;
    int q = t >> 6, lane = t & 63;
    for (int i = t; i < 8192; i += 256){
        int ci = i >> 5, cc = i & 31;
        wl[ci*32 + cc] = wp[cc*256 + ci];
    }
    __syncthreads();
    int p = pt*64 + lane;
    float acc[32] = {};
    const bf16* xb = out1 + b*1048576 + p;
    for (int ci = q*64; ci < q*64 + 64; ++ci){
        float v = __bfloat162float(xb[ci*4096]);
        const float* wr = &wl[ci*32];
        #pragma unroll
        for (int c8 = 0; c8 < 8; ++c8){
            float4 w4 = *(const float4*)&wr[c8*4];
            acc[c8*4+0] += w4.x*v; acc[c8*4+1] += w4.y*v;
            acc[c8*4+2] += w4.z*v; acc[c8*4+3] += w4.w*v;
        }
    }
    #pragma unroll
    for (int cc = 0; cc < 32; ++cc) part[q][lane][cc] = f2b(acc[cc]);
    __syncthreads();
    int p_loc = t >> 2, qq = t & 3;
    int pg = pt*64 + p_loc;
    float a8[8];
    float ss = 0.f;
    #pragma unroll
    for (int c = 0; c < 8; ++c){
        int cc = qq*8 + c;
        float v = b2f_bits(part[0][p_loc][cc]) + b2f_bits(part[1][p_loc][cc])
                + b2f_bits(part[2][p_loc][cc]) + b2f_bits(part[3][p_loc][cc]) + bp[cc];
        a8[c] = v;
        ss += v*v;
    }
    ss += __shfl_xor(ss, 1, 4);
    ss += __shfl_xor(ss, 2, 4);
    if (qq == 0) rn2[b*4096 + pg] = 1.f / fmaxf(sqrtf(ss), 1e-12f);
    #pragma unroll
    for (int c = 0; c < 8; ++c) tbuf[(b*32 + qq*8 + c)*4096 + pg] = a8[c];
    s16x8 o8;
    #pragma unroll
    for (int c = 0; c < 8; ++c) o8[c] = f2b(a8[c]);
    *(s16x8*)&tTb[(b*4096 + pg)*32 + qq*8] = o8;
}

// ---------------------------------------------------------------------------
// G1) Gram partials, p-sliced, conflict-free transposed LDS tile
// ---------------------------------------------------------------------------
__global__ __launch_bounds__(256) void gram2_k(const float* __restrict__ tbuf, float* __restrict__ part){
    __shared__ float tl[128][33];
    int ps = blockIdx.x, b = blockIdx.y, t = threadIdx.x;
    for (int idx = t; idx < 4096; idx += 256){
        int cc = idx >> 7, pp = idx & 127;
        tl[pp][cc] = tbuf[(b*32+cc)*4096 + ps*128 + pp];
    }
    __syncthreads();
    #pragma unroll
    for (int k = 0; k < 4; ++k){
        int pair = k*256 + t;
        int i = pair >> 5, j = pair & 31;
        float s = 0.f;
        #pragma unroll 4
        for (int pp = 0; pp < 128; ++pp) s += tl[pp][i]*tl[pp][j];
        part[(b*32+ps)*1024 + pair] = s;
    }
}

// ---------------------------------------------------------------------------
// G2) attn1 softmax; rn1 derived inline from the gram diagonal (rn1_k gone)
// ---------------------------------------------------------------------------
__global__ __launch_bounds__(64) void attn1_k(const float* __restrict__ part,
                                              float* __restrict__ attn1T){
    int i = blockIdx.x, b = blockIdx.y, j = threadIdx.x;
    float gij = 0.f, gjj = 0.f;
    if (j < 32){
        #pragma unroll 8
        for (int ps = 0; ps < 32; ++ps){
            const float* pp = part + (b*32+ps)*1024;
            gij += pp[i*32 + j];
            gjj += pp[j*33];
        }
    }
    float rnj = 1.f / fmaxf(sqrtf(gjj), 1e-12f);
    float rni = __shfl(rnj, i, 64);
    float e = (j < 32) ? __expf(rni*rnj*gij) : 0.f;
    float sum = e;
    #pragma unroll
    for (int o = 32; o > 0; o >>= 1) sum += __shfl_xor(sum, o, 64);
    if (j < 32) attn1T[b*1024 + j*32 + i] = e / sum;
}

// ---------------------------------------------------------------------------
// G3) fold channel-attention + both 1x1 convs into per-batch matrices:
//     w3a = w3[:, :32] @ attn1;  WtT[b][j][co] = (w4@w3a + w4)[co][j]
//     WoT[b][j][co] = (w4@w3b)[co][j];  bf[b][co] = w4@b3 + b4
//     Exact fp32 reassociation of (out2_k -> out5_k -> final_k).
// ---------------------------------------------------------------------------
__global__ __launch_bounds__(256) void fold_k(const float* __restrict__ attn1T,
        const float* __restrict__ w3, const float* __restrict__ b3,
        const float* __restrict__ w4, const float* __restrict__ b4,
        float* __restrict__ WtT, float* __restrict__ WoT, float* __restrict__ bfo){
    __shared__ float a1[1024];     // attn1[i][j]
    __shared__ float w3a[1024];    // [cc][j]
    __shared__ float w3bs[1024];   // [cc][j]
    int b = blockIdx.x, t = threadIdx.x;
    for (int idx = t; idx < 1024; idx += 256){
        int i = idx >> 5, j = idx & 31;
        a1[idx]   = attn1T[b*1024 + j*32 + i];
        w3bs[idx] = w3[i*64 + 32 + j];
    }
    __syncthreads();
    for (int idx = t; idx < 1024; idx += 256){
        int cc = idx >> 5, j = idx & 31;
        float s = 0.f;
        #pragma unroll 8
        for (int i = 0; i < 32; ++i) s += w3[cc*64 + i]*a1[i*32 + j];
        w3a[idx] = s;
    }
    __syncthreads();
    int co = t;
    float w4r[32];
    #pragma unroll
    for (int cc = 0; cc < 32; ++cc) w4r[cc] = w4[co*32 + cc];
    float bfv = b4[co];
    #pragma unroll
    for (int cc = 0; cc < 32; ++cc) bfv += w4r[cc]*b3[cc];
    bfo[b*256 + co] = bfv;
    for (int j = 0; j < 32; ++j){
        float st = w4r[j];           // w4 identity term = +t residual through w4
        float so = 0.f;
        #pragma unroll 8
        for (int cc = 0; cc < 32; ++cc){
            st += w4r[cc]*w3a[cc*32 + j];
            so += w4r[cc]*w3bs[cc*32 + j];
        }
        WtT[(b*32 + j)*256 + co] = st;
        WoT[(b*32 + j)*256 + co] = so;
    }
}

// ---------------------------------------------------------------------------
// J) spatial attention via MFMA flash (unchanged from passing R10)
// ---------------------------------------------------------------------------
__global__ __launch_bounds__(256) void flashm_k(const s16* __restrict__ tTb, const float* __restrict__ rn2,
                                                float* __restrict__ partA, float* __restrict__ partL){
    __shared__ alignas(16) s16 kvb[128*36];      // [j][ci]   9216 B
    __shared__ alignas(16) s16 vts[32*132];      // [ci][j]   8448 B
    __shared__ alignas(16) s16 pls[4][16*132];   // per-wave P [m][j] 16896 B
    __shared__ float rnj[128];
    __shared__ float ri[64];
    const int ib = blockIdx.x, b = blockIdx.y, chunk = blockIdx.z;
    const int t = threadIdx.x, wv = t >> 6, lane = t & 63;
    const int lm = lane & 15, g = lane >> 4;
    const int i0 = ib*64;

    if (t < 64) ri[t] = rn2[b*4096 + i0 + t];
    s16x8 qf = *(const s16x8*)&tTb[(b*4096 + i0 + wv*16 + lm)*32 + g*8];
    __syncthreads();
    float rni4[4];
    #pragma unroll
    for (int r = 0; r < 4; ++r) rni4[r] = ri[wv*16 + g*4 + r];

    f32x4 oacc[2];
    oacc[0] = (f32x4){0.f,0.f,0.f,0.f};
    oacc[1] = (f32x4){0.f,0.f,0.f,0.f};
    float lacc[4] = {0.f,0.f,0.f,0.f};
    s16* pw = pls[wv];

    for (int jt = chunk*16; jt < chunk*16 + 16; ++jt){
        const int j0 = jt*128;
        __syncthreads();
        for (int gi = t; gi < 512; gi += 256){
            int j = gi >> 2, g8 = gi & 3;
            s16x8 v = *(const s16x8*)&tTb[(b*4096 + j0 + j)*32 + g8*8];
            s16* d = &kvb[j*36 + g8*8];
            *(s16x4*)d       = __builtin_shufflevector(v, v, 0,1,2,3);
            *(s16x4*)(d + 4) = __builtin_shufflevector(v, v, 4,5,6,7);
            #pragma unroll
            for (int e = 0; e < 8; ++e) vts[(g8*8 + e)*132 + j] = v[e];
        }
        if (t < 128) rnj[t] = rn2[b*4096 + j0 + t];
        __syncthreads();
        #pragma unroll
        for (int nt = 0; nt < 8; ++nt){
            const s16* bp = &kvb[(nt*16 + lm)*36 + g*8];
            s16x4 blo = *(const s16x4*)bp;
            s16x4 bhi = *(const s16x4*)(bp + 4);
            s16x8 bf = __builtin_shufflevector(blo, bhi, 0,1,2,3,4,5,6,7);
            f32x4 s = __builtin_amdgcn_mfma_f32_16x16x32_bf16(qf, bf,
                        (f32x4){0.f,0.f,0.f,0.f}, 0, 0, 0);
            float rj = rnj[nt*16 + lm];
            #pragma unroll
            for (int r = 0; r < 4; ++r){
                float e = __expf(s[r]*rni4[r]*rj);
                lacc[r] += e;
                pw[(g*4 + r)*132 + nt*16 + lm] = f2b(e);
            }
        }
        #pragma unroll
        for (int ks = 0; ks < 4; ++ks){
            const s16* ap = &pw[lm*132 + ks*32 + g*8];
            s16x4 alo = *(const s16x4*)ap;
            s16x4 ahi = *(const s16x4*)(ap + 4);
            s16x8 af = __builtin_shufflevector(alo, ahi, 0,1,2,3,4,5,6,7);
            #pragma unroll
            for (int n2 = 0; n2 < 2; ++n2){
                const s16* vp = &vts[(n2*16 + lm)*132 + ks*32 + g*8];
                s16x4 vlo = *(const s16x4*)vp;
                s16x4 vhi = *(const s16x4*)(vp + 4);
                s16x8 vf = __builtin_shufflevector(vlo, vhi, 0,1,2,3,4,5,6,7);
                oacc[n2] = __builtin_amdgcn_mfma_f32_16x16x32_bf16(af, vf, oacc[n2], 0, 0, 0);
            }
        }
    }
    #pragma unroll
    for (int r = 0; r < 4; ++r){
        float v = lacc[r];
        v += __shfl_xor(v, 1, 16); v += __shfl_xor(v, 2, 16);
        v += __shfl_xor(v, 4, 16); v += __shfl_xor(v, 8, 16);
        lacc[r] = v;
    }
    const int base = (b*2 + chunk)*4096 + i0 + wv*16;
    #pragma unroll
    for (int n2 = 0; n2 < 2; ++n2)
        #pragma unroll
        for (int r = 0; r < 4; ++r)
            partA[(base + g*4 + r)*32 + n2*16 + lm] = oacc[n2][r];
    if (lm == 0){
        #pragma unroll
        for (int r = 0; r < 4; ++r) partL[base + g*4 + r] = lacc[r];
    }
}

// ---------------------------------------------------------------------------
// L) fused epilogue: out = WtT@t + WoT@out3 + bf, out3 merged inline from
//    flash partials (mrg2_k removed).  W reads wave-uniform -> scalar loads.
// ---------------------------------------------------------------------------
__global__ __launch_bounds__(256) void finalfuse_k(const float* __restrict__ tbuf,
        const float* __restrict__ partA, const float* __restrict__ partL,
        const float* __restrict__ WtT, const float* __restrict__ WoT,
        const float* __restrict__ bfo, float* __restrict__ out){
    int pt = blockIdx.x, cog = blockIdx.y, b = blockIdx.z, t = threadIdx.x;
    int p = pt*256 + t;
    float l = partL[(b*2 + 0)*4096 + p] + partL[(b*2 + 1)*4096 + p];
    float inv = 1.f / l;
    const float* pa0 = partA + ((b*2 + 0)*4096 + p)*32;
    const float* pa1 = partA + ((b*2 + 1)*4096 + p)*32;
    float v3[32];
    #pragma unroll
    for (int q = 0; q < 8; ++q){
        float4 a = *(const float4*)&pa0[q*4];
        float4 c = *(const float4*)&pa1[q*4];
        v3[q*4+0] = (a.x + c.x)*inv; v3[q*4+1] = (a.y + c.y)*inv;
        v3[q*4+2] = (a.z + c.z)*inv; v3[q*4+3] = (a.w + c.w)*inv;
    }
    float acc[32];
    #pragma unroll
    for (int co = 0; co < 32; ++co) acc[co] = bfo[b*256 + cog*32 + co];
    for (int j = 0; j < 32; ++j){
        float vt = tbuf[(b*32 + j)*4096 + p];
        float vo = v3[j];
        const float* wtr = WtT + (b*32 + j)*256 + cog*32;   // wave-uniform
        const float* wor = WoT + (b*32 + j)*256 + cog*32;   // wave-uniform
        #pragma unroll
        for (int co = 0; co < 32; ++co) acc[co] += wtr[co]*vt + wor[co]*vo;
    }
    #pragma unroll
    for (int co = 0; co < 32; ++co)
        out[((b*256 + cog*32 + co)*4096) + p] = acc[co];
}

// ---------------------------------------------------------------------------
// Workspace layout (bytes), peak ~19.0 MB:
//   [0,        8388608)  xcl -> out1 -> gram part -> flash partA (4 MB)
//   [8388608, 16777216)  y0  -> tbuf / tTb
//   [12582912, ...)      WtT/WoT/bf (260 KB)
//   [16777216, ...)      wpk -> partL;  attn1T/rn2 near byte 18.9 MB
// ---------------------------------------------------------------------------
extern "C" void kernel_launch(void* const* d_in, const int* in_sizes, int n_in,
                              void* d_out, int out_size, void* d_ws, size_t ws_size,
                              hipStream_t stream) {
    const float* x      = (const float*)d_in[0];
    const float* w_conv = (const float*)d_in[1];
    const float* b_conv = (const float*)d_in[2];
    const float* w01 = (const float*)d_in[3];  const float* b01 = (const float*)d_in[4];
    const float* w02 = (const float*)d_in[5];  const float* b02 = (const float*)d_in[6];
    const float* w11 = (const float*)d_in[7];  const float* b11 = (const float*)d_in[8];
    const float* w12 = (const float*)d_in[9];  const float* b12 = (const float*)d_in[10];
    const float* w21 = (const float*)d_in[11]; const float* b21 = (const float*)d_in[12];
    const float* w22 = (const float*)d_in[13]; const float* b22 = (const float*)d_in[14];
    const float* w_proj = (const float*)d_in[15]; const float* b_proj = (const float*)d_in[16];
    const float* w3 = (const float*)d_in[17]; const float* b3 = (const float*)d_in[18];
    const float* w4 = (const float*)d_in[19]; const float* b4 = (const float*)d_in[20];

    char* wsb = (char*)d_ws;
    s16*   xcl  = (s16*)wsb;                        // 4,194,304 s16 (conv input)
    bf16*  out1 = (bf16*)wsb;                       // same slot, after conv
    bf16*  y0   = (bf16*)(wsb + 8388608);           // 4,194,304 bf16
    s16*   wpk  = (s16*)(wsb + 16777216);           // 589,824 s16
    float* f    = (float*)d_ws;
    float* part   = f + 0;         // gram partials (out1 dead after proj)
    float* partA  = f + 0;         // flash partials 2x4x4096x32 f = 4 MB
    float* tbuf   = f + 2097152;   // byte  8,388,608 (overlays dead y0)
    s16*   tTb    = (s16*)(wsb + 10485760);         // 524,288 s16 = 1 MB
    float* WtT    = f + 3145728;   // byte 12,582,912  (4x32x256 f)
    float* WoT    = f + 3178496;
    float* bfo    = f + 3211264;
    float* partL  = f + 4194304;   // byte 16,777,216 (wpk dead by flashm)
    float* attn1T = f + 4722816;
    float* rn2    = f + 4726912;

    xtrans_k<<<dim3(64, 4), 256, 0, stream>>>(x, xcl);
    wpack_k<<<dim3(2304), 256, 0, stream>>>(w_conv, wpk);
    conv3x3m_k<<<dim3(128, 4), 256, 0, stream>>>(xcl, wpk, b_conv, y0);
    sepconv_k<<<dim3(1024), 256, 0, stream>>>(y0, w01, b01, w02, b02,
                                              w11, b11, w12, b12,
                                              w21, b21, w22, b22, out1);
    proj_k<<<dim3(64, 4), 256, 0, stream>>>(out1, w_proj, b_proj, tbuf, tTb, rn2);
    gram2_k<<<dim3(32, 4), 256, 0, stream>>>(tbuf, part);
    attn1_k<<<dim3(32, 4), 64, 0, stream>>>(part, attn1T);
    fold_k<<<dim3(4), 256, 0, stream>>>(attn1T, w3, b3, w4, b4, WtT, WoT, bfo);
    flashm_k<<<dim3(64, 4, 2), 256, 0, stream>>>(tTb, rn2, partA, partL);
    finalfuse_k<<<dim3(16, 8, 4), 256, 0, stream>>>(tbuf, partA, partL, WtT, WoT, bfo,
                                                    (float*)d_out);
}

// Round 12
// 314.293 us; speedup vs baseline: 5.9457x; 1.0302x over previous
//
#include <hip/hip_runtime.h>
#include <hip/hip_bf16.h>

typedef __hip_bfloat16 bf16;
typedef short s16;
typedef __attribute__((ext_vector_type(4))) short s16x4;
typedef __attribute__((ext_vector_type(8))) short s16x8;
typedef __attribute__((ext_vector_type(4))) float f32x4;

__device__ __forceinline__ s16 f2b(float f){
    unsigned u = __float_as_uint(f);
    unsigned r = (u + 0x7FFFu + ((u >> 16) & 1u)) >> 16;
    return (s16)r;
}
__device__ __forceinline__ float b2f_bits(s16 v){
    return __uint_as_float(((unsigned)(unsigned short)v) << 16);
}

// ---------------------------------------------------------------------------
// A1) x (fp32 NCHW) -> xcl (bf16-bits channels-last [b][h][w][ci])
// ---------------------------------------------------------------------------
__global__ __launch_bounds__(256) void xtrans_k(const float* __restrict__ x, s16* __restrict__ xcl){
    __shared__ s16 lb[64][258];
    int h = blockIdx.x, b = blockIdx.y, t = threadIdx.x;
    for (int i = t; i < 16384; i += 256){
        int ci = i >> 6, w = i & 63;
        lb[w][ci] = f2b(x[((b*256 + ci)*64 + h)*64 + w]);
    }
    __syncthreads();
    for (int i = t; i < 16384; i += 256){
        int w = i >> 8, ci = i & 255;
        xcl[(b*4096 + h*64 + w)*256 + ci] = lb[w][ci];
    }
}

// ---------------------------------------------------------------------------
// A2) w_conv (fp32 [co][ci][3][3]) -> wpk (bf16-bits [cc8][tap9][co256][ci32])
// ---------------------------------------------------------------------------
__global__ __launch_bounds__(256) void wpack_k(const float* __restrict__ w, s16* __restrict__ wpk){
    int idx = blockIdx.x*256 + threadIdx.x;      // < 589824
    int cil = idx & 31;
    int r   = idx >> 5;
    int co  = r & 255;
    int r2  = r >> 8;
    int tap = r2 % 9, cc = r2 / 9;
    wpk[idx] = f2b(w[(co*256 + cc*32 + cil)*9 + tap]);
}

// ---------------------------------------------------------------------------
// B) 3x3 conv as MFMA implicit GEMM — M=64 retile, tap-row-grouped weights.
//    Block = 1 h-row x 64 w (M=64) x 64 co; grid (256 sp, 4 cog) = 1024
//    blocks -> 4 blocks/CU co-resident (LDS 33.8 KB).  Per cc chunk: stage
//    3 x-rows once; weights staged one kh-row (3 taps) at a time.
// ---------------------------------------------------------------------------
__global__ __launch_bounds__(256) void conv3x3m_k(const s16* __restrict__ xcl,
        const s16* __restrict__ wpk, const float* __restrict__ bias,
        bf16* __restrict__ y0){
    __shared__ alignas(16) s16 smem[16896];      // 33.8 KB (staging 28.1 / epi 17.2)
    s16* xls = smem;                             // [3 rows][66 w][36 ci-pad] = 7128
    s16* wls = smem + 7128;                      // [3 tap][64 co][36 ci-pad] = 6912
    const int sp = blockIdx.x, cog = blockIdx.y;
    const int b = sp >> 6, h0 = sp & 63;
    const int t = threadIdx.x;
    const int wv = t >> 6, lane = t & 63;
    const int lm = lane & 15, g = lane >> 4;

    f32x4 acc[4];
    #pragma unroll
    for (int ni = 0; ni < 4; ++ni) acc[ni] = (f32x4){0.f,0.f,0.f,0.f};

    for (int cc = 0; cc < 8; ++cc){
        __syncthreads();
        // stage x: rows h0-1..h0+1, w=-1..64, 32 ci (granules of 8 ci = 16B)
        for (int i = t; i < 792; i += 256){
            int g8 = i & 3, wi = (i>>2) % 66, r = (i>>2) / 66;
            int h = h0 - 1 + r, w = wi - 1;
            s16x8 v = {0,0,0,0,0,0,0,0};
            if (h >= 0 && h < 64 && w >= 0 && w < 64)
                v = *(const s16x8*)&xcl[(b*4096 + h*64 + w)*256 + cc*32 + g8*8];
            s16* d = &xls[(r*66 + wi)*36 + g8*8];
            *(s16x4*)d       = __builtin_shufflevector(v, v, 0,1,2,3);
            *(s16x4*)(d + 4) = __builtin_shufflevector(v, v, 4,5,6,7);
        }
        // stage w group 0 (taps 0..2)
        for (int i = t; i < 768; i += 256){
            int g8 = i & 3, co = (i>>2) & 63, tl = i >> 8;
            s16x8 v = *(const s16x8*)&wpk[((cc*9 + tl)*256 + cog*64 + co)*32 + g8*8];
            s16* d = &wls[(tl*64 + co)*36 + g8*8];
            *(s16x4*)d       = __builtin_shufflevector(v, v, 0,1,2,3);
            *(s16x4*)(d + 4) = __builtin_shufflevector(v, v, 4,5,6,7);
        }
        __syncthreads();
        for (int tg = 0; tg < 3; ++tg){          // tg == kh (weights for row kh)
            #pragma unroll
            for (int tl = 0; tl < 3; ++tl){      // tl == kw
                const s16* pa = &xls[(tg*66 + wv*16 + lm + tl)*36 + g*8];
                s16x4 alo = *(const s16x4*)pa;
                s16x4 ahi = *(const s16x4*)(pa + 4);
                s16x8 af = __builtin_shufflevector(alo, ahi, 0,1,2,3,4,5,6,7);
                #pragma unroll
                for (int ni = 0; ni < 4; ++ni){
                    const s16* pb = &wls[(tl*64 + ni*16 + lm)*36 + g*8];
                    s16x4 blo = *(const s16x4*)pb;
                    s16x4 bhi = *(const s16x4*)(pb + 4);
                    s16x8 bf = __builtin_shufflevector(blo, bhi, 0,1,2,3,4,5,6,7);
                    acc[ni] = __builtin_amdgcn_mfma_f32_16x16x32_bf16(af, bf, acc[ni], 0, 0, 0);
                }
            }
            if (tg < 2){
                __syncthreads();
                for (int i = t; i < 768; i += 256){
                    int g8 = i & 3, co = (i>>2) & 63, tl = i >> 8;
                    s16x8 v = *(const s16x8*)&wpk[((cc*9 + (tg+1)*3 + tl)*256 + cog*64 + co)*32 + g8*8];
                    s16* d = &wls[(tl*64 + co)*36 + g8*8];
                    *(s16x4*)d       = __builtin_shufflevector(v, v, 0,1,2,3);
                    *(s16x4*)(d + 4) = __builtin_shufflevector(v, v, 4,5,6,7);
                }
                __syncthreads();
            }
        }
    }
    // epilogue: acc -> LDS [co][67 pad] -> coalesced bf16 stores (+bias)
    __syncthreads();
    float* ot = (float*)smem;                    // [64 co][67 m-pad]
    #pragma unroll
    for (int ni = 0; ni < 4; ++ni)
        #pragma unroll
        for (int r = 0; r < 4; ++r){
            int m  = wv*16 + g*4 + r;            // row = (lane>>4)*4+reg (verified)
            int co = ni*16 + lm;                 // col = lane&15 (verified)
            ot[co*67 + m] = acc[ni][r];
        }
    __syncthreads();
    for (int i = t; i < 4096; i += 256){
        int co = i >> 6, m = i & 63;
        float v = ot[co*67 + m] + bias[cog*64 + co];
        y0[((b*256 + cog*64 + co)*64 + h0)*64 + m] = __float2bfloat16(v);
    }
}

// ---------------------------------------------------------------------------
// C) fused separable depthwise (7/11/21) + residual, sliding-window (R10)
// ---------------------------------------------------------------------------
template<int K>
__device__ __forceinline__ void sep_branch(const float (*__restrict__ pl)[65], float (*__restrict__ hp)[65],
                                           int c, int t,
                                           const float* __restrict__ wh, const float* __restrict__ bh,
                                           const float* __restrict__ wv, const float* __restrict__ bv,
                                           float* acc){
    constexpr int P = K/2;
    constexpr int W = 16 + 2*P;
    float wk[K];
    #pragma unroll
    for (int j = 0; j < K; ++j) wk[j] = wh[c*K + j];
    float bhv = bh[c];
    {
        int h = t >> 2, w0 = (t & 3)*16;
        float win[W];
        #pragma unroll
        for (int j = 0; j < W; ++j){
            int ww = w0 - P + j;
            win[j] = (ww >= 0 && ww < 64) ? pl[h][ww] : 0.f;
        }
        __syncthreads();                 // prev-branch hp reads complete
        #pragma unroll
        for (int i = 0; i < 16; ++i){
            float s = bhv;
            #pragma unroll
            for (int k = 0; k < K; ++k) s += win[i+k]*wk[k];
            hp[h][w0 + i] = s;
        }
    }
    float vk[K];
    #pragma unroll
    for (int j = 0; j < K; ++j) vk[j] = wv[c*K + j];
    float bvv = bv[c];
    __syncthreads();                     // hp writes visible
    {
        int w = t & 63, h0 = (t >> 6)*16;
        float win[W];
        #pragma unroll
        for (int j = 0; j < W; ++j){
            int hh = h0 - P + j;
            win[j] = (hh >= 0 && hh < 64) ? hp[hh][w] : 0.f;
        }
        #pragma unroll
        for (int i = 0; i < 16; ++i){
            float s = bvv;
            #pragma unroll
            for (int k = 0; k < K; ++k) s += win[i+k]*vk[k];
            acc[i] += s;
        }
    }
}

__global__ __launch_bounds__(256) void sepconv_k(const bf16* __restrict__ y0,
        const float* __restrict__ w01, const float* __restrict__ b01,
        const float* __restrict__ w02, const float* __restrict__ b02,
        const float* __restrict__ w11, const float* __restrict__ b11,
        const float* __restrict__ w12, const float* __restrict__ b12,
        const float* __restrict__ w21, const float* __restrict__ b21,
        const float* __restrict__ w22, const float* __restrict__ b22,
        bf16* __restrict__ out1){
    __shared__ float pl[64][65];
    __shared__ float hp[64][65];
    int bc = blockIdx.x;             // b*256 + c
    int c = bc & 255;
    int t = threadIdx.x;
    const bf16* src = y0 + bc*4096;
    for (int i = t; i < 4096; i += 256) pl[i>>6][i&63] = __bfloat162float(src[i]);
    __syncthreads();
    float acc[16];
    #pragma unroll
    for (int k = 0; k < 16; ++k) acc[k] = 0.f;
    sep_branch<7 >(pl, hp, c, t, w01, b01, w02, b02, acc);
    sep_branch<11>(pl, hp, c, t, w11, b11, w12, b12, acc);
    sep_branch<21>(pl, hp, c, t, w21, b21, w22, b22, acc);
    bf16* dst = out1 + bc*4096;
    {
        int w = t & 63, h0 = (t >> 6)*16;
        #pragma unroll
        for (int i = 0; i < 16; ++i)
            dst[(h0 + i)*64 + w] = __float2bfloat16(acc[i] + pl[h0 + i][w]);
    }
}

// ---------------------------------------------------------------------------
// E) 1x1 projection 256->32, 4-way ci-split (unchanged from passing R10)
// ---------------------------------------------------------------------------
__global__ __launch_bounds__(256) void proj_k(const bf16* __restrict__ out1, const float* __restrict__ wp,
                                              const float* __restrict__ bp, float* __restrict__ tbuf,
                                              s16* __restrict__ tTb, float* __restrict__ rn2){
    __shared__ float wl[256*32];         // [ci][cc] fp32, 32 KB
    __shared__ s16 part[4][64][36];      // bf16 partials, 18.4 KB
    int pt = blockIdx.x, b = blockIdx.y, t = threadIdx.x;
    int q = t >> 6, lane = t & 63;
    for (int i = t; i < 8192; i += 256){
        int ci = i >> 5, cc = i & 31;
        wl[ci*32 + cc] = wp[cc*256 + ci];
    }
    __syncthreads();
    int p = pt*64 + lane;
    float acc[32] = {};
    const bf16* xb = out1 + b*1048576 + p;
    for (int ci = q*64; ci < q*64 + 64; ++ci){
        float v = __bfloat162float(xb[ci*4096]);
        const float* wr = &wl[ci*32];
        #pragma unroll
        for (int c8 = 0; c8 < 8; ++c8){
            float4 w4 = *(const float4*)&wr[c8*4];
            acc[c8*4+0] += w4.x*v; acc[c8*4+1] += w4.y*v;
            acc[c8*4+2] += w4.z*v; acc[c8*4+3] += w4.w*v;
        }
    }
    #pragma unroll
    for (int cc = 0; cc < 32; ++cc) part[q][lane][cc] = f2b(acc[cc]);
    __syncthreads();
    int p_loc = t >> 2, qq = t & 3;
    int pg = pt*64 + p_loc;
    float a8[8];
    float ss = 0.f;
    #pragma unroll
    for (int c = 0; c < 8; ++c){
        int cc = qq*8 + c;
        float v = b2f_bits(part[0][p_loc][cc]) + b2f_bits(part[1][p_loc][cc])
                + b2f_bits(part[2][p_loc][cc]) + b2f_bits(part[3][p_loc][cc]) + bp[cc];
        a8[c] = v;
        ss += v*v;
    }
    ss += __shfl_xor(ss, 1, 4);
    ss += __shfl_xor(ss, 2, 4);
    if (qq == 0) rn2[b*4096 + pg] = 1.f / fmaxf(sqrtf(ss), 1e-12f);
    #pragma unroll
    for (int c = 0; c < 8; ++c) tbuf[(b*32 + qq*8 + c)*4096 + pg] = a8[c];
    s16x8 o8;
    #pragma unroll
    for (int c = 0; c < 8; ++c) o8[c] = f2b(a8[c]);
    *(s16x8*)&tTb[(b*4096 + pg)*32 + qq*8] = o8;
}

// ---------------------------------------------------------------------------
// G1) Gram via MFMA: part[b][ks][i*32+j] = sum_{p in ks-slice} t_i[p] t_j[p].
//     Grid (16 ks, 4 b).  LDS ts[32][268] bf16 (pad 268 -> conflict-free b64
//     frags).  4 waves = 2x2 16x16 tiles; 8 k-steps of 16x16x32.
//     Operand/C-D mappings identical to the HW-verified conv kernel.
// ---------------------------------------------------------------------------
__global__ __launch_bounds__(256) void gramm_k(const float* __restrict__ tbuf, float* __restrict__ part){
    __shared__ alignas(16) s16 ts[32*268];       // 16.75 KB
    int ks = blockIdx.x, b = blockIdx.y, t = threadIdx.x;
    {
        int cc = t >> 3, p0 = (t & 7)*32;
        const float* src = tbuf + (b*32 + cc)*4096 + ks*256 + p0;
        s16* d = &ts[cc*268 + p0];
        #pragma unroll
        for (int q = 0; q < 4; ++q){
            float4 v0 = *(const float4*)&src[q*8];
            float4 v1 = *(const float4*)&src[q*8 + 4];
            s16x4 o0, o1;
            o0[0]=f2b(v0.x); o0[1]=f2b(v0.y); o0[2]=f2b(v0.z); o0[3]=f2b(v0.w);
            o1[0]=f2b(v1.x); o1[1]=f2b(v1.y); o1[2]=f2b(v1.z); o1[3]=f2b(v1.w);
            *(s16x4*)&d[q*8]     = o0;
            *(s16x4*)&d[q*8 + 4] = o1;
        }
    }
    __syncthreads();
    int wv = t >> 6, lane = t & 63, lm = lane & 15, g = lane >> 4;
    int mi = wv >> 1, ni = wv & 1;
    f32x4 acc = (f32x4){0.f,0.f,0.f,0.f};
    const s16* ar = &ts[(mi*16 + lm)*268];
    const s16* br = &ts[(ni*16 + lm)*268];
    #pragma unroll
    for (int kk = 0; kk < 8; ++kk){
        const s16* ap = ar + kk*32 + g*8;
        s16x4 alo = *(const s16x4*)ap;
        s16x4 ahi = *(const s16x4*)(ap + 4);
        s16x8 af = __builtin_shufflevector(alo, ahi, 0,1,2,3,4,5,6,7);
        const s16* bp = br + kk*32 + g*8;
        s16x4 blo = *(const s16x4*)bp;
        s16x4 bhi = *(const s16x4*)(bp + 4);
        s16x8 bf = __builtin_shufflevector(blo, bhi, 0,1,2,3,4,5,6,7);
        acc = __builtin_amdgcn_mfma_f32_16x16x32_bf16(af, bf, acc, 0, 0, 0);
    }
    float* pd = part + (b*16 + ks)*1024;
    #pragma unroll
    for (int r = 0; r < 4; ++r){
        int i = mi*16 + g*4 + r, j = ni*16 + lm;
        pd[i*32 + j] = acc[r];
    }
}

// ---------------------------------------------------------------------------
// G2) attn1 softmax; rn1 from gram diagonal; 16 k-slice partials.
// ---------------------------------------------------------------------------
__global__ __launch_bounds__(64) void attn1_k(const float* __restrict__ part,
                                              float* __restrict__ attn1T){
    int i = blockIdx.x, b = blockIdx.y, j = threadIdx.x;
    float gij = 0.f, gjj = 0.f;
    if (j < 32){
        #pragma unroll 8
        for (int ps = 0; ps < 16; ++ps){
            const float* pp = part + (b*16+ps)*1024;
            gij += pp[i*32 + j];
            gjj += pp[j*33];
        }
    }
    float rnj = 1.f / fmaxf(sqrtf(gjj), 1e-12f);
    float rni = __shfl(rnj, i, 64);
    float e = (j < 32) ? __expf(rni*rnj*gij) : 0.f;
    float sum = e;
    #pragma unroll
    for (int o = 32; o > 0; o >>= 1) sum += __shfl_xor(sum, o, 64);
    if (j < 32) attn1T[b*1024 + j*32 + i] = e / sum;
}

// ---------------------------------------------------------------------------
// G3) fold channel-attention + both 1x1 convs (unchanged from passing R11)
// ---------------------------------------------------------------------------
__global__ __launch_bounds__(256) void fold_k(const float* __restrict__ attn1T,
        const float* __restrict__ w3, const float* __restrict__ b3,
        const float* __restrict__ w4, const float* __restrict__ b4,
        float* __restrict__ WtT, float* __restrict__ WoT, float* __restrict__ bfo){
    __shared__ float a1[1024];     // attn1[i][j]
    __shared__ float w3a[1024];    // [cc][j]
    __shared__ float w3bs[1024];   // [cc][j]
    int b = blockIdx.x, t = threadIdx.x;
    for (int idx = t; idx < 1024; idx += 256){
        int i = idx >> 5, j = idx & 31;
        a1[idx]   = attn1T[b*1024 + j*32 + i];
        w3bs[idx] = w3[i*64 + 32 + j];
    }
    __syncthreads();
    for (int idx = t; idx < 1024; idx += 256){
        int cc = idx >> 5, j = idx & 31;
        float s = 0.f;
        #pragma unroll 8
        for (int i = 0; i < 32; ++i) s += w3[cc*64 + i]*a1[i*32 + j];
        w3a[idx] = s;
    }
    __syncthreads();
    int co = t;
    float w4r[32];
    #pragma unroll
    for (int cc = 0; cc < 32; ++cc) w4r[cc] = w4[co*32 + cc];
    float bfv = b4[co];
    #pragma unroll
    for (int cc = 0; cc < 32; ++cc) bfv += w4r[cc]*b3[cc];
    bfo[b*256 + co] = bfv;
    for (int j = 0; j < 32; ++j){
        float st = w4r[j];           // w4 identity term = +t residual through w4
        float so = 0.f;
        #pragma unroll 8
        for (int cc = 0; cc < 32; ++cc){
            st += w4r[cc]*w3a[cc*32 + j];
            so += w4r[cc]*w3bs[cc*32 + j];
        }
        WtT[(b*32 + j)*256 + co] = st;
        WoT[(b*32 + j)*256 + co] = so;
    }
}

// ---------------------------------------------------------------------------
// J) spatial attention via MFMA flash (unchanged from passing R11)
// ---------------------------------------------------------------------------
__global__ __launch_bounds__(256) void flashm_k(const s16* __restrict__ tTb, const float* __restrict__ rn2,
                                                float* __restrict__ partA, float* __restrict__ partL){
    __shared__ alignas(16) s16 kvb[128*36];      // [j][ci]   9216 B
    __shared__ alignas(16) s16 vts[32*132];      // [ci][j]   8448 B
    __shared__ alignas(16) s16 pls[4][16*132];   // per-wave P [m][j] 16896 B
    __shared__ float rnj[128];
    __shared__ float ri[64];
    const int ib = blockIdx.x, b = blockIdx.y, chunk = blockIdx.z;
    const int t = threadIdx.x, wv = t >> 6, lane = t & 63;
    const int lm = lane & 15, g = lane >> 4;
    const int i0 = ib*64;

    if (t < 64) ri[t] = rn2[b*4096 + i0 + t];
    s16x8 qf = *(const s16x8*)&tTb[(b*4096 + i0 + wv*16 + lm)*32 + g*8];
    __syncthreads();
    float rni4[4];
    #pragma unroll
    for (int r = 0; r < 4; ++r) rni4[r] = ri[wv*16 + g*4 + r];

    f32x4 oacc[2];
    oacc[0] = (f32x4){0.f,0.f,0.f,0.f};
    oacc[1] = (f32x4){0.f,0.f,0.f,0.f};
    float lacc[4] = {0.f,0.f,0.f,0.f};
    s16* pw = pls[wv];

    for (int jt = chunk*16; jt < chunk*16 + 16; ++jt){
        const int j0 = jt*128;
        __syncthreads();
        for (int gi = t; gi < 512; gi += 256){
            int j = gi >> 2, g8 = gi & 3;
            s16x8 v = *(const s16x8*)&tTb[(b*4096 + j0 + j)*32 + g8*8];
            s16* d = &kvb[j*36 + g8*8];
            *(s16x4*)d       = __builtin_shufflevector(v, v, 0,1,2,3);
            *(s16x4*)(d + 4) = __builtin_shufflevector(v, v, 4,5,6,7);
            #pragma unroll
            for (int e = 0; e < 8; ++e) vts[(g8*8 + e)*132 + j] = v[e];
        }
        if (t < 128) rnj[t] = rn2[b*4096 + j0 + t];
        __syncthreads();
        #pragma unroll
        for (int nt = 0; nt < 8; ++nt){
            const s16* bp = &kvb[(nt*16 + lm)*36 + g*8];
            s16x4 blo = *(const s16x4*)bp;
            s16x4 bhi = *(const s16x4*)(bp + 4);
            s16x8 bf = __builtin_shufflevector(blo, bhi, 0,1,2,3,4,5,6,7);
            f32x4 s = __builtin_amdgcn_mfma_f32_16x16x32_bf16(qf, bf,
                        (f32x4){0.f,0.f,0.f,0.f}, 0, 0, 0);
            float rj = rnj[nt*16 + lm];
            #pragma unroll
            for (int r = 0; r < 4; ++r){
                float e = __expf(s[r]*rni4[r]*rj);
                lacc[r] += e;
                pw[(g*4 + r)*132 + nt*16 + lm] = f2b(e);
            }
        }
        #pragma unroll
        for (int ks = 0; ks < 4; ++ks){
            const s16* ap = &pw[lm*132 + ks*32 + g*8];
            s16x4 alo = *(const s16x4*)ap;
            s16x4 ahi = *(const s16x4*)(ap + 4);
            s16x8 af = __builtin_shufflevector(alo, ahi, 0,1,2,3,4,5,6,7);
            #pragma unroll
            for (int n2 = 0; n2 < 2; ++n2){
                const s16* vp = &vts[(n2*16 + lm)*132 + ks*32 + g*8];
                s16x4 vlo = *(const s16x4*)vp;
                s16x4 vhi = *(const s16x4*)(vp + 4);
                s16x8 vf = __builtin_shufflevector(vlo, vhi, 0,1,2,3,4,5,6,7);
                oacc[n2] = __builtin_amdgcn_mfma_f32_16x16x32_bf16(af, vf, oacc[n2], 0, 0, 0);
            }
        }
    }
    #pragma unroll
    for (int r = 0; r < 4; ++r){
        float v = lacc[r];
        v += __shfl_xor(v, 1, 16); v += __shfl_xor(v, 2, 16);
        v += __shfl_xor(v, 4, 16); v += __shfl_xor(v, 8, 16);
        lacc[r] = v;
    }
    const int base = (b*2 + chunk)*4096 + i0 + wv*16;
    #pragma unroll
    for (int n2 = 0; n2 < 2; ++n2)
        #pragma unroll
        for (int r = 0; r < 4; ++r)
            partA[(base + g*4 + r)*32 + n2*16 + lm] = oacc[n2][r];
    if (lm == 0){
        #pragma unroll
        for (int r = 0; r < 4; ++r) partL[base + g*4 + r] = lacc[r];
    }
}

// ---------------------------------------------------------------------------
// L) fused epilogue (unchanged from passing R11)
// ---------------------------------------------------------------------------
__global__ __launch_bounds__(256) void finalfuse_k(const float* __restrict__ tbuf,
        const float* __restrict__ partA, const float* __restrict__ partL,
        const float* __restrict__ WtT, const float* __restrict__ WoT,
        const float* __restrict__ bfo, float* __restrict__ out){
    int pt = blockIdx.x, cog = blockIdx.y, b = blockIdx.z, t = threadIdx.x;
    int p = pt*256 + t;
    float l = partL[(b*2 + 0)*4096 + p] + partL[(b*2 + 1)*4096 + p];
    float inv = 1.f / l;
    const float* pa0 = partA + ((b*2 + 0)*4096 + p)*32;
    const float* pa1 = partA + ((b*2 + 1)*4096 + p)*32;
    float v3[32];
    #pragma unroll
    for (int q = 0; q < 8; ++q){
        float4 a = *(const float4*)&pa0[q*4];
        float4 c = *(const float4*)&pa1[q*4];
        v3[q*4+0] = (a.x + c.x)*inv; v3[q*4+1] = (a.y + c.y)*inv;
        v3[q*4+2] = (a.z + c.z)*inv; v3[q*4+3] = (a.w + c.w)*inv;
    }
    float acc[32];
    #pragma unroll
    for (int co = 0; co < 32; ++co) acc[co] = bfo[b*256 + cog*32 + co];
    for (int j = 0; j < 32; ++j){
        float vt = tbuf[(b*32 + j)*4096 + p];
        float vo = v3[j];
        const float* wtr = WtT + (b*32 + j)*256 + cog*32;   // wave-uniform
        const float* wor = WoT + (b*32 + j)*256 + cog*32;   // wave-uniform
        #pragma unroll
        for (int co = 0; co < 32; ++co) acc[co] += wtr[co]*vt + wor[co]*vo;
    }
    #pragma unroll
    for (int co = 0; co < 32; ++co)
        out[((b*256 + cog*32 + co)*4096) + p] = acc[co];
}

// ---------------------------------------------------------------------------
// Workspace layout (bytes), peak ~19.0 MB:
//   [0,        8388608)  xcl -> out1 -> gram part (256 KB) -> flash partA (4 MB)
//   [8388608, 16777216)  y0  -> tbuf / tTb
//   [12582912, ...)      WtT/WoT/bf (260 KB)
//   [16777216, ...)      wpk -> partL;  attn1T/rn2 near byte 18.9 MB
// ---------------------------------------------------------------------------
extern "C" void kernel_launch(void* const* d_in, const int* in_sizes, int n_in,
                              void* d_out, int out_size, void* d_ws, size_t ws_size,
                              hipStream_t stream) {
    const float* x      = (const float*)d_in[0];
    const float* w_conv = (const float*)d_in[1];
    const float* b_conv = (const float*)d_in[2];
    const float* w01 = (const float*)d_in[3];  const float* b01 = (const float*)d_in[4];
    const float* w02 = (const float*)d_in[5];  const float* b02 = (const float*)d_in[6];
    const float* w11 = (const float*)d_in[7];  const float* b11 = (const float*)d_in[8];
    const float* w12 = (const float*)d_in[9];  const float* b12 = (const float*)d_in[10];
    const float* w21 = (const float*)d_in[11]; const float* b21 = (const float*)d_in[12];
    const float* w22 = (const float*)d_in[13]; const float* b22 = (const float*)d_in[14];
    const float* w_proj = (const float*)d_in[15]; const float* b_proj = (const float*)d_in[16];
    const float* w3 = (const float*)d_in[17]; const float* b3 = (const float*)d_in[18];
    const float* w4 = (const float*)d_in[19]; const float* b4 = (const float*)d_in[20];

    char* wsb = (char*)d_ws;
    s16*   xcl  = (s16*)wsb;                        // 4,194,304 s16 (conv input)
    bf16*  out1 = (bf16*)wsb;                       // same slot, after conv
    bf16*  y0   = (bf16*)(wsb + 8388608);           // 4,194,304 bf16
    s16*   wpk  = (s16*)(wsb + 16777216);           // 589,824 s16
    float* f    = (float*)d_ws;
    float* part   = f + 0;         // gram partials 4x16x1024 f (out1 dead)
    float* partA  = f + 0;         // flash partials 2x4x4096x32 f = 4 MB
    float* tbuf   = f + 2097152;   // byte  8,388,608 (overlays dead y0)
    s16*   tTb    = (s16*)(wsb + 10485760);         // 524,288 s16 = 1 MB
    float* WtT    = f + 3145728;   // byte 12,582,912  (4x32x256 f)
    float* WoT    = f + 3178496;
    float* bfo    = f + 3211264;
    float* partL  = f + 4194304;   // byte 16,777,216 (wpk dead by flashm)
    float* attn1T = f + 4722816;
    float* rn2    = f + 4726912;

    xtrans_k<<<dim3(64, 4), 256, 0, stream>>>(x, xcl);
    wpack_k<<<dim3(2304), 256, 0, stream>>>(w_conv, wpk);
    conv3x3m_k<<<dim3(256, 4), 256, 0, stream>>>(xcl, wpk, b_conv, y0);
    sepconv_k<<<dim3(1024), 256, 0, stream>>>(y0, w01, b01, w02, b02,
                                              w11, b11, w12, b12,
                                              w21, b21, w22, b22, out1);
    proj_k<<<dim3(64, 4), 256, 0, stream>>>(out1, w_proj, b_proj, tbuf, tTb, rn2);
    gramm_k<<<dim3(16, 4), 256, 0, stream>>>(tbuf, part);
    attn1_k<<<dim3(32, 4), 64, 0, stream>>>(part, attn1T);
    fold_k<<<dim3(4), 256, 0, stream>>>(attn1T, w3, b3, w4, b4, WtT, WoT, bfo);
    flashm_k<<<dim3(64, 4, 2), 256, 0, stream>>>(tTb, rn2, partA, partL);
    finalfuse_k<<<dim3(16, 8, 4), 256, 0, stream>>>(tbuf, partA, partL, WtT, WoT, bfo,
                                                    (float*)d_out);
}

// Round 13
// 308.522 us; speedup vs baseline: 6.0569x; 1.0187x over previous
//
#include <hip/hip_runtime.h>
#include <hip/hip_bf16.h>

typedef __hip_bfloat16 bf16;
typedef short s16;
typedef __attribute__((ext_vector_type(4))) short s16x4;
typedef __attribute__((ext_vector_type(8))) short s16x8;
typedef __attribute__((ext_vector_type(4))) float f32x4;

__device__ __forceinline__ s16 f2b(float f){
    unsigned u = __float_as_uint(f);
    unsigned r = (u + 0x7FFFu + ((u >> 16) & 1u)) >> 16;
    return (s16)r;
}
__device__ __forceinline__ float b2f_bits(s16 v){
    return __uint_as_float(((unsigned)(unsigned short)v) << 16);
}

// ---------------------------------------------------------------------------
// A1) x (fp32 NCHW) -> xcl (bf16-bits channels-last [b][h][w][ci])
// ---------------------------------------------------------------------------
__global__ __launch_bounds__(256) void xtrans_k(const float* __restrict__ x, s16* __restrict__ xcl){
    __shared__ s16 lb[64][258];
    int h = blockIdx.x, b = blockIdx.y, t = threadIdx.x;
    for (int i = t; i < 16384; i += 256){
        int ci = i >> 6, w = i & 63;
        lb[w][ci] = f2b(x[((b*256 + ci)*64 + h)*64 + w]);
    }
    __syncthreads();
    for (int i = t; i < 16384; i += 256){
        int w = i >> 8, ci = i & 255;
        xcl[(b*4096 + h*64 + w)*256 + ci] = lb[w][ci];
    }
}

// ---------------------------------------------------------------------------
// A2) w_conv (fp32 [co][ci][3][3]) -> wpk (bf16-bits [cc8][tap9][co256][ci32])
// ---------------------------------------------------------------------------
__global__ __launch_bounds__(256) void wpack_k(const float* __restrict__ w, s16* __restrict__ wpk){
    int idx = blockIdx.x*256 + threadIdx.x;      // < 589824
    int cil = idx & 31;
    int r   = idx >> 5;
    int co  = r & 255;
    int r2  = r >> 8;
    int tap = r2 % 9, cc = r2 / 9;
    wpk[idx] = f2b(w[(co*256 + cc*32 + cil)*9 + tap]);
}

// ---------------------------------------------------------------------------
// B) 3x3 conv 256->256 as MFMA implicit GEMM — REVERTED to the R11 M=128
//    tile (2 h-rows x 64 w x 64 co; 60.5 KB LDS; 2 barriers per cc chunk).
//    R12's M=64 retile regressed (more barriers + 1.5x x re-fetch).
// ---------------------------------------------------------------------------
__global__ __launch_bounds__(256) void conv3x3m_k(const s16* __restrict__ xcl,
        const s16* __restrict__ wpk, const float* __restrict__ bias,
        bf16* __restrict__ y0){
    __shared__ alignas(16) s16 smem[30240];      // 60.5 KB
    s16* xls = smem;                             // [4 rows][66 w][36 ci-pad]
    s16* wls = smem + 9504;                      // [9 tap][64 co][36 ci-pad]
    const int sp = blockIdx.x, cog = blockIdx.y;
    const int b = sp >> 5, h0 = (sp & 31)*2;
    const int t = threadIdx.x;
    const int wv = t >> 6, lane = t & 63;
    const int lm = lane & 15, g = lane >> 4;

    f32x4 acc[2][4];
    #pragma unroll
    for (int mi = 0; mi < 2; ++mi)
        #pragma unroll
        for (int ni = 0; ni < 4; ++ni) acc[mi][ni] = (f32x4){0.f,0.f,0.f,0.f};

    for (int cc = 0; cc < 8; ++cc){
        __syncthreads();
        for (int i = t; i < 1056; i += 256){
            int g8 = i & 3, wi = (i>>2) % 66, r = (i>>2) / 66;
            int h = h0 - 1 + r, w = wi - 1;
            s16x8 v = {0,0,0,0,0,0,0,0};
            if (h >= 0 && h < 64 && w >= 0 && w < 64)
                v = *(const s16x8*)&xcl[(b*4096 + h*64 + w)*256 + cc*32 + g8*8];
            s16* d = &xls[(r*66 + wi)*36 + g8*8];
            *(s16x4*)d       = __builtin_shufflevector(v, v, 0,1,2,3);
            *(s16x4*)(d + 4) = __builtin_shufflevector(v, v, 4,5,6,7);
        }
        for (int i = t; i < 2304; i += 256){
            int g8 = i & 3, co = (i>>2) & 63, tap = i >> 8;
            s16x8 v = *(const s16x8*)&wpk[((cc*9 + tap)*256 + cog*64 + co)*32 + g8*8];
            s16* d = &wls[(tap*64 + co)*36 + g8*8];
            *(s16x4*)d       = __builtin_shufflevector(v, v, 0,1,2,3);
            *(s16x4*)(d + 4) = __builtin_shufflevector(v, v, 4,5,6,7);
        }
        __syncthreads();
        #pragma unroll
        for (int tap = 0; tap < 9; ++tap){
            const int kh = tap/3, kw = tap%3;
            s16x8 bfr[4], afr[2];
            #pragma unroll
            for (int ni = 0; ni < 4; ++ni){
                const s16* p = &wls[(tap*64 + ni*16 + lm)*36 + g*8];
                s16x4 lo = *(const s16x4*)p;
                s16x4 hi = *(const s16x4*)(p + 4);
                bfr[ni] = __builtin_shufflevector(lo, hi, 0,1,2,3,4,5,6,7);
            }
            #pragma unroll
            for (int mi = 0; mi < 2; ++mi){
                int m = (wv*2 + mi)*16 + lm;
                int hr = m >> 6, ww = m & 63;
                const s16* p = &xls[((hr + kh)*66 + (ww + kw))*36 + g*8];
                s16x4 lo = *(const s16x4*)p;
                s16x4 hi = *(const s16x4*)(p + 4);
                afr[mi] = __builtin_shufflevector(lo, hi, 0,1,2,3,4,5,6,7);
            }
            #pragma unroll
            for (int mi = 0; mi < 2; ++mi)
                #pragma unroll
                for (int ni = 0; ni < 4; ++ni)
                    acc[mi][ni] = __builtin_amdgcn_mfma_f32_16x16x32_bf16(
                        afr[mi], bfr[ni], acc[mi][ni], 0, 0, 0);
        }
    }
    __syncthreads();
    float* ot = (float*)smem;                    // [64 co][132 m-pad]
    #pragma unroll
    for (int mi = 0; mi < 2; ++mi)
        #pragma unroll
        for (int ni = 0; ni < 4; ++ni)
            #pragma unroll
            for (int r = 0; r < 4; ++r){
                int m  = (wv*2 + mi)*16 + g*4 + r;
                int co = ni*16 + lm;
                ot[co*132 + m] = acc[mi][ni][r];
            }
    __syncthreads();
    for (int i = t; i < 8192; i += 256){
        int co = i >> 7, m = i & 127;
        float v = ot[co*132 + m] + bias[cog*64 + co];
        y0[((b*256 + cog*64 + co)*64 + h0 + (m>>6))*64 + (m & 63)] = __float2bfloat16(v);
    }
}

// ---------------------------------------------------------------------------
// C) fused separable depthwise (7/11/21) + residual, sliding-window (R10)
// ---------------------------------------------------------------------------
template<int K>
__device__ __forceinline__ void sep_branch(const float (*__restrict__ pl)[65], float (*__restrict__ hp)[65],
                                           int c, int t,
                                           const float* __restrict__ wh, const float* __restrict__ bh,
                                           const float* __restrict__ wv, const float* __restrict__ bv,
                                           float* acc){
    constexpr int P = K/2;
    constexpr int W = 16 + 2*P;
    float wk[K];
    #pragma unroll
    for (int j = 0; j < K; ++j) wk[j] = wh[c*K + j];
    float bhv = bh[c];
    {
        int h = t >> 2, w0 = (t & 3)*16;
        float win[W];
        #pragma unroll
        for (int j = 0; j < W; ++j){
            int ww = w0 - P + j;
            win[j] = (ww >= 0 && ww < 64) ? pl[h][ww] : 0.f;
        }
        __syncthreads();                 // prev-branch hp reads complete
        #pragma unroll
        for (int i = 0; i < 16; ++i){
            float s = bhv;
            #pragma unroll
            for (int k = 0; k < K; ++k) s += win[i+k]*wk[k];
            hp[h][w0 + i] = s;
        }
    }
    float vk[K];
    #pragma unroll
    for (int j = 0; j < K; ++j) vk[j] = wv[c*K + j];
    float bvv = bv[c];
    __syncthreads();                     // hp writes visible
    {
        int w = t & 63, h0 = (t >> 6)*16;
        float win[W];
        #pragma unroll
        for (int j = 0; j < W; ++j){
            int hh = h0 - P + j;
            win[j] = (hh >= 0 && hh < 64) ? hp[hh][w] : 0.f;
        }
        #pragma unroll
        for (int i = 0; i < 16; ++i){
            float s = bvv;
            #pragma unroll
            for (int k = 0; k < K; ++k) s += win[i+k]*vk[k];
            acc[i] += s;
        }
    }
}

__global__ __launch_bounds__(256) void sepconv_k(const bf16* __restrict__ y0,
        const float* __restrict__ w01, const float* __restrict__ b01,
        const float* __restrict__ w02, const float* __restrict__ b02,
        const float* __restrict__ w11, const float* __restrict__ b11,
        const float* __restrict__ w12, const float* __restrict__ b12,
        const float* __restrict__ w21, const float* __restrict__ b21,
        const float* __restrict__ w22, const float* __restrict__ b22,
        bf16* __restrict__ out1){
    __shared__ float pl[64][65];
    __shared__ float hp[64][65];
    int bc = blockIdx.x;             // b*256 + c
    int c = bc & 255;
    int t = threadIdx.x;
    const bf16* src = y0 + bc*4096;
    for (int i = t; i < 4096; i += 256) pl[i>>6][i&63] = __bfloat162float(src[i]);
    __syncthreads();
    float acc[16];
    #pragma unroll
    for (int k = 0; k < 16; ++k) acc[k] = 0.f;
    sep_branch<7 >(pl, hp, c, t, w01, b01, w02, b02, acc);
    sep_branch<11>(pl, hp, c, t, w11, b11, w12, b12, acc);
    sep_branch<21>(pl, hp, c, t, w21, b21, w22, b22, acc);
    bf16* dst = out1 + bc*4096;
    {
        int w = t & 63, h0 = (t >> 6)*16;
        #pragma unroll
        for (int i = 0; i < 16; ++i)
            dst[(h0 + i)*64 + w] = __float2bfloat16(acc[i] + pl[h0 + i][w]);
    }
}

// ---------------------------------------------------------------------------
// E) 1x1 projection 256->32, 4-way ci-split (unchanged from passing R12)
// ---------------------------------------------------------------------------
__global__ __launch_bounds__(256) void proj_k(const bf16* __restrict__ out1, const float* __restrict__ wp,
                                              const float* __restrict__ bp, float* __restrict__ tbuf,
                                              s16* __restrict__ tTb, float* __restrict__ rn2){
    __shared__ float wl[256*32];         // [ci][cc] fp32, 32 KB
    __shared__ s16 part[4][64][36];      // bf16 partials, 18.4 KB
    int pt = blockIdx.x, b = blockIdx.y, t = threadIdx.x;
    int q = t >> 6, lane = t & 63;
    for (int i = t; i < 8192; i += 256){
        int ci = i >> 5, cc = i & 31;
        wl[ci*32 + cc] = wp[cc*256 + ci];
    }
    __syncthreads();
    int p = pt*64 + lane;
    float acc[32] = {};
    const bf16* xb = out1 + b*1048576 + p;
    for (int ci = q*64; ci < q*64 + 64; ++ci){
        float v = __bfloat162float(xb[ci*4096]);
        const float* wr = &wl[ci*32];
        #pragma unroll
        for (int c8 = 0; c8 < 8; ++c8){
            float4 w4 = *(const float4*)&wr[c8*4];
            acc[c8*4+0] += w4.x*v; acc[c8*4+1] += w4.y*v;
            acc[c8*4+2] += w4.z*v; acc[c8*4+3] += w4.w*v;
        }
    }
    #pragma unroll
    for (int cc = 0; cc < 32; ++cc) part[q][lane][cc] = f2b(acc[cc]);
    __syncthreads();
    int p_loc = t >> 2, qq = t & 3;
    int pg = pt*64 + p_loc;
    float a8[8];
    float ss = 0.f;
    #pragma unroll
    for (int c = 0; c < 8; ++c){
        int cc = qq*8 + c;
        float v = b2f_bits(part[0][p_loc][cc]) + b2f_bits(part[1][p_loc][cc])
                + b2f_bits(part[2][p_loc][cc]) + b2f_bits(part[3][p_loc][cc]) + bp[cc];
        a8[c] = v;
        ss += v*v;
    }
    ss += __shfl_xor(ss, 1, 4);
    ss += __shfl_xor(ss, 2, 4);
    if (qq == 0) rn2[b*4096 + pg] = 1.f / fmaxf(sqrtf(ss), 1e-12f);
    #pragma unroll
    for (int c = 0; c < 8; ++c) tbuf[(b*32 + qq*8 + c)*4096 + pg] = a8[c];
    s16x8 o8;
    #pragma unroll
    for (int c = 0; c < 8; ++c) o8[c] = f2b(a8[c]);
    *(s16x8*)&tTb[(b*4096 + pg)*32 + qq*8] = o8;
}

// ---------------------------------------------------------------------------
// G1) Gram via MFMA (unchanged from passing R12)
// ---------------------------------------------------------------------------
__global__ __launch_bounds__(256) void gramm_k(const float* __restrict__ tbuf, float* __restrict__ part){
    __shared__ alignas(16) s16 ts[32*268];       // 16.75 KB
    int ks = blockIdx.x, b = blockIdx.y, t = threadIdx.x;
    {
        int cc = t >> 3, p0 = (t & 7)*32;
        const float* src = tbuf + (b*32 + cc)*4096 + ks*256 + p0;
        s16* d = &ts[cc*268 + p0];
        #pragma unroll
        for (int q = 0; q < 4; ++q){
            float4 v0 = *(const float4*)&src[q*8];
            float4 v1 = *(const float4*)&src[q*8 + 4];
            s16x4 o0, o1;
            o0[0]=f2b(v0.x); o0[1]=f2b(v0.y); o0[2]=f2b(v0.z); o0[3]=f2b(v0.w);
            o1[0]=f2b(v1.x); o1[1]=f2b(v1.y); o1[2]=f2b(v1.z); o1[3]=f2b(v1.w);
            *(s16x4*)&d[q*8]     = o0;
            *(s16x4*)&d[q*8 + 4] = o1;
        }
    }
    __syncthreads();
    int wv = t >> 6, lane = t & 63, lm = lane & 15, g = lane >> 4;
    int mi = wv >> 1, ni = wv & 1;
    f32x4 acc = (f32x4){0.f,0.f,0.f,0.f};
    const s16* ar = &ts[(mi*16 + lm)*268];
    const s16* br = &ts[(ni*16 + lm)*268];
    #pragma unroll
    for (int kk = 0; kk < 8; ++kk){
        const s16* ap = ar + kk*32 + g*8;
        s16x4 alo = *(const s16x4*)ap;
        s16x4 ahi = *(const s16x4*)(ap + 4);
        s16x8 af = __builtin_shufflevector(alo, ahi, 0,1,2,3,4,5,6,7);
        const s16* bp = br + kk*32 + g*8;
        s16x4 blo = *(const s16x4*)bp;
        s16x4 bhi = *(const s16x4*)(bp + 4);
        s16x8 bf = __builtin_shufflevector(blo, bhi, 0,1,2,3,4,5,6,7);
        acc = __builtin_amdgcn_mfma_f32_16x16x32_bf16(af, bf, acc, 0, 0, 0);
    }
    float* pd = part + (b*16 + ks)*1024;
    #pragma unroll
    for (int r = 0; r < 4; ++r){
        int i = mi*16 + g*4 + r, j = ni*16 + lm;
        pd[i*32 + j] = acc[r];
    }
}

// ---------------------------------------------------------------------------
// G2) attn1 softmax; rn1 from gram diagonal; 16 k-slice partials.
// ---------------------------------------------------------------------------
__global__ __launch_bounds__(64) void attn1_k(const float* __restrict__ part,
                                              float* __restrict__ attn1T){
    int i = blockIdx.x, b = blockIdx.y, j = threadIdx.x;
    float gij = 0.f, gjj = 0.f;
    if (j < 32){
        #pragma unroll 8
        for (int ps = 0; ps < 16; ++ps){
            const float* pp = part + (b*16+ps)*1024;
            gij += pp[i*32 + j];
            gjj += pp[j*33];
        }
    }
    float rnj = 1.f / fmaxf(sqrtf(gjj), 1e-12f);
    float rni = __shfl(rnj, i, 64);
    float e = (j < 32) ? __expf(rni*rnj*gij) : 0.f;
    float sum = e;
    #pragma unroll
    for (int o = 32; o > 0; o >>= 1) sum += __shfl_xor(sum, o, 64);
    if (j < 32) attn1T[b*1024 + j*32 + i] = e / sum;
}

// ---------------------------------------------------------------------------
// G3) fold channel-attention + both 1x1 convs (unchanged from passing R12)
// ---------------------------------------------------------------------------
__global__ __launch_bounds__(256) void fold_k(const float* __restrict__ attn1T,
        const float* __restrict__ w3, const float* __restrict__ b3,
        const float* __restrict__ w4, const float* __restrict__ b4,
        float* __restrict__ WtT, float* __restrict__ WoT, float* __restrict__ bfo){
    __shared__ float a1[1024];     // attn1[i][j]
    __shared__ float w3a[1024];    // [cc][j]
    __shared__ float w3bs[1024];   // [cc][j]
    int b = blockIdx.x, t = threadIdx.x;
    for (int idx = t; idx < 1024; idx += 256){
        int i = idx >> 5, j = idx & 31;
        a1[idx]   = attn1T[b*1024 + j*32 + i];
        w3bs[idx] = w3[i*64 + 32 + j];
    }
    __syncthreads();
    for (int idx = t; idx < 1024; idx += 256){
        int cc = idx >> 5, j = idx & 31;
        float s = 0.f;
        #pragma unroll 8
        for (int i = 0; i < 32; ++i) s += w3[cc*64 + i]*a1[i*32 + j];
        w3a[idx] = s;
    }
    __syncthreads();
    int co = t;
    float w4r[32];
    #pragma unroll
    for (int cc = 0; cc < 32; ++cc) w4r[cc] = w4[co*32 + cc];
    float bfv = b4[co];
    #pragma unroll
    for (int cc = 0; cc < 32; ++cc) bfv += w4r[cc]*b3[cc];
    bfo[b*256 + co] = bfv;
    for (int j = 0; j < 32; ++j){
        float st = w4r[j];           // w4 identity term = +t residual through w4
        float so = 0.f;
        #pragma unroll 8
        for (int cc = 0; cc < 32; ++cc){
            st += w4r[cc]*w3a[cc*32 + j];
            so += w4r[cc]*w3bs[cc*32 + j];
        }
        WtT[(b*32 + j)*256 + co] = st;
        WoT[(b*32 + j)*256 + co] = so;
    }
}

// ---------------------------------------------------------------------------
// J) spatial attention via MFMA flash — 4-way j-chunk split (grid 1024 ->
//    4 blocks/CU co-resident; was 2).  Each chunk covers 8 of 32 j-tiles.
// ---------------------------------------------------------------------------
__global__ __launch_bounds__(256) void flashm_k(const s16* __restrict__ tTb, const float* __restrict__ rn2,
                                                float* __restrict__ partA, float* __restrict__ partL){
    __shared__ alignas(16) s16 kvb[128*36];      // [j][ci]   9216 B
    __shared__ alignas(16) s16 vts[32*132];      // [ci][j]   8448 B
    __shared__ alignas(16) s16 pls[4][16*132];   // per-wave P [m][j] 16896 B
    __shared__ float rnj[128];
    __shared__ float ri[64];
    const int ib = blockIdx.x, b = blockIdx.y, chunk = blockIdx.z;
    const int t = threadIdx.x, wv = t >> 6, lane = t & 63;
    const int lm = lane & 15, g = lane >> 4;
    const int i0 = ib*64;

    if (t < 64) ri[t] = rn2[b*4096 + i0 + t];
    s16x8 qf = *(const s16x8*)&tTb[(b*4096 + i0 + wv*16 + lm)*32 + g*8];
    __syncthreads();
    float rni4[4];
    #pragma unroll
    for (int r = 0; r < 4; ++r) rni4[r] = ri[wv*16 + g*4 + r];

    f32x4 oacc[2];
    oacc[0] = (f32x4){0.f,0.f,0.f,0.f};
    oacc[1] = (f32x4){0.f,0.f,0.f,0.f};
    float lacc[4] = {0.f,0.f,0.f,0.f};
    s16* pw = pls[wv];

    for (int jt = chunk*8; jt < chunk*8 + 8; ++jt){
        const int j0 = jt*128;
        __syncthreads();
        for (int gi = t; gi < 512; gi += 256){
            int j = gi >> 2, g8 = gi & 3;
            s16x8 v = *(const s16x8*)&tTb[(b*4096 + j0 + j)*32 + g8*8];
            s16* d = &kvb[j*36 + g8*8];
            *(s16x4*)d       = __builtin_shufflevector(v, v, 0,1,2,3);
            *(s16x4*)(d + 4) = __builtin_shufflevector(v, v, 4,5,6,7);
            #pragma unroll
            for (int e = 0; e < 8; ++e) vts[(g8*8 + e)*132 + j] = v[e];
        }
        if (t < 128) rnj[t] = rn2[b*4096 + j0 + t];
        __syncthreads();
        #pragma unroll
        for (int nt = 0; nt < 8; ++nt){
            const s16* bp = &kvb[(nt*16 + lm)*36 + g*8];
            s16x4 blo = *(const s16x4*)bp;
            s16x4 bhi = *(const s16x4*)(bp + 4);
            s16x8 bf = __builtin_shufflevector(blo, bhi, 0,1,2,3,4,5,6,7);
            f32x4 s = __builtin_amdgcn_mfma_f32_16x16x32_bf16(qf, bf,
                        (f32x4){0.f,0.f,0.f,0.f}, 0, 0, 0);
            float rj = rnj[nt*16 + lm];
            #pragma unroll
            for (int r = 0; r < 4; ++r){
                float e = __expf(s[r]*rni4[r]*rj);
                lacc[r] += e;
                pw[(g*4 + r)*132 + nt*16 + lm] = f2b(e);
            }
        }
        #pragma unroll
        for (int ks = 0; ks < 4; ++ks){
            const s16* ap = &pw[lm*132 + ks*32 + g*8];
            s16x4 alo = *(const s16x4*)ap;
            s16x4 ahi = *(const s16x4*)(ap + 4);
            s16x8 af = __builtin_shufflevector(alo, ahi, 0,1,2,3,4,5,6,7);
            #pragma unroll
            for (int n2 = 0; n2 < 2; ++n2){
                const s16* vp = &vts[(n2*16 + lm)*132 + ks*32 + g*8];
                s16x4 vlo = *(const s16x4*)vp;
                s16x4 vhi = *(const s16x4*)(vp + 4);
                s16x8 vf = __builtin_shufflevector(vlo, vhi, 0,1,2,3,4,5,6,7);
                oacc[n2] = __builtin_amdgcn_mfma_f32_16x16x32_bf16(af, vf, oacc[n2], 0, 0, 0);
            }
        }
    }
    #pragma unroll
    for (int r = 0; r < 4; ++r){
        float v = lacc[r];
        v += __shfl_xor(v, 1, 16); v += __shfl_xor(v, 2, 16);
        v += __shfl_xor(v, 4, 16); v += __shfl_xor(v, 8, 16);
        lacc[r] = v;
    }
    const int base = (b*4 + chunk)*4096 + i0 + wv*16;
    #pragma unroll
    for (int n2 = 0; n2 < 2; ++n2)
        #pragma unroll
        for (int r = 0; r < 4; ++r)
            partA[(base + g*4 + r)*32 + n2*16 + lm] = oacc[n2][r];
    if (lm == 0){
        #pragma unroll
        for (int r = 0; r < 4; ++r) partL[base + g*4 + r] = lacc[r];
    }
}

// ---------------------------------------------------------------------------
// L) fused epilogue — 4-chunk merge variant.
// ---------------------------------------------------------------------------
__global__ __launch_bounds__(256) void finalfuse_k(const float* __restrict__ tbuf,
        const float* __restrict__ partA, const float* __restrict__ partL,
        const float* __restrict__ WtT, const float* __restrict__ WoT,
        const float* __restrict__ bfo, float* __restrict__ out){
    int pt = blockIdx.x, cog = blockIdx.y, b = blockIdx.z, t = threadIdx.x;
    int p = pt*256 + t;
    float l = 0.f;
    #pragma unroll
    for (int c = 0; c < 4; ++c) l += partL[(b*4 + c)*4096 + p];
    float inv = 1.f / l;
    float v3[32];
    #pragma unroll
    for (int q = 0; q < 8; ++q){
        float4 s0 = *(const float4*)&partA[((b*4 + 0)*4096 + p)*32 + q*4];
        float4 s1 = *(const float4*)&partA[((b*4 + 1)*4096 + p)*32 + q*4];
        float4 s2 = *(const float4*)&partA[((b*4 + 2)*4096 + p)*32 + q*4];
        float4 s3 = *(const float4*)&partA[((b*4 + 3)*4096 + p)*32 + q*4];
        v3[q*4+0] = (s0.x + s1.x + s2.x + s3.x)*inv;
        v3[q*4+1] = (s0.y + s1.y + s2.y + s3.y)*inv;
        v3[q*4+2] = (s0.z + s1.z + s2.z + s3.z)*inv;
        v3[q*4+3] = (s0.w + s1.w + s2.w + s3.w)*inv;
    }
    float acc[32];
    #pragma unroll
    for (int co = 0; co < 32; ++co) acc[co] = bfo[b*256 + cog*32 + co];
    for (int j = 0; j < 32; ++j){
        float vt = tbuf[(b*32 + j)*4096 + p];
        float vo = v3[j];
        const float* wtr = WtT + (b*32 + j)*256 + cog*32;   // wave-uniform
        const float* wor = WoT + (b*32 + j)*256 + cog*32;   // wave-uniform
        #pragma unroll
        for (int co = 0; co < 32; ++co) acc[co] += wtr[co]*vt + wor[co]*vo;
    }
    #pragma unroll
    for (int co = 0; co < 32; ++co)
        out[((b*256 + cog*32 + co)*4096) + p] = acc[co];
}

// ---------------------------------------------------------------------------
// Workspace layout (bytes), peak ~19.0 MB:
//   [0,        8388608)  xcl -> out1 -> gram part (256 KB) -> flash partA (8 MB)
//   [8388608, 16777216)  y0  -> tbuf / tTb
//   [12582912, ...)      WtT/WoT/bf (260 KB)
//   [16777216, ...)      wpk -> partL (256 KB);  attn1T/rn2 near byte 18.9 MB
// ---------------------------------------------------------------------------
extern "C" void kernel_launch(void* const* d_in, const int* in_sizes, int n_in,
                              void* d_out, int out_size, void* d_ws, size_t ws_size,
                              hipStream_t stream) {
    const float* x      = (const float*)d_in[0];
    const float* w_conv = (const float*)d_in[1];
    const float* b_conv = (const float*)d_in[2];
    const float* w01 = (const float*)d_in[3];  const float* b01 = (const float*)d_in[4];
    const float* w02 = (const float*)d_in[5];  const float* b02 = (const float*)d_in[6];
    const float* w11 = (const float*)d_in[7];  const float* b11 = (const float*)d_in[8];
    const float* w12 = (const float*)d_in[9];  const float* b12 = (const float*)d_in[10];
    const float* w21 = (const float*)d_in[11]; const float* b21 = (const float*)d_in[12];
    const float* w22 = (const float*)d_in[13]; const float* b22 = (const float*)d_in[14];
    const float* w_proj = (const float*)d_in[15]; const float* b_proj = (const float*)d_in[16];
    const float* w3 = (const float*)d_in[17]; const float* b3 = (const float*)d_in[18];
    const float* w4 = (const float*)d_in[19]; const float* b4 = (const float*)d_in[20];

    char* wsb = (char*)d_ws;
    s16*   xcl  = (s16*)wsb;                        // 4,194,304 s16 (conv input)
    bf16*  out1 = (bf16*)wsb;                       // same slot, after conv
    bf16*  y0   = (bf16*)(wsb + 8388608);           // 4,194,304 bf16
    s16*   wpk  = (s16*)(wsb + 16777216);           // 589,824 s16
    float* f    = (float*)d_ws;
    float* part   = f + 0;         // gram partials 4x16x1024 f (out1 dead)
    float* partA  = f + 0;         // flash partials 4x4x4096x32 f = 8 MB
    float* tbuf   = f + 2097152;   // byte  8,388,608 (overlays dead y0)
    s16*   tTb    = (s16*)(wsb + 10485760);         // 524,288 s16 = 1 MB
    float* WtT    = f + 3145728;   // byte 12,582,912  (4x32x256 f)
    float* WoT    = f + 3178496;
    float* bfo    = f + 3211264;
    float* partL  = f + 4194304;   // byte 16,777,216 (wpk dead by flashm), 64K f
    float* attn1T = f + 4722816;
    float* rn2    = f + 4726912;

    xtrans_k<<<dim3(64, 4), 256, 0, stream>>>(x, xcl);
    wpack_k<<<dim3(2304), 256, 0, stream>>>(w_conv, wpk);
    conv3x3m_k<<<dim3(128, 4), 256, 0, stream>>>(xcl, wpk, b_conv, y0);
    sepconv_k<<<dim3(1024), 256, 0, stream>>>(y0, w01, b01, w02, b02,
                                              w11, b11, w12, b12,
                                              w21, b21, w22, b22, out1);
    proj_k<<<dim3(64, 4), 256, 0, stream>>>(out1, w_proj, b_proj, tbuf, tTb, rn2);
    gramm_k<<<dim3(16, 4), 256, 0, stream>>>(tbuf, part);
    attn1_k<<<dim3(32, 4), 64, 0, stream>>>(part, attn1T);
    fold_k<<<dim3(4), 256, 0, stream>>>(attn1T, w3, b3, w4, b4, WtT, WoT, bfo);
    flashm_k<<<dim3(64, 4, 4), 256, 0, stream>>>(tTb, rn2, partA, partL);
    finalfuse_k<<<dim3(16, 8, 4), 256, 0, stream>>>(tbuf, partA, partL, WtT, WoT, bfo,
                                                    (float*)d_out);
}

// Round 14
// 294.733 us; speedup vs baseline: 6.3402x; 1.0468x over previous
//
#include <hip/hip_runtime.h>
#include <hip/hip_bf16.h>

typedef __hip_bfloat16 bf16;
typedef short s16;
typedef __attribute__((ext_vector_type(4))) short s16x4;
typedef __attribute__((ext_vector_type(8))) short s16x8;
typedef __attribute__((ext_vector_type(4))) float f32x4;

__device__ __forceinline__ s16 f2b(float f){
    unsigned u = __float_as_uint(f);
    unsigned r = (u + 0x7FFFu + ((u >> 16) & 1u)) >> 16;
    return (s16)r;
}
__device__ __forceinline__ float b2f_bits(s16 v){
    return __uint_as_float(((unsigned)(unsigned short)v) << 16);
}

// ---------------------------------------------------------------------------
// A) fused prep: blocks 0..255 = x transpose (NCHW fp32 -> CL bf16-bits);
//    blocks 256..831 = conv-weight pack ([co][ci][3][3] -> [cc][tap][co][ci32])
// ---------------------------------------------------------------------------
__global__ __launch_bounds__(256) void prep_k(const float* __restrict__ x, s16* __restrict__ xcl,
                                              const float* __restrict__ w, s16* __restrict__ wpk){
    __shared__ s16 lb[64][258];
    int blk = blockIdx.x, t = threadIdx.x;
    if (blk < 256){
        int h = blk & 63, b = blk >> 6;
        for (int i = t; i < 16384; i += 256){
            int ci = i >> 6, ww = i & 63;
            lb[ww][ci] = f2b(x[((b*256 + ci)*64 + h)*64 + ww]);
        }
        __syncthreads();
        for (int i = t; i < 16384; i += 256){
            int ww = i >> 8, ci = i & 255;
            xcl[(b*4096 + h*64 + ww)*256 + ci] = lb[ww][ci];
        }
    } else {
        int base = (blk - 256)*1024 + t;
        #pragma unroll
        for (int k = 0; k < 4; ++k){
            int idx = base + k*256;              // < 589824
            int cil = idx & 31;
            int r   = idx >> 5;
            int co  = r & 255;
            int r2  = r >> 8;
            int tap = r2 % 9, cc = r2 / 9;
            wpk[idx] = f2b(w[(co*256 + cc*32 + cil)*9 + tap]);
        }
    }
}

// ---------------------------------------------------------------------------
// B) 3x3 conv 256->256 as MFMA implicit GEMM (R11/R13 M=128 tile, unchanged)
// ---------------------------------------------------------------------------
__global__ __launch_bounds__(256) void conv3x3m_k(const s16* __restrict__ xcl,
        const s16* __restrict__ wpk, const float* __restrict__ bias,
        bf16* __restrict__ y0){
    __shared__ alignas(16) s16 smem[30240];      // 60.5 KB
    s16* xls = smem;                             // [4 rows][66 w][36 ci-pad]
    s16* wls = smem + 9504;                      // [9 tap][64 co][36 ci-pad]
    const int sp = blockIdx.x, cog = blockIdx.y;
    const int b = sp >> 5, h0 = (sp & 31)*2;
    const int t = threadIdx.x;
    const int wv = t >> 6, lane = t & 63;
    const int lm = lane & 15, g = lane >> 4;

    f32x4 acc[2][4];
    #pragma unroll
    for (int mi = 0; mi < 2; ++mi)
        #pragma unroll
        for (int ni = 0; ni < 4; ++ni) acc[mi][ni] = (f32x4){0.f,0.f,0.f,0.f};

    for (int cc = 0; cc < 8; ++cc){
        __syncthreads();
        for (int i = t; i < 1056; i += 256){
            int g8 = i & 3, wi = (i>>2) % 66, r = (i>>2) / 66;
            int h = h0 - 1 + r, w = wi - 1;
            s16x8 v = {0,0,0,0,0,0,0,0};
            if (h >= 0 && h < 64 && w >= 0 && w < 64)
                v = *(const s16x8*)&xcl[(b*4096 + h*64 + w)*256 + cc*32 + g8*8];
            s16* d = &xls[(r*66 + wi)*36 + g8*8];
            *(s16x4*)d       = __builtin_shufflevector(v, v, 0,1,2,3);
            *(s16x4*)(d + 4) = __builtin_shufflevector(v, v, 4,5,6,7);
        }
        for (int i = t; i < 2304; i += 256){
            int g8 = i & 3, co = (i>>2) & 63, tap = i >> 8;
            s16x8 v = *(const s16x8*)&wpk[((cc*9 + tap)*256 + cog*64 + co)*32 + g8*8];
            s16* d = &wls[(tap*64 + co)*36 + g8*8];
            *(s16x4*)d       = __builtin_shufflevector(v, v, 0,1,2,3);
            *(s16x4*)(d + 4) = __builtin_shufflevector(v, v, 4,5,6,7);
        }
        __syncthreads();
        #pragma unroll
        for (int tap = 0; tap < 9; ++tap){
            const int kh = tap/3, kw = tap%3;
            s16x8 bfr[4], afr[2];
            #pragma unroll
            for (int ni = 0; ni < 4; ++ni){
                const s16* p = &wls[(tap*64 + ni*16 + lm)*36 + g*8];
                s16x4 lo = *(const s16x4*)p;
                s16x4 hi = *(const s16x4*)(p + 4);
                bfr[ni] = __builtin_shufflevector(lo, hi, 0,1,2,3,4,5,6,7);
            }
            #pragma unroll
            for (int mi = 0; mi < 2; ++mi){
                int m = (wv*2 + mi)*16 + lm;
                int hr = m >> 6, ww = m & 63;
                const s16* p = &xls[((hr + kh)*66 + (ww + kw))*36 + g*8];
                s16x4 lo = *(const s16x4*)p;
                s16x4 hi = *(const s16x4*)(p + 4);
                afr[mi] = __builtin_shufflevector(lo, hi, 0,1,2,3,4,5,6,7);
            }
            #pragma unroll
            for (int mi = 0; mi < 2; ++mi)
                #pragma unroll
                for (int ni = 0; ni < 4; ++ni)
                    acc[mi][ni] = __builtin_amdgcn_mfma_f32_16x16x32_bf16(
                        afr[mi], bfr[ni], acc[mi][ni], 0, 0, 0);
        }
    }
    __syncthreads();
    float* ot = (float*)smem;                    // [64 co][132 m-pad]
    #pragma unroll
    for (int mi = 0; mi < 2; ++mi)
        #pragma unroll
        for (int ni = 0; ni < 4; ++ni)
            #pragma unroll
            for (int r = 0; r < 4; ++r){
                int m  = (wv*2 + mi)*16 + g*4 + r;
                int co = ni*16 + lm;
                ot[co*132 + m] = acc[mi][ni][r];
            }
    __syncthreads();
    for (int i = t; i < 8192; i += 256){
        int co = i >> 7, m = i & 127;
        float v = ot[co*132 + m] + bias[cog*64 + co];
        y0[((b*256 + cog*64 + co)*64 + h0 + (m>>6))*64 + (m & 63)] = __float2bfloat16(v);
    }
}

// ---------------------------------------------------------------------------
// C) fused separable depthwise (7/11/21) + residual, sliding-window (R13)
// ---------------------------------------------------------------------------
template<int K>
__device__ __forceinline__ void sep_branch(const float (*__restrict__ pl)[65], float (*__restrict__ hp)[65],
                                           int c, int t,
                                           const float* __restrict__ wh, const float* __restrict__ bh,
                                           const float* __restrict__ wv, const float* __restrict__ bv,
                                           float* acc){
    constexpr int P = K/2;
    constexpr int W = 16 + 2*P;
    float wk[K];
    #pragma unroll
    for (int j = 0; j < K; ++j) wk[j] = wh[c*K + j];
    float bhv = bh[c];
    {
        int h = t >> 2, w0 = (t & 3)*16;
        float win[W];
        #pragma unroll
        for (int j = 0; j < W; ++j){
            int ww = w0 - P + j;
            win[j] = (ww >= 0 && ww < 64) ? pl[h][ww] : 0.f;
        }
        __syncthreads();                 // prev-branch hp reads complete
        #pragma unroll
        for (int i = 0; i < 16; ++i){
            float s = bhv;
            #pragma unroll
            for (int k = 0; k < K; ++k) s += win[i+k]*wk[k];
            hp[h][w0 + i] = s;
        }
    }
    float vk[K];
    #pragma unroll
    for (int j = 0; j < K; ++j) vk[j] = wv[c*K + j];
    float bvv = bv[c];
    __syncthreads();                     // hp writes visible
    {
        int w = t & 63, h0 = (t >> 6)*16;
        float win[W];
        #pragma unroll
        for (int j = 0; j < W; ++j){
            int hh = h0 - P + j;
            win[j] = (hh >= 0 && hh < 64) ? hp[hh][w] : 0.f;
        }
        #pragma unroll
        for (int i = 0; i < 16; ++i){
            float s = bvv;
            #pragma unroll
            for (int k = 0; k < K; ++k) s += win[i+k]*vk[k];
            acc[i] += s;
        }
    }
}

__global__ __launch_bounds__(256) void sepconv_k(const bf16* __restrict__ y0,
        const float* __restrict__ w01, const float* __restrict__ b01,
        const float* __restrict__ w02, const float* __restrict__ b02,
        const float* __restrict__ w11, const float* __restrict__ b11,
        const float* __restrict__ w12, const float* __restrict__ b12,
        const float* __restrict__ w21, const float* __restrict__ b21,
        const float* __restrict__ w22, const float* __restrict__ b22,
        bf16* __restrict__ out1){
    __shared__ float pl[64][65];
    __shared__ float hp[64][65];
    int bc = blockIdx.x;             // b*256 + c
    int c = bc & 255;
    int t = threadIdx.x;
    const bf16* src = y0 + bc*4096;
    for (int i = t; i < 4096; i += 256) pl[i>>6][i&63] = __bfloat162float(src[i]);
    __syncthreads();
    float acc[16];
    #pragma unroll
    for (int k = 0; k < 16; ++k) acc[k] = 0.f;
    sep_branch<7 >(pl, hp, c, t, w01, b01, w02, b02, acc);
    sep_branch<11>(pl, hp, c, t, w11, b11, w12, b12, acc);
    sep_branch<21>(pl, hp, c, t, w21, b21, w22, b22, acc);
    bf16* dst = out1 + bc*4096;
    {
        int w = t & 63, h0 = (t >> 6)*16;
        #pragma unroll
        for (int i = 0; i < 16; ++i)
            dst[(h0 + i)*64 + w] = __float2bfloat16(acc[i] + pl[h0 + i][w]);
    }
}

// ---------------------------------------------------------------------------
// E) 1x1 projection 256->32, 4-way ci-split.  Now writes ONLY tTb (bf16) +
//    rn2 — the fp32 tbuf is gone (gramm/finalfuse read tTb).
// ---------------------------------------------------------------------------
__global__ __launch_bounds__(256) void proj_k(const bf16* __restrict__ out1, const float* __restrict__ wp,
                                              const float* __restrict__ bp,
                                              s16* __restrict__ tTb, float* __restrict__ rn2){
    __shared__ float wl[256*32];         // [ci][cc] fp32, 32 KB
    __shared__ s16 part[4][64][36];      // bf16 partials, 18.4 KB
    int pt = blockIdx.x, b = blockIdx.y, t = threadIdx.x;
    int q = t >> 6, lane = t & 63;
    for (int i = t; i < 8192; i += 256){
        int ci = i >> 5, cc = i & 31;
        wl[ci*32 + cc] = wp[cc*256 + ci];
    }
    __syncthreads();
    int p = pt*64 + lane;
    float acc[32] = {};
    const bf16* xb = out1 + b*1048576 + p;
    for (int ci = q*64; ci < q*64 + 64; ++ci){
        float v = __bfloat162float(xb[ci*4096]);
        const float* wr = &wl[ci*32];
        #pragma unroll
        for (int c8 = 0; c8 < 8; ++c8){
            float4 w4 = *(const float4*)&wr[c8*4];
            acc[c8*4+0] += w4.x*v; acc[c8*4+1] += w4.y*v;
            acc[c8*4+2] += w4.z*v; acc[c8*4+3] += w4.w*v;
        }
    }
    #pragma unroll
    for (int cc = 0; cc < 32; ++cc) part[q][lane][cc] = f2b(acc[cc]);
    __syncthreads();
    int p_loc = t >> 2, qq = t & 3;
    int pg = pt*64 + p_loc;
    float a8[8];
    float ss = 0.f;
    #pragma unroll
    for (int c = 0; c < 8; ++c){
        int cc = qq*8 + c;
        float v = b2f_bits(part[0][p_loc][cc]) + b2f_bits(part[1][p_loc][cc])
                + b2f_bits(part[2][p_loc][cc]) + b2f_bits(part[3][p_loc][cc]) + bp[cc];
        a8[c] = v;
        ss += v*v;
    }
    ss += __shfl_xor(ss, 1, 4);
    ss += __shfl_xor(ss, 2, 4);
    if (qq == 0) rn2[b*4096 + pg] = 1.f / fmaxf(sqrtf(ss), 1e-12f);
    s16x8 o8;
    #pragma unroll
    for (int c = 0; c < 8; ++c) o8[c] = f2b(a8[c]);
    *(s16x8*)&tTb[(b*4096 + pg)*32 + qq*8] = o8;
}

// ---------------------------------------------------------------------------
// G1) Gram via MFMA, staged from tTb (thread t = one p-row, 64B contiguous
//     read, column-scatter into ts[cc][p] — 2-way bank max).
// ---------------------------------------------------------------------------
__global__ __launch_bounds__(256) void gramm_k(const s16* __restrict__ tTb, float* __restrict__ part){
    __shared__ alignas(16) s16 ts[32*268];       // 16.75 KB
    int ks = blockIdx.x, b = blockIdx.y, t = threadIdx.x;
    {
        const s16* src = &tTb[(b*4096 + ks*256 + t)*32];
        s16 row[32];
        #pragma unroll
        for (int q = 0; q < 4; ++q){
            s16x8 v = *(const s16x8*)&src[q*8];
            #pragma unroll
            for (int e = 0; e < 8; ++e) row[q*8 + e] = v[e];
        }
        #pragma unroll
        for (int cc = 0; cc < 32; ++cc) ts[cc*268 + t] = row[cc];
    }
    __syncthreads();
    int wv = t >> 6, lane = t & 63, lm = lane & 15, g = lane >> 4;
    int mi = wv >> 1, ni = wv & 1;
    f32x4 acc = (f32x4){0.f,0.f,0.f,0.f};
    const s16* ar = &ts[(mi*16 + lm)*268];
    const s16* br = &ts[(ni*16 + lm)*268];
    #pragma unroll
    for (int kk = 0; kk < 8; ++kk){
        const s16* ap = ar + kk*32 + g*8;
        s16x4 alo = *(const s16x4*)ap;
        s16x4 ahi = *(const s16x4*)(ap + 4);
        s16x8 af = __builtin_shufflevector(alo, ahi, 0,1,2,3,4,5,6,7);
        const s16* bp = br + kk*32 + g*8;
        s16x4 blo = *(const s16x4*)bp;
        s16x4 bhi = *(const s16x4*)(bp + 4);
        s16x8 bf = __builtin_shufflevector(blo, bhi, 0,1,2,3,4,5,6,7);
        acc = __builtin_amdgcn_mfma_f32_16x16x32_bf16(af, bf, acc, 0, 0, 0);
    }
    float* pd = part + (b*16 + ks)*1024;
    #pragma unroll
    for (int r = 0; r < 4; ++r){
        int i = mi*16 + g*4 + r, j = ni*16 + lm;
        pd[i*32 + j] = acc[r];
    }
}

// ---------------------------------------------------------------------------
// G2+G3) fused: attn1 softmax (rn1 from gram diag) + fold into WtT/WoT/bfo.
//     Grid (4 b) x 256 threads.
// ---------------------------------------------------------------------------
__global__ __launch_bounds__(256) void afold_k(const float* __restrict__ part,
        const float* __restrict__ w3, const float* __restrict__ b3,
        const float* __restrict__ w4, const float* __restrict__ b4,
        float* __restrict__ WtT, float* __restrict__ WoT, float* __restrict__ bfo){
    __shared__ float rn[32];
    __shared__ float rsum[32];
    __shared__ float a1[1024];     // attn1[i][j] (exp, then normalized)
    __shared__ float w3a[1024];    // [cc][j]
    __shared__ float w3bs[1024];   // [cc][j]
    int b = blockIdx.x, t = threadIdx.x;
    // rnj from gram diagonal
    if (t < 32){
        float gjj = 0.f;
        #pragma unroll 8
        for (int ps = 0; ps < 16; ++ps) gjj += part[(b*16+ps)*1024 + t*33];
        rn[t] = 1.f / fmaxf(sqrtf(gjj), 1e-12f);
    }
    for (int idx = t; idx < 1024; idx += 256){
        int i = idx >> 5, j = idx & 31;
        w3bs[idx] = w3[i*64 + 32 + j];
    }
    __syncthreads();
    // exp(scores)
    for (int e = t; e < 1024; e += 256){
        int i = e >> 5, j = e & 31;
        float gij = 0.f;
        #pragma unroll 8
        for (int ps = 0; ps < 16; ++ps) gij += part[(b*16+ps)*1024 + e];
        a1[e] = __expf(rn[i]*rn[j]*gij);
    }
    __syncthreads();
    if (t < 32){
        float s = 0.f;
        #pragma unroll 8
        for (int j = 0; j < 32; ++j) s += a1[t*32 + j];
        rsum[t] = 1.f / s;
    }
    __syncthreads();
    for (int e = t; e < 1024; e += 256) a1[e] *= rsum[e >> 5];
    __syncthreads();
    // w3a = w3[:, :32] @ attn1
    for (int idx = t; idx < 1024; idx += 256){
        int cc = idx >> 5, j = idx & 31;
        float s = 0.f;
        #pragma unroll 8
        for (int i = 0; i < 32; ++i) s += w3[cc*64 + i]*a1[i*32 + j];
        w3a[idx] = s;
    }
    __syncthreads();
    int co = t;
    float w4r[32];
    #pragma unroll
    for (int cc = 0; cc < 32; ++cc) w4r[cc] = w4[co*32 + cc];
    float bfv = b4[co];
    #pragma unroll
    for (int cc = 0; cc < 32; ++cc) bfv += w4r[cc]*b3[cc];
    bfo[b*256 + co] = bfv;
    for (int j = 0; j < 32; ++j){
        float st = w4r[j];           // w4 identity term = +t residual through w4
        float so = 0.f;
        #pragma unroll 8
        for (int cc = 0; cc < 32; ++cc){
            st += w4r[cc]*w3a[cc*32 + j];
            so += w4r[cc]*w3bs[cc*32 + j];
        }
        WtT[(b*32 + j)*256 + co] = st;
        WoT[(b*32 + j)*256 + co] = so;
    }
}

// ---------------------------------------------------------------------------
// J) spatial attention via MFMA flash — 4-way j-chunk split (R13, unchanged)
// ---------------------------------------------------------------------------
__global__ __launch_bounds__(256) void flashm_k(const s16* __restrict__ tTb, const float* __restrict__ rn2,
                                                float* __restrict__ partA, float* __restrict__ partL){
    __shared__ alignas(16) s16 kvb[128*36];      // [j][ci]   9216 B
    __shared__ alignas(16) s16 vts[32*132];      // [ci][j]   8448 B
    __shared__ alignas(16) s16 pls[4][16*132];   // per-wave P [m][j] 16896 B
    __shared__ float rnj[128];
    __shared__ float ri[64];
    const int ib = blockIdx.x, b = blockIdx.y, chunk = blockIdx.z;
    const int t = threadIdx.x, wv = t >> 6, lane = t & 63;
    const int lm = lane & 15, g = lane >> 4;
    const int i0 = ib*64;

    if (t < 64) ri[t] = rn2[b*4096 + i0 + t];
    s16x8 qf = *(const s16x8*)&tTb[(b*4096 + i0 + wv*16 + lm)*32 + g*8];
    __syncthreads();
    float rni4[4];
    #pragma unroll
    for (int r = 0; r < 4; ++r) rni4[r] = ri[wv*16 + g*4 + r];

    f32x4 oacc[2];
    oacc[0] = (f32x4){0.f,0.f,0.f,0.f};
    oacc[1] = (f32x4){0.f,0.f,0.f,0.f};
    float lacc[4] = {0.f,0.f,0.f,0.f};
    s16* pw = pls[wv];

    for (int jt = chunk*8; jt < chunk*8 + 8; ++jt){
        const int j0 = jt*128;
        __syncthreads();
        for (int gi = t; gi < 512; gi += 256){
            int j = gi >> 2, g8 = gi & 3;
            s16x8 v = *(const s16x8*)&tTb[(b*4096 + j0 + j)*32 + g8*8];
            s16* d = &kvb[j*36 + g8*8];
            *(s16x4*)d       = __builtin_shufflevector(v, v, 0,1,2,3);
            *(s16x4*)(d + 4) = __builtin_shufflevector(v, v, 4,5,6,7);
            #pragma unroll
            for (int e = 0; e < 8; ++e) vts[(g8*8 + e)*132 + j] = v[e];
        }
        if (t < 128) rnj[t] = rn2[b*4096 + j0 + t];
        __syncthreads();
        #pragma unroll
        for (int nt = 0; nt < 8; ++nt){
            const s16* bp = &kvb[(nt*16 + lm)*36 + g*8];
            s16x4 blo = *(const s16x4*)bp;
            s16x4 bhi = *(const s16x4*)(bp + 4);
            s16x8 bf = __builtin_shufflevector(blo, bhi, 0,1,2,3,4,5,6,7);
            f32x4 s = __builtin_amdgcn_mfma_f32_16x16x32_bf16(qf, bf,
                        (f32x4){0.f,0.f,0.f,0.f}, 0, 0, 0);
            float rj = rnj[nt*16 + lm];
            #pragma unroll
            for (int r = 0; r < 4; ++r){
                float e = __expf(s[r]*rni4[r]*rj);
                lacc[r] += e;
                pw[(g*4 + r)*132 + nt*16 + lm] = f2b(e);
            }
        }
        #pragma unroll
        for (int ks = 0; ks < 4; ++ks){
            const s16* ap = &pw[lm*132 + ks*32 + g*8];
            s16x4 alo = *(const s16x4*)ap;
            s16x4 ahi = *(const s16x4*)(ap + 4);
            s16x8 af = __builtin_shufflevector(alo, ahi, 0,1,2,3,4,5,6,7);
            #pragma unroll
            for (int n2 = 0; n2 < 2; ++n2){
                const s16* vp = &vts[(n2*16 + lm)*132 + ks*32 + g*8];
                s16x4 vlo = *(const s16x4*)vp;
                s16x4 vhi = *(const s16x4*)(vp + 4);
                s16x8 vf = __builtin_shufflevector(vlo, vhi, 0,1,2,3,4,5,6,7);
                oacc[n2] = __builtin_amdgcn_mfma_f32_16x16x32_bf16(af, vf, oacc[n2], 0, 0, 0);
            }
        }
    }
    #pragma unroll
    for (int r = 0; r < 4; ++r){
        float v = lacc[r];
        v += __shfl_xor(v, 1, 16); v += __shfl_xor(v, 2, 16);
        v += __shfl_xor(v, 4, 16); v += __shfl_xor(v, 8, 16);
        lacc[r] = v;
    }
    const int base = (b*4 + chunk)*4096 + i0 + wv*16;
    #pragma unroll
    for (int n2 = 0; n2 < 2; ++n2)
        #pragma unroll
        for (int r = 0; r < 4; ++r)
            partA[(base + g*4 + r)*32 + n2*16 + lm] = oacc[n2][r];
    if (lm == 0){
        #pragma unroll
        for (int r = 0; r < 4; ++r) partL[base + g*4 + r] = lacc[r];
    }
}

// ---------------------------------------------------------------------------
// L) fused epilogue — t loaded from tTb (64 B/lane contiguous), 4-chunk merge.
// ---------------------------------------------------------------------------
__global__ __launch_bounds__(256) void finalfuse_k(const s16* __restrict__ tTb,
        const float* __restrict__ partA, const float* __restrict__ partL,
        const float* __restrict__ WtT, const float* __restrict__ WoT,
        const float* __restrict__ bfo, float* __restrict__ out){
    int pt = blockIdx.x, cog = blockIdx.y, b = blockIdx.z, t = threadIdx.x;
    int p = pt*256 + t;
    float l = 0.f;
    #pragma unroll
    for (int c = 0; c < 4; ++c) l += partL[(b*4 + c)*4096 + p];
    float inv = 1.f / l;
    float v3[32];
    #pragma unroll
    for (int q = 0; q < 8; ++q){
        float4 s0 = *(const float4*)&partA[((b*4 + 0)*4096 + p)*32 + q*4];
        float4 s1 = *(const float4*)&partA[((b*4 + 1)*4096 + p)*32 + q*4];
        float4 s2 = *(const float4*)&partA[((b*4 + 2)*4096 + p)*32 + q*4];
        float4 s3 = *(const float4*)&partA[((b*4 + 3)*4096 + p)*32 + q*4];
        v3[q*4+0] = (s0.x + s1.x + s2.x + s3.x)*inv;
        v3[q*4+1] = (s0.y + s1.y + s2.y + s3.y)*inv;
        v3[q*4+2] = (s0.z + s1.z + s2.z + s3.z)*inv;
        v3[q*4+3] = (s0.w + s1.w + s2.w + s3.w)*inv;
    }
    float vt[32];
    {
        const s16* tp = &tTb[(b*4096 + p)*32];
        #pragma unroll
        for (int q = 0; q < 4; ++q){
            s16x8 v = *(const s16x8*)&tp[q*8];
            #pragma unroll
            for (int e = 0; e < 8; ++e) vt[q*8 + e] = b2f_bits(v[e]);
        }
    }
    float acc[32];
    #pragma unroll
    for (int co = 0; co < 32; ++co) acc[co] = bfo[b*256 + cog*32 + co];
    for (int j = 0; j < 32; ++j){
        float vtj = vt[j];
        float vo  = v3[j];
        const float* wtr = WtT + (b*32 + j)*256 + cog*32;   // wave-uniform
        const float* wor = WoT + (b*32 + j)*256 + cog*32;   // wave-uniform
        #pragma unroll
        for (int co = 0; co < 32; ++co) acc[co] += wtr[co]*vtj + wor[co]*vo;
    }
    #pragma unroll
    for (int co = 0; co < 32; ++co)
        out[((b*256 + cog*32 + co)*4096) + p] = acc[co];
}

// ---------------------------------------------------------------------------
// Workspace layout (bytes), peak ~19.0 MB:
//   [0,        8388608)  xcl -> out1 -> gram part (256 KB) -> flash partA (8 MB)
//   [8388608, 16777216)  y0  -> tTb (1 MB at +10.5 MB)
//   [12582912, ...)      WtT/WoT/bfo (260 KB)
//   [16777216, ...)      wpk -> partL (256 KB);  rn2 near byte 18.9 MB
// ---------------------------------------------------------------------------
extern "C" void kernel_launch(void* const* d_in, const int* in_sizes, int n_in,
                              void* d_out, int out_size, void* d_ws, size_t ws_size,
                              hipStream_t stream) {
    const float* x      = (const float*)d_in[0];
    const float* w_conv = (const float*)d_in[1];
    const float* b_conv = (const float*)d_in[2];
    const float* w01 = (const float*)d_in[3];  const float* b01 = (const float*)d_in[4];
    const float* w02 = (const float*)d_in[5];  const float* b02 = (const float*)d_in[6];
    const float* w11 = (const float*)d_in[7];  const float* b11 = (const float*)d_in[8];
    const float* w12 = (const float*)d_in[9];  const float* b12 = (const float*)d_in[10];
    const float* w21 = (const float*)d_in[11]; const float* b21 = (const float*)d_in[12];
    const float* w22 = (const float*)d_in[13]; const float* b22 = (const float*)d_in[14];
    const float* w_proj = (const float*)d_in[15]; const float* b_proj = (const float*)d_in[16];
    const float* w3 = (const float*)d_in[17]; const float* b3 = (const float*)d_in[18];
    const float* w4 = (const float*)d_in[19]; const float* b4 = (const float*)d_in[20];

    char* wsb = (char*)d_ws;
    s16*   xcl  = (s16*)wsb;                        // 4,194,304 s16 (conv input)
    bf16*  out1 = (bf16*)wsb;                       // same slot, after conv
    bf16*  y0   = (bf16*)(wsb + 8388608);           // 4,194,304 bf16
    s16*   wpk  = (s16*)(wsb + 16777216);           // 589,824 s16
    float* f    = (float*)d_ws;
    float* part   = f + 0;         // gram partials 4x16x1024 f (out1 dead)
    float* partA  = f + 0;         // flash partials 4x4x4096x32 f = 8 MB
    s16*   tTb    = (s16*)(wsb + 10485760);         // 524,288 s16 = 1 MB
    float* WtT    = f + 3145728;   // byte 12,582,912  (4x32x256 f)
    float* WoT    = f + 3178496;
    float* bfo    = f + 3211264;
    float* partL  = f + 4194304;   // byte 16,777,216 (wpk dead by flashm), 64K f
    float* rn2    = f + 4726912;

    prep_k<<<dim3(832), 256, 0, stream>>>(x, xcl, w_conv, wpk);
    conv3x3m_k<<<dim3(128, 4), 256, 0, stream>>>(xcl, wpk, b_conv, y0);
    sepconv_k<<<dim3(1024), 256, 0, stream>>>(y0, w01, b01, w02, b02,
                                              w11, b11, w12, b12,
                                              w21, b21, w22, b22, out1);
    proj_k<<<dim3(64, 4), 256, 0, stream>>>(out1, w_proj, b_proj, tTb, rn2);
    gramm_k<<<dim3(16, 4), 256, 0, stream>>>(tTb, part);
    afold_k<<<dim3(4), 256, 0, stream>>>(part, w3, b3, w4, b4, WtT, WoT, bfo);
    flashm_k<<<dim3(64, 4, 4), 256, 0, stream>>>(tTb, rn2, partA, partL);
    finalfuse_k<<<dim3(16, 8, 4), 256, 0, stream>>>(tTb, partA, partL, WtT, WoT, bfo,
                                                    (float*)d_out);
}